// Round 6
// baseline (1797.935 us; speedup 1.0000x reference)
//
#include <hip/hip_runtime.h>
#include <math.h>

#define WP_ 63
#define NPATCH 3969
#define PI_D 3.141592653589793
#define TWO_PI_D 6.283185307179586476925287

// numpy remainder(v, 2pi): fmod then fix sign
__device__ __forceinline__ double remtp_d(double v) {
  double r = fmod(v, TWO_PI_D);
  if (r < 0.0) r += TWO_PI_D;
  return r;
}

// np.linspace(-1,1,8): y = i*step + start (two roundings), y[-1]=stop exact
__device__ __forceinline__ double lin8d(int i) {
  if (i == 7) return 1.0;
  return __dadd_rn(__dmul_rn((double)i, 2.0 / 7.0), -1.0);
}
// np.linspace(0,2pi,32)[:31]: i*step (+0.0 exact)
__device__ __forceinline__ double angd(int n) {
  return __dmul_rn((double)n, TWO_PI_D / 31.0);
}
// np.linspace(-3,3,31): i*0.2 + (-3), y[-1]=3 exact
__device__ __forceinline__ double xyd(int n) {
  if (n == 30) return 3.0;
  return __dadd_rn(__dmul_rn((double)n, 6.0 / 30.0), -3.0);
}

// x^35 LSB-first binary exponentiation (numpy npy_pow integer fast path)
__device__ __forceinline__ double pow35_d(double x) {
#pragma clang fp contract(off)
  double x2 = x * x;
  double r = x * x2;      // x^3
  double b = x2 * x2;     // x^4
  b = b * b;              // x^8
  b = b * b;              // x^16
  b = b * b;              // x^32
  return r * b;           // x^35
}

// fdlibm-style atan for x >= 0, branchless (select range reduction,
// one f64 divide, 11-term odd poly). |err| < ~1.5 ulp -> loss noise 1e-15.
__device__ __forceinline__ double atan_pos(double x) {
  bool c0 = x < 0.4375;
  bool c1 = x < 0.6875;
  bool c2 = x < 1.1875;
  bool c3 = x < 2.4375;
  double num = c0 ? x : c1 ? (2.0 * x - 1.0) : c2 ? (x - 1.0)
             : c3 ? (x - 1.5) : -1.0;
  double den = c0 ? 1.0 : c1 ? (2.0 + x) : c2 ? (x + 1.0)
             : c3 ? (1.0 + 1.5 * x) : x;
  double hi = c0 ? 0.0
            : c1 ? 4.63647609000806093515e-01
            : c2 ? 7.85398163397448278999e-01
            : c3 ? 9.82793723247329054082e-01
                 : 1.57079632679489655800e+00;
  double lo = c0 ? 0.0
            : c1 ? 2.26987774529616870924e-17
            : c2 ? 3.06161699786838301793e-17
            : c3 ? 1.39033110312309984516e-17
                 : 6.12323399573676603587e-17;
  double t = num / den;
  double z = t * t;
  double w = z * z;
  double s1 = z * (3.33333333333329318027e-01 +
              w * (1.42857142725034663711e-01 +
              w * (9.09088713343650656196e-02 +
              w * (6.66107313738753120669e-02 +
              w * (4.97687799461593236017e-02 +
              w *  1.62858201153657823623e-02)))));
  double s2 = w * (-1.99999999998764832476e-01 +
              w * (-1.11111104054623557880e-01 +
              w * (-7.69187620504482999495e-02 +
              w * (-5.83357013379057348645e-02 +
              w *  -3.65315727442169155270e-02))));
  return hi - ((t * (s1 + s2) - lo) - t);
}

// h = 0.5*(1 + (2/pi)*atan(d/0.01)); 1.0/0.01 rounds to exactly 100.0 in f64
__device__ __forceinline__ double hstep(double d) {
  double z = d * 100.0;
  double az = fabs(z);
  double a = atan_pos(az);
  a = (z < 0.0) ? -a : a;
  return 0.5 + 0.31830988618379067154 * a;  // 1/pi
}

struct JPd {
  double s1, c1, s2, c2, s3, c3, s4, c4;
  double sg13, sg42, gt13, gt42;
};

__device__ JPd jprep_d(double p0, double p1, double p2) {
#pragma clang fp contract(off)
  double r0 = remtp_d(p0), r1 = remtp_d(p1), r2 = remtp_d(p2);
  double mn = fmin(r0, r1), mx = fmax(r0, r1);
  double a1 = fmin(mn, r2);
  double a3 = fmax(mx, r2);
  double a2 = fmax(mn, fmin(mx, r2));  // exact 3-sort median
  double remm = remtp_d(0.5 * (a1 - a3));
  double a4 = 0.5 * (a1 + a3) + ((remm >= PI_D) ? PI_D : 0.0);
  JPd j;
  double r42 = remtp_d(a2 - a4);
  j.sg42 = (r42 < PI_D) ? 1.0 : -1.0;
  j.gt42 = pow35_d(r42 / PI_D - 1.0) * 0.1;
  double r13 = remtp_d(a3 - a1);
  j.sg13 = (r13 < PI_D) ? 1.0 : -1.0;
  j.gt13 = pow35_d(r13 / PI_D - 1.0) * 0.1;
  j.s1 = sin(a1); j.c1 = cos(a1);
  j.s2 = sin(a2); j.c2 = cos(a2);
  j.s3 = sin(a3); j.c3 = cos(a3);
  j.s4 = sin(a4); j.c4 = cos(a4);
  return j;
}

// distances + wedge weights (FMA contraction allowed: ~1ulp reordering,
// loss noise ~1e-15 -- same band as f64 transcendental noise, no flips)
__device__ __forceinline__ void jdw_d(const JPd& j, double dx, double dy,
                                      double& d13, double& d42,
                                      double& w0, double& w1, double& w2) {
  double hl1 = (-j.s1) * dx + j.c1 * dy;
  double hl2 = (-j.s2) * dx + j.c2 * dy;
  double hl3 = (-j.s3) * dx + j.c3 * dy;
  double hl4 = (-j.s4) * dx + j.c4 * dy;
  d13 = j.sg13 * fmin(j.sg13 * hl1, (-j.sg13) * hl3) + j.gt13;
  d42 = j.sg42 * fmin(j.sg42 * hl4, (-j.sg42) * hl2) + j.gt42;
  double h1 = hstep(d13);
  double h2 = hstep(d42);
  w0 = 1.0 - h1;
  w1 = h1 * (1.0 - h2);
  w2 = h1 * h2;
}

// ---------------- Kernel A: coordinate descent (float64, one-pass) -------
// 1 wave = 1 patch. lane = 32*pixel_half + candidate.
__global__ void __launch_bounds__(256, 4)
foj_descent(const float* __restrict__ x, double* __restrict__ pout) {
  const int tid = threadIdx.x;
  const int wv = tid >> 6;
  const int lane = tid & 63;
  const int hp = lane >> 5;     // pixel half (0: rows 0-3, 1: rows 4-7)
  const int cand = lane & 31;
  const int patch = blockIdx.x * 4 + wv;

  __shared__ float4 simg[4][64];
  if (patch < NPATCH) {
    int ph = patch / WP_;
    int pw = patch - ph * WP_;
    int py = lane >> 3, pxx = lane & 7;
    int base = (ph * 4 + py) * 256 + (pw * 4 + pxx);
    float4 v;
    v.x = x[base];
    v.y = x[65536 + base];
    v.z = x[131072 + base];
    v.w = 0.0f;
    simg[wv][lane] = v;
  }
  __syncthreads();
  if (patch >= NPATCH) return;
  const float4* sp = simg[wv];

  double q0 = 0.0, q1 = 0.0, q2 = 0.0, q3 = 0.0, q4 = 0.0;

#pragma unroll 1
  for (int i = 0; i < 5; ++i) {
    double rv = (i < 3) ? angd(cand) : xyd(cand);
    double p0 = q0 + ((i == 0) ? rv : 0.0);
    double p1 = q1 + ((i == 1) ? rv : 0.0);
    double p2 = q2 + ((i == 2) ? rv : 0.0);
    double x0 = q3 + ((i == 3) ? rv : 0.0);
    double y0 = q4 + ((i == 4) ? rv : 0.0);

    JPd j = jprep_d(p0, p1, p2);

    double den0 = 0, den1 = 0, den2 = 0;
    double n00 = 0, n01 = 0, n02 = 0, n10 = 0, n11 = 0, n12 = 0;
    double n20 = 0, n21 = 0, n22 = 0;
    double W00 = 0, W01 = 0, W02 = 0, W11 = 0, W12 = 0, W22 = 0;
#pragma unroll 1
    for (int r = 0; r < 4; ++r) {
      int iy = hp * 4 + r;
      double liny = (iy == 7) ? 1.0
                  : __dadd_rn(__dmul_rn((double)iy, 2.0 / 7.0), -1.0);
      double dy = liny - y0;
      const float4* rowp = sp + hp * 32 + r * 8;
#pragma unroll
      for (int c = 0; c < 8; ++c) {
        double dx = lin8d(c) - x0;   // c compile-time -> literal
        double d13, d42, w0, w1, w2;
        jdw_d(j, dx, dy, d13, d42, w0, w1, w2);
        float4 im = rowp[c];
        double ix = (double)im.x, iy2 = (double)im.y, iz = (double)im.z;
        den0 += w0; den1 += w1; den2 += w2;
        n00 += ix * w0; n01 += ix * w1; n02 += ix * w2;
        n10 += iy2 * w0; n11 += iy2 * w1; n12 += iy2 * w2;
        n20 += iz * w0; n21 += iz * w1; n22 += iz * w2;
        W00 += w0 * w0; W01 += w0 * w1; W02 += w0 * w2;
        W11 += w1 * w1; W12 += w1 * w2; W22 += w2 * w2;
      }
    }
    // combine halves (lane i <-> i+32); f64 add commutative -> identical
    den0 += __shfl_xor(den0, 32); den1 += __shfl_xor(den1, 32); den2 += __shfl_xor(den2, 32);
    n00 += __shfl_xor(n00, 32); n01 += __shfl_xor(n01, 32); n02 += __shfl_xor(n02, 32);
    n10 += __shfl_xor(n10, 32); n11 += __shfl_xor(n11, 32); n12 += __shfl_xor(n12, 32);
    n20 += __shfl_xor(n20, 32); n21 += __shfl_xor(n21, 32); n22 += __shfl_xor(n22, 32);
    W00 += __shfl_xor(W00, 32); W01 += __shfl_xor(W01, 32); W02 += __shfl_xor(W02, 32);
    W11 += __shfl_xor(W11, 32); W12 += __shfl_xor(W12, 32); W22 += __shfl_xor(W22, 32);

    double e0 = den0 + 1e-10, e1 = den1 + 1e-10, e2 = den2 + 1e-10;
    double c00 = n00 / e0, c01 = n01 / e1, c02 = n02 / e2;
    double c10 = n10 / e0, c11 = n11 / e1, c12 = n12 / e2;
    double c20 = n20 / e0, c21 = n21 / e1, c22 = n22 / e2;

    // expanded residual: loss + ssq = c^T W c - 2 c.n (ssq const -> argmin inv)
    double loss =
        c00 * (W00 * c00 + W01 * c01 + W02 * c02 - 2.0 * n00) +
        c01 * (W01 * c00 + W11 * c01 + W12 * c02 - 2.0 * n01) +
        c02 * (W02 * c00 + W12 * c01 + W22 * c02 - 2.0 * n02) +
        c10 * (W00 * c10 + W01 * c11 + W02 * c12 - 2.0 * n10) +
        c11 * (W01 * c10 + W11 * c11 + W12 * c12 - 2.0 * n11) +
        c12 * (W02 * c10 + W12 * c11 + W22 * c12 - 2.0 * n12) +
        c20 * (W00 * c20 + W01 * c21 + W02 * c22 - 2.0 * n20) +
        c21 * (W01 * c20 + W11 * c21 + W12 * c22 - 2.0 * n21) +
        c22 * (W02 * c20 + W12 * c21 + W22 * c22 - 2.0 * n22);

    // argmin over 31 candidates, first-index tie-break (np.argmin)
    double bl = (cand < 31) ? loss : (double)INFINITY;
    int bi = cand;
#pragma unroll
    for (int m = 1; m <= 16; m <<= 1) {
      double ol = __shfl_xor(bl, m);
      int oi = __shfl_xor(bi, m);
      if (ol < bl || (ol == bl && oi < bi)) { bl = ol; bi = oi; }
    }
    double upd = (i < 3) ? angd(bi) : xyd(bi);
    if (i == 0) q0 += upd;
    else if (i == 1) q1 += upd;
    else if (i == 2) q2 += upd;
    else if (i == 3) q3 += upd;
    else q4 += upd;
  }

  if (lane == 0) {
    pout[patch * 5 + 0] = q0;
    pout[patch * 5 + 1] = q1;
    pout[patch * 5 + 2] = q2;
    pout[patch * 5 + 3] = q3;
    pout[patch * 5 + 4] = q4;
  }
}

// ---------------- Kernel B: final reconstruction + fold (atomic) --------
__global__ void __launch_bounds__(256) foj_final(const float* __restrict__ x,
                                                 const double* __restrict__ pin,
                                                 float* __restrict__ out) {
  int lane = threadIdx.x & 63;
  int patch = blockIdx.x * 4 + (threadIdx.x >> 6);
  if (patch >= NPATCH) return;
  int ph = patch / WP_;
  int pw = patch - ph * WP_;
  double q0 = pin[patch * 5 + 0];
  double q1 = pin[patch * 5 + 1];
  double q2 = pin[patch * 5 + 2];
  double x0 = pin[patch * 5 + 3];
  double y0 = pin[patch * 5 + 4];

  JPd j = jprep_d(q0, q1, q2);
  int pi2 = lane >> 3, pj = lane & 7;
  double dx = lin8d(pj) - x0;
  double dy = lin8d(pi2) - y0;
  double d13, d42, w0, w1, w2;
  jdw_d(j, dx, dy, d13, d42, w0, w1, w2);

  int oy = ph * 4 + pi2, ox = pw * 4 + pj;
  double im0 = (double)x[oy * 256 + ox];
  double im1 = (double)x[65536 + oy * 256 + ox];
  double im2 = (double)x[131072 + oy * 256 + ox];

  double red[12] = {w0, w1, w2,
                    im0 * w0, im0 * w1, im0 * w2,
                    im1 * w0, im1 * w1, im1 * w2,
                    im2 * w0, im2 * w1, im2 * w2};
#pragma unroll
  for (int t = 0; t < 12; ++t) {
    double v = red[t];
#pragma unroll
    for (int m = 1; m <= 32; m <<= 1) v += __shfl_xor(v, m);
    red[t] = v;
  }
  double e0 = red[0] + 1e-10, e1 = red[1] + 1e-10, e2 = red[2] + 1e-10;
  double pv0 = w0 * (red[3] / e0) + w1 * (red[4] / e1) + w2 * (red[5] / e2);
  double pv1 = w0 * (red[6] / e0) + w1 * (red[7] / e1) + w2 * (red[8] / e2);
  double pv2 = w0 * (red[9] / e0) + w1 * (red[10] / e1) + w2 * (red[11] / e2);

  double minabs = (d13 < 0.0) ? -d13
                              : ((d42 < 0.0) ? fmin(d13, -d42) : fmin(d13, d42));
  double tb = minabs / 0.05;
  double bnd = 1.0 / (1.0 + tb * tb);

  atomicAdd(&out[oy * 256 + ox], (float)pv0);
  atomicAdd(&out[65536 + oy * 256 + ox], (float)pv1);
  atomicAdd(&out[131072 + oy * 256 + ox], (float)pv2);
  atomicAdd(&out[196608 + oy * 256 + ox], (float)bnd);
}

// ---------------- Kernel C: divide by num_patches -----------------------
__global__ void __launch_bounds__(256) foj_norm(float* __restrict__ out) {
  int idx = blockIdx.x * 256 + threadIdx.x;
  int y = idx >> 8, xx = idx & 255;
  int hlo = (y >= 4) ? ((y - 4) >> 2) : 0;
  int hhi = min(62, y >> 2);
  int wlo = (xx >= 4) ? ((xx - 4) >> 2) : 0;
  int whi = min(62, xx >> 2);
  float np_ = (float)((hhi - hlo + 1) * (whi - wlo + 1));
  out[idx] /= np_;
  out[65536 + idx] /= np_;
  out[131072 + idx] /= np_;
  out[196608 + idx] /= np_;
}

extern "C" void kernel_launch(void* const* d_in, const int* in_sizes, int n_in,
                              void* d_out, int out_size, void* d_ws, size_t ws_size,
                              hipStream_t stream) {
  const float* x = (const float*)d_in[0];
  float* out = (float*)d_out;
  double* pws = (double*)d_ws;  // 3969*5 doubles = ~159 KB scratch

  foj_descent<<<(NPATCH + 3) / 4, 256, 0, stream>>>(x, pws);
  hipMemsetAsync(d_out, 0, (size_t)out_size * sizeof(float), stream);
  foj_final<<<(NPATCH + 3) / 4, 256, 0, stream>>>(x, pws, out);
  foj_norm<<<256, 256, 0, stream>>>(out);
}

// Round 7
// 434.904 us; speedup vs baseline: 4.1341x; 4.1341x over previous
//
#include <hip/hip_runtime.h>
#include <math.h>

#define WP_ 63
#define NPATCH 3969
#define PI_D 3.141592653589793
#define TWO_PI_D 6.283185307179586476925287

// numpy remainder(v, 2pi): fmod then fix sign
__device__ __forceinline__ double remtp_d(double v) {
  double r = fmod(v, TWO_PI_D);
  if (r < 0.0) r += TWO_PI_D;
  return r;
}

// np.linspace(-1,1,8): y = i*step + start (two roundings), y[-1]=stop exact
__device__ __forceinline__ double lin8d(int i) {
  if (i == 7) return 1.0;
  return __dadd_rn(__dmul_rn((double)i, 2.0 / 7.0), -1.0);
}
// np.linspace(0,2pi,32)[:31]: i*step (+0.0 exact)
__device__ __forceinline__ double angd(int n) {
  return __dmul_rn((double)n, TWO_PI_D / 31.0);
}
// np.linspace(-3,3,31): i*0.2 + (-3), y[-1]=3 exact
__device__ __forceinline__ double xyd(int n) {
  if (n == 30) return 3.0;
  return __dadd_rn(__dmul_rn((double)n, 6.0 / 30.0), -3.0);
}

// x^35 LSB-first binary exponentiation (numpy npy_pow integer fast path)
__device__ __forceinline__ double pow35_d(double x) {
#pragma clang fp contract(off)
  double x2 = x * x;
  double r = x * x2;      // x^3
  double b = x2 * x2;     // x^4
  b = b * b;              // x^8
  b = b * b;              // x^16
  b = b * b;              // x^32
  return r * b;           // x^35
}

// fdlibm-style atan for x >= 0, branchless (select range reduction,
// one f64 divide, 11-term odd poly). |err| < ~1.5 ulp -> loss noise 1e-15.
__device__ __forceinline__ double atan_pos(double x) {
  bool c0 = x < 0.4375;
  bool c1 = x < 0.6875;
  bool c2 = x < 1.1875;
  bool c3 = x < 2.4375;
  double num = c0 ? x : c1 ? (2.0 * x - 1.0) : c2 ? (x - 1.0)
             : c3 ? (x - 1.5) : -1.0;
  double den = c0 ? 1.0 : c1 ? (2.0 + x) : c2 ? (x + 1.0)
             : c3 ? (1.0 + 1.5 * x) : x;
  double hi = c0 ? 0.0
            : c1 ? 4.63647609000806093515e-01
            : c2 ? 7.85398163397448278999e-01
            : c3 ? 9.82793723247329054082e-01
                 : 1.57079632679489655800e+00;
  double lo = c0 ? 0.0
            : c1 ? 2.26987774529616870924e-17
            : c2 ? 3.06161699786838301793e-17
            : c3 ? 1.39033110312309984516e-17
                 : 6.12323399573676603587e-17;
  double t = num / den;
  double z = t * t;
  double w = z * z;
  double s1 = z * (3.33333333333329318027e-01 +
              w * (1.42857142725034663711e-01 +
              w * (9.09088713343650656196e-02 +
              w * (6.66107313738753120669e-02 +
              w * (4.97687799461593236017e-02 +
              w *  1.62858201153657823623e-02)))));
  double s2 = w * (-1.99999999998764832476e-01 +
              w * (-1.11111104054623557880e-01 +
              w * (-7.69187620504482999495e-02 +
              w * (-5.83357013379057348645e-02 +
              w *  -3.65315727442169155270e-02))));
  return hi - ((t * (s1 + s2) - lo) - t);
}

// h = 0.5*(1 + (2/pi)*atan(d/0.01)); 1.0/0.01 rounds to exactly 100.0 in f64
__device__ __forceinline__ double hstep(double d) {
  double z = d * 100.0;
  double az = fabs(z);
  double a = atan_pos(az);
  a = (z < 0.0) ? -a : a;
  return 0.5 + 0.31830988618379067154 * a;  // 1/pi
}

struct JPd {
  double s1, c1, s2, c2, s3, c3, s4, c4;
  double sg13, sg42, gt13, gt42;
};

__device__ JPd jprep_d(double p0, double p1, double p2) {
#pragma clang fp contract(off)
  double r0 = remtp_d(p0), r1 = remtp_d(p1), r2 = remtp_d(p2);
  double mn = fmin(r0, r1), mx = fmax(r0, r1);
  double a1 = fmin(mn, r2);
  double a3 = fmax(mx, r2);
  double a2 = fmax(mn, fmin(mx, r2));  // exact 3-sort median
  double remm = remtp_d(0.5 * (a1 - a3));
  double a4 = 0.5 * (a1 + a3) + ((remm >= PI_D) ? PI_D : 0.0);
  JPd j;
  double r42 = remtp_d(a2 - a4);
  j.sg42 = (r42 < PI_D) ? 1.0 : -1.0;
  j.gt42 = pow35_d(r42 / PI_D - 1.0) * 0.1;
  double r13 = remtp_d(a3 - a1);
  j.sg13 = (r13 < PI_D) ? 1.0 : -1.0;
  j.gt13 = pow35_d(r13 / PI_D - 1.0) * 0.1;
  j.s1 = sin(a1); j.c1 = cos(a1);
  j.s2 = sin(a2); j.c2 = cos(a2);
  j.s3 = sin(a3); j.c3 = cos(a3);
  j.s4 = sin(a4); j.c4 = cos(a4);
  return j;
}

// distances + wedge weights (FMA contraction allowed: ~1ulp reordering,
// loss noise ~1e-15 -- same band as f64 transcendental noise; verified
// zero argmin flips in round 6)
__device__ __forceinline__ void jdw_d(const JPd& j, double dx, double dy,
                                      double& d13, double& d42,
                                      double& w0, double& w1, double& w2) {
  double hl1 = (-j.s1) * dx + j.c1 * dy;
  double hl2 = (-j.s2) * dx + j.c2 * dy;
  double hl3 = (-j.s3) * dx + j.c3 * dy;
  double hl4 = (-j.s4) * dx + j.c4 * dy;
  d13 = j.sg13 * fmin(j.sg13 * hl1, (-j.sg13) * hl3) + j.gt13;
  d42 = j.sg42 * fmin(j.sg42 * hl4, (-j.sg42) * hl2) + j.gt42;
  double h1 = hstep(d13);
  double h2 = hstep(d42);
  w0 = 1.0 - h1;
  w1 = h1 * (1.0 - h2);
  w2 = h1 * h2;
}

// ---------------- Kernel A: coordinate descent (float64, one-pass) -------
// 1 wave = 1 patch. lane = 32*pixel_half + candidate.
// NOTE: plain launch bounds. (256,4) forced RA below natural pressure and
// produced 5.3 GB of scratch spill traffic per dispatch (round 6).
__global__ void __launch_bounds__(256)
foj_descent(const float* __restrict__ x, double* __restrict__ pout) {
  const int tid = threadIdx.x;
  const int wv = tid >> 6;
  const int lane = tid & 63;
  const int hp = lane >> 5;     // pixel half (0: rows 0-3, 1: rows 4-7)
  const int cand = lane & 31;
  const int patch = blockIdx.x * 4 + wv;

  __shared__ float4 simg[4][64];
  if (patch < NPATCH) {
    int ph = patch / WP_;
    int pw = patch - ph * WP_;
    int py = lane >> 3, pxx = lane & 7;
    int base = (ph * 4 + py) * 256 + (pw * 4 + pxx);
    float4 v;
    v.x = x[base];
    v.y = x[65536 + base];
    v.z = x[131072 + base];
    v.w = 0.0f;
    simg[wv][lane] = v;
  }
  __syncthreads();
  if (patch >= NPATCH) return;
  const float4* sp = simg[wv];

  double q0 = 0.0, q1 = 0.0, q2 = 0.0, q3 = 0.0, q4 = 0.0;

#pragma unroll 1
  for (int i = 0; i < 5; ++i) {
    double rv = (i < 3) ? angd(cand) : xyd(cand);
    double p0 = q0 + ((i == 0) ? rv : 0.0);
    double p1 = q1 + ((i == 1) ? rv : 0.0);
    double p2 = q2 + ((i == 2) ? rv : 0.0);
    double x0 = q3 + ((i == 3) ? rv : 0.0);
    double y0 = q4 + ((i == 4) ? rv : 0.0);

    JPd j = jprep_d(p0, p1, p2);

    double den0 = 0, den1 = 0, den2 = 0;
    double n00 = 0, n01 = 0, n02 = 0, n10 = 0, n11 = 0, n12 = 0;
    double n20 = 0, n21 = 0, n22 = 0;
    double W00 = 0, W01 = 0, W02 = 0, W11 = 0, W12 = 0, W22 = 0;
#pragma unroll 1
    for (int r = 0; r < 4; ++r) {
      int iy = hp * 4 + r;
      double liny = (iy == 7) ? 1.0
                  : __dadd_rn(__dmul_rn((double)iy, 2.0 / 7.0), -1.0);
      double dy = liny - y0;
      const float4* rowp = sp + hp * 32 + r * 8;
#pragma unroll
      for (int c = 0; c < 8; ++c) {
        double dx = lin8d(c) - x0;   // c compile-time -> literal
        double d13, d42, w0, w1, w2;
        jdw_d(j, dx, dy, d13, d42, w0, w1, w2);
        float4 im = rowp[c];
        double ix = (double)im.x, iy2 = (double)im.y, iz = (double)im.z;
        den0 += w0; den1 += w1; den2 += w2;
        n00 += ix * w0; n01 += ix * w1; n02 += ix * w2;
        n10 += iy2 * w0; n11 += iy2 * w1; n12 += iy2 * w2;
        n20 += iz * w0; n21 += iz * w1; n22 += iz * w2;
        W00 += w0 * w0; W01 += w0 * w1; W02 += w0 * w2;
        W11 += w1 * w1; W12 += w1 * w2; W22 += w2 * w2;
      }
    }
    // combine halves (lane i <-> i+32); f64 add commutative -> identical
    den0 += __shfl_xor(den0, 32); den1 += __shfl_xor(den1, 32); den2 += __shfl_xor(den2, 32);
    n00 += __shfl_xor(n00, 32); n01 += __shfl_xor(n01, 32); n02 += __shfl_xor(n02, 32);
    n10 += __shfl_xor(n10, 32); n11 += __shfl_xor(n11, 32); n12 += __shfl_xor(n12, 32);
    n20 += __shfl_xor(n20, 32); n21 += __shfl_xor(n21, 32); n22 += __shfl_xor(n22, 32);
    W00 += __shfl_xor(W00, 32); W01 += __shfl_xor(W01, 32); W02 += __shfl_xor(W02, 32);
    W11 += __shfl_xor(W11, 32); W12 += __shfl_xor(W12, 32); W22 += __shfl_xor(W22, 32);

    double e0 = den0 + 1e-10, e1 = den1 + 1e-10, e2 = den2 + 1e-10;
    double c00 = n00 / e0, c01 = n01 / e1, c02 = n02 / e2;
    double c10 = n10 / e0, c11 = n11 / e1, c12 = n12 / e2;
    double c20 = n20 / e0, c21 = n21 / e1, c22 = n22 / e2;

    // expanded residual: loss + ssq = c^T W c - 2 c.n (ssq const -> argmin inv)
    double loss =
        c00 * (W00 * c00 + W01 * c01 + W02 * c02 - 2.0 * n00) +
        c01 * (W01 * c00 + W11 * c01 + W12 * c02 - 2.0 * n01) +
        c02 * (W02 * c00 + W12 * c01 + W22 * c02 - 2.0 * n02) +
        c10 * (W00 * c10 + W01 * c11 + W02 * c12 - 2.0 * n10) +
        c11 * (W01 * c10 + W11 * c11 + W12 * c12 - 2.0 * n11) +
        c12 * (W02 * c10 + W12 * c11 + W22 * c12 - 2.0 * n12) +
        c20 * (W00 * c20 + W01 * c21 + W02 * c22 - 2.0 * n20) +
        c21 * (W01 * c20 + W11 * c21 + W12 * c22 - 2.0 * n21) +
        c22 * (W02 * c20 + W12 * c21 + W22 * c22 - 2.0 * n22);

    // argmin over 31 candidates, first-index tie-break (np.argmin)
    double bl = (cand < 31) ? loss : (double)INFINITY;
    int bi = cand;
#pragma unroll
    for (int m = 1; m <= 16; m <<= 1) {
      double ol = __shfl_xor(bl, m);
      int oi = __shfl_xor(bi, m);
      if (ol < bl || (ol == bl && oi < bi)) { bl = ol; bi = oi; }
    }
    double upd = (i < 3) ? angd(bi) : xyd(bi);
    if (i == 0) q0 += upd;
    else if (i == 1) q1 += upd;
    else if (i == 2) q2 += upd;
    else if (i == 3) q3 += upd;
    else q4 += upd;
  }

  if (lane == 0) {
    pout[patch * 5 + 0] = q0;
    pout[patch * 5 + 1] = q1;
    pout[patch * 5 + 2] = q2;
    pout[patch * 5 + 3] = q3;
    pout[patch * 5 + 4] = q4;
  }
}

// ---------------- Kernel B: final reconstruction + fold (atomic) --------
__global__ void __launch_bounds__(256) foj_final(const float* __restrict__ x,
                                                 const double* __restrict__ pin,
                                                 float* __restrict__ out) {
  int lane = threadIdx.x & 63;
  int patch = blockIdx.x * 4 + (threadIdx.x >> 6);
  if (patch >= NPATCH) return;
  int ph = patch / WP_;
  int pw = patch - ph * WP_;
  double q0 = pin[patch * 5 + 0];
  double q1 = pin[patch * 5 + 1];
  double q2 = pin[patch * 5 + 2];
  double x0 = pin[patch * 5 + 3];
  double y0 = pin[patch * 5 + 4];

  JPd j = jprep_d(q0, q1, q2);
  int pi2 = lane >> 3, pj = lane & 7;
  double dx = lin8d(pj) - x0;
  double dy = lin8d(pi2) - y0;
  double d13, d42, w0, w1, w2;
  jdw_d(j, dx, dy, d13, d42, w0, w1, w2);

  int oy = ph * 4 + pi2, ox = pw * 4 + pj;
  double im0 = (double)x[oy * 256 + ox];
  double im1 = (double)x[65536 + oy * 256 + ox];
  double im2 = (double)x[131072 + oy * 256 + ox];

  double red[12] = {w0, w1, w2,
                    im0 * w0, im0 * w1, im0 * w2,
                    im1 * w0, im1 * w1, im1 * w2,
                    im2 * w0, im2 * w1, im2 * w2};
#pragma unroll
  for (int t = 0; t < 12; ++t) {
    double v = red[t];
#pragma unroll
    for (int m = 1; m <= 32; m <<= 1) v += __shfl_xor(v, m);
    red[t] = v;
  }
  double e0 = red[0] + 1e-10, e1 = red[1] + 1e-10, e2 = red[2] + 1e-10;
  double pv0 = w0 * (red[3] / e0) + w1 * (red[4] / e1) + w2 * (red[5] / e2);
  double pv1 = w0 * (red[6] / e0) + w1 * (red[7] / e1) + w2 * (red[8] / e2);
  double pv2 = w0 * (red[9] / e0) + w1 * (red[10] / e1) + w2 * (red[11] / e2);

  double minabs = (d13 < 0.0) ? -d13
                              : ((d42 < 0.0) ? fmin(d13, -d42) : fmin(d13, d42));
  double tb = minabs / 0.05;
  double bnd = 1.0 / (1.0 + tb * tb);

  atomicAdd(&out[oy * 256 + ox], (float)pv0);
  atomicAdd(&out[65536 + oy * 256 + ox], (float)pv1);
  atomicAdd(&out[131072 + oy * 256 + ox], (float)pv2);
  atomicAdd(&out[196608 + oy * 256 + ox], (float)bnd);
}

// ---------------- Kernel C: divide by num_patches -----------------------
__global__ void __launch_bounds__(256) foj_norm(float* __restrict__ out) {
  int idx = blockIdx.x * 256 + threadIdx.x;
  int y = idx >> 8, xx = idx & 255;
  int hlo = (y >= 4) ? ((y - 4) >> 2) : 0;
  int hhi = min(62, y >> 2);
  int wlo = (xx >= 4) ? ((xx - 4) >> 2) : 0;
  int whi = min(62, xx >> 2);
  float np_ = (float)((hhi - hlo + 1) * (whi - wlo + 1));
  out[idx] /= np_;
  out[65536 + idx] /= np_;
  out[131072 + idx] /= np_;
  out[196608 + idx] /= np_;
}

extern "C" void kernel_launch(void* const* d_in, const int* in_sizes, int n_in,
                              void* d_out, int out_size, void* d_ws, size_t ws_size,
                              hipStream_t stream) {
  const float* x = (const float*)d_in[0];
  float* out = (float*)d_out;
  double* pws = (double*)d_ws;  // 3969*5 doubles = ~159 KB scratch

  foj_descent<<<(NPATCH + 3) / 4, 256, 0, stream>>>(x, pws);
  hipMemsetAsync(d_out, 0, (size_t)out_size * sizeof(float), stream);
  foj_final<<<(NPATCH + 3) / 4, 256, 0, stream>>>(x, pws, out);
  foj_norm<<<256, 256, 0, stream>>>(out);
}

// Round 8
// 185.720 us; speedup vs baseline: 9.6809x; 2.3417x over previous
//
#include <hip/hip_runtime.h>
#include <math.h>

#define WP_ 63
#define NPATCH 3969
#define PI_D 3.141592653589793
#define TWO_PI_D 6.283185307179586476925287

// numpy remainder(v, 2pi): fmod then fix sign
__device__ __forceinline__ double remtp_d(double v) {
  double r = fmod(v, TWO_PI_D);
  if (r < 0.0) r += TWO_PI_D;
  return r;
}

// np.linspace(-1,1,8): y = i*step + start (two roundings), y[-1]=stop exact
__device__ __forceinline__ double lin8d(int i) {
  if (i == 7) return 1.0;
  return __dadd_rn(__dmul_rn((double)i, 2.0 / 7.0), -1.0);
}
// np.linspace(0,2pi,32)[:31]: i*step (+0.0 exact)
__device__ __forceinline__ double angd(int n) {
  return __dmul_rn((double)n, TWO_PI_D / 31.0);
}
// np.linspace(-3,3,31): i*0.2 + (-3), y[-1]=3 exact
__device__ __forceinline__ double xyd(int n) {
  if (n == 30) return 3.0;
  return __dadd_rn(__dmul_rn((double)n, 6.0 / 30.0), -3.0);
}

// x^35 LSB-first binary exponentiation (numpy npy_pow integer fast path)
__device__ __forceinline__ double pow35_d(double x) {
#pragma clang fp contract(off)
  double x2 = x * x;
  double r = x * x2;      // x^3
  double b = x2 * x2;     // x^4
  b = b * b;              // x^8
  b = b * b;              // x^16
  b = b * b;              // x^32
  return r * b;           // x^35
}

// ---------- table-based atan for hstep (descent kernel only) ------------
// atan(u) = atan(c) + atan((u-c)/(1+u*c)), c from 57-entry LDS table
// indexed by exponent+top-2-mantissa bits of u. |t| <= 0.0625 -> 7-term
// Taylor, poly err ~1e-19; total ~1 ulp (same class as ocml, proven r4-r7).
#define TABN 57
__device__ __forceinline__ void build_atan_tab(double2* tab) {
  int k = threadIdx.x;
  if (k < 56) {
    // bin k covers u with ((hibits>>18) - 4076) == k; c = bin midpoint
    int hi = ((4076 + k) << 18) | (1 << 17);
    double c = __hiloint2double(hi, 0);
    tab[k] = double2{c, atan(c)};   // ocml atan, once per block
  } else if (k == 56) {
    tab[56] = double2{0.0, 0.0};    // small-|u| bin: c = 0
  }
}

__device__ __forceinline__ double hstep_tab(const double2* __restrict__ tab,
                                            double d) {
  double z = d * 100.0;             // 1.0/0.01 == 100.0 exactly in f64
  double u = fabs(z);
  int hi = __double2hiint(u);
  int idx = (hi >> 18) - 4076;
  idx = (idx < 0) ? 56 : ((idx > 55) ? 55 : idx);
  double2 e = tab[idx];
  double den = fma(u, e.x, 1.0);
  double t = (u - e.x) / den;       // IEEE div: correctly rounded
  double z2 = t * t;
  double p = 1.0 / 13.0;
  p = fma(z2, p, -1.0 / 11.0);
  p = fma(z2, p, 1.0 / 9.0);
  p = fma(z2, p, -1.0 / 7.0);
  p = fma(z2, p, 1.0 / 5.0);
  p = fma(z2, p, -1.0 / 3.0);
  p = fma(z2, p, 1.0);
  double a = fma(t, p, e.y);        // atan(u) >= 0
  a = copysign(a, z);
  return fma(a, 0.31830988618379067154, 0.5);  // 0.5 + a/pi
}

struct JPd {
  double s1, c1, s2, c2, s3, c3, s4, c4;
  double sg13, sg42, gt13, gt42;
};

__device__ JPd jprep_d(double p0, double p1, double p2) {
#pragma clang fp contract(off)
  double r0 = remtp_d(p0), r1 = remtp_d(p1), r2 = remtp_d(p2);
  double mn = fmin(r0, r1), mx = fmax(r0, r1);
  double a1 = fmin(mn, r2);
  double a3 = fmax(mx, r2);
  double a2 = fmax(mn, fmin(mx, r2));  // exact 3-sort median
  double remm = remtp_d(0.5 * (a1 - a3));
  double a4 = 0.5 * (a1 + a3) + ((remm >= PI_D) ? PI_D : 0.0);
  JPd j;
  double r42 = remtp_d(a2 - a4);
  j.sg42 = (r42 < PI_D) ? 1.0 : -1.0;
  j.gt42 = pow35_d(r42 / PI_D - 1.0) * 0.1;
  double r13 = remtp_d(a3 - a1);
  j.sg13 = (r13 < PI_D) ? 1.0 : -1.0;
  j.gt13 = pow35_d(r13 / PI_D - 1.0) * 0.1;
  sincos(a1, &j.s1, &j.c1);
  sincos(a2, &j.s2, &j.c2);
  sincos(a3, &j.s3, &j.c3);
  sincos(a4, &j.s4, &j.c4);
  return j;
}

// distances only (shared by both hstep flavors)
__device__ __forceinline__ void jdist_d(const JPd& j, double dx, double dy,
                                        double& d13, double& d42) {
  double hl1 = (-j.s1) * dx + j.c1 * dy;
  double hl2 = (-j.s2) * dx + j.c2 * dy;
  double hl3 = (-j.s3) * dx + j.c3 * dy;
  double hl4 = (-j.s4) * dx + j.c4 * dy;
  d13 = j.sg13 * fmin(j.sg13 * hl1, (-j.sg13) * hl3) + j.gt13;
  d42 = j.sg42 * fmin(j.sg42 * hl4, (-j.sg42) * hl2) + j.gt42;
}

// ---------------- Kernel A: coordinate descent (float64, one-pass) -------
// 1 wave = 1 patch. lane = 32*pixel_half + candidate.
__global__ void __launch_bounds__(256)
foj_descent(const float* __restrict__ x, double* __restrict__ pout) {
  const int tid = threadIdx.x;
  const int wv = tid >> 6;
  const int lane = tid & 63;
  const int hp = lane >> 5;     // pixel half (0: rows 0-3, 1: rows 4-7)
  const int cand = lane & 31;
  const int patch = blockIdx.x * 4 + wv;

  __shared__ double2 stab[TABN];
  __shared__ float4 simg[4][64];
  build_atan_tab(stab);
  if (patch < NPATCH) {
    int ph = patch / WP_;
    int pw = patch - ph * WP_;
    int py = lane >> 3, pxx = lane & 7;
    int base = (ph * 4 + py) * 256 + (pw * 4 + pxx);
    float4 v;
    v.x = x[base];
    v.y = x[65536 + base];
    v.z = x[131072 + base];
    v.w = 0.0f;
    simg[wv][lane] = v;
  }
  __syncthreads();
  if (patch >= NPATCH) return;
  const float4* sp = simg[wv];

  double q0 = 0.0, q1 = 0.0, q2 = 0.0, q3 = 0.0, q4 = 0.0;

#pragma unroll 1
  for (int i = 0; i < 5; ++i) {
    double rv = (i < 3) ? angd(cand) : xyd(cand);
    double p0 = q0 + ((i == 0) ? rv : 0.0);
    double p1 = q1 + ((i == 1) ? rv : 0.0);
    double p2 = q2 + ((i == 2) ? rv : 0.0);
    double x0 = q3 + ((i == 3) ? rv : 0.0);
    double y0 = q4 + ((i == 4) ? rv : 0.0);

    JPd j = jprep_d(p0, p1, p2);

    double den0 = 0, den1 = 0, den2 = 0;
    double n00 = 0, n01 = 0, n02 = 0, n10 = 0, n11 = 0, n12 = 0;
    double n20 = 0, n21 = 0, n22 = 0;
    double W00 = 0, W01 = 0, W02 = 0, W11 = 0, W12 = 0, W22 = 0;
#pragma unroll 1
    for (int r = 0; r < 4; ++r) {
      int iy = hp * 4 + r;
      double liny = (iy == 7) ? 1.0
                  : __dadd_rn(__dmul_rn((double)iy, 2.0 / 7.0), -1.0);
      double dy = liny - y0;
      const float4* rowp = sp + hp * 32 + r * 8;
#pragma unroll
      for (int c = 0; c < 8; ++c) {
        double dx = lin8d(c) - x0;   // c compile-time -> literal
        double d13, d42;
        jdist_d(j, dx, dy, d13, d42);
        double h1 = hstep_tab(stab, d13);
        double h2 = hstep_tab(stab, d42);
        double w0 = 1.0 - h1;
        double w1 = h1 * (1.0 - h2);
        double w2 = h1 * h2;
        float4 im = rowp[c];
        double ix = (double)im.x, iy2 = (double)im.y, iz = (double)im.z;
        den0 += w0; den1 += w1; den2 += w2;
        n00 += ix * w0; n01 += ix * w1; n02 += ix * w2;
        n10 += iy2 * w0; n11 += iy2 * w1; n12 += iy2 * w2;
        n20 += iz * w0; n21 += iz * w1; n22 += iz * w2;
        W00 += w0 * w0; W01 += w0 * w1; W02 += w0 * w2;
        W11 += w1 * w1; W12 += w1 * w2; W22 += w2 * w2;
      }
    }
    // combine halves (lane i <-> i+32); f64 add commutative -> identical
    den0 += __shfl_xor(den0, 32); den1 += __shfl_xor(den1, 32); den2 += __shfl_xor(den2, 32);
    n00 += __shfl_xor(n00, 32); n01 += __shfl_xor(n01, 32); n02 += __shfl_xor(n02, 32);
    n10 += __shfl_xor(n10, 32); n11 += __shfl_xor(n11, 32); n12 += __shfl_xor(n12, 32);
    n20 += __shfl_xor(n20, 32); n21 += __shfl_xor(n21, 32); n22 += __shfl_xor(n22, 32);
    W00 += __shfl_xor(W00, 32); W01 += __shfl_xor(W01, 32); W02 += __shfl_xor(W02, 32);
    W11 += __shfl_xor(W11, 32); W12 += __shfl_xor(W12, 32); W22 += __shfl_xor(W22, 32);

    double e0 = den0 + 1e-10, e1 = den1 + 1e-10, e2 = den2 + 1e-10;
    double c00 = n00 / e0, c01 = n01 / e1, c02 = n02 / e2;
    double c10 = n10 / e0, c11 = n11 / e1, c12 = n12 / e2;
    double c20 = n20 / e0, c21 = n21 / e1, c22 = n22 / e2;

    // expanded residual: loss + ssq = c^T W c - 2 c.n (ssq const -> argmin inv)
    double loss =
        c00 * (W00 * c00 + W01 * c01 + W02 * c02 - 2.0 * n00) +
        c01 * (W01 * c00 + W11 * c01 + W12 * c02 - 2.0 * n01) +
        c02 * (W02 * c00 + W12 * c01 + W22 * c02 - 2.0 * n02) +
        c10 * (W00 * c10 + W01 * c11 + W02 * c12 - 2.0 * n10) +
        c11 * (W01 * c10 + W11 * c11 + W12 * c12 - 2.0 * n11) +
        c12 * (W02 * c10 + W12 * c11 + W22 * c12 - 2.0 * n12) +
        c20 * (W00 * c20 + W01 * c21 + W02 * c22 - 2.0 * n20) +
        c21 * (W01 * c20 + W11 * c21 + W12 * c22 - 2.0 * n21) +
        c22 * (W02 * c20 + W12 * c21 + W22 * c22 - 2.0 * n22);

    // argmin over 31 candidates, first-index tie-break (np.argmin)
    double bl = (cand < 31) ? loss : (double)INFINITY;
    int bi = cand;
#pragma unroll
    for (int m = 1; m <= 16; m <<= 1) {
      double ol = __shfl_xor(bl, m);
      int oi = __shfl_xor(bi, m);
      if (ol < bl || (ol == bl && oi < bi)) { bl = ol; bi = oi; }
    }
    double upd = (i < 3) ? angd(bi) : xyd(bi);
    if (i == 0) q0 += upd;
    else if (i == 1) q1 += upd;
    else if (i == 2) q2 += upd;
    else if (i == 3) q3 += upd;
    else q4 += upd;
  }

  if (lane == 0) {
    pout[patch * 5 + 0] = q0;
    pout[patch * 5 + 1] = q1;
    pout[patch * 5 + 2] = q2;
    pout[patch * 5 + 3] = q3;
    pout[patch * 5 + 4] = q4;
  }
}

// ---------------- Kernel B: final reconstruction + fold (atomic) --------
__global__ void __launch_bounds__(256) foj_final(const float* __restrict__ x,
                                                 const double* __restrict__ pin,
                                                 float* __restrict__ out) {
  int lane = threadIdx.x & 63;
  int patch = blockIdx.x * 4 + (threadIdx.x >> 6);
  if (patch >= NPATCH) return;
  int ph = patch / WP_;
  int pw = patch - ph * WP_;
  double q0 = pin[patch * 5 + 0];
  double q1 = pin[patch * 5 + 1];
  double q2 = pin[patch * 5 + 2];
  double x0 = pin[patch * 5 + 3];
  double y0 = pin[patch * 5 + 4];

  JPd j = jprep_d(q0, q1, q2);
  int pi2 = lane >> 3, pj = lane & 7;
  double dx = lin8d(pj) - x0;
  double dy = lin8d(pi2) - y0;
  double d13, d42;
  jdist_d(j, dx, dy, d13, d42);
  double h1 = 0.5 + 0.31830988618379067154 * atan(d13 * 100.0);  // ocml
  double h2 = 0.5 + 0.31830988618379067154 * atan(d42 * 100.0);
  double w0 = 1.0 - h1;
  double w1 = h1 * (1.0 - h2);
  double w2 = h1 * h2;

  int oy = ph * 4 + pi2, ox = pw * 4 + pj;
  double im0 = (double)x[oy * 256 + ox];
  double im1 = (double)x[65536 + oy * 256 + ox];
  double im2 = (double)x[131072 + oy * 256 + ox];

  double red[12] = {w0, w1, w2,
                    im0 * w0, im0 * w1, im0 * w2,
                    im1 * w0, im1 * w1, im1 * w2,
                    im2 * w0, im2 * w1, im2 * w2};
#pragma unroll
  for (int t = 0; t < 12; ++t) {
    double v = red[t];
#pragma unroll
    for (int m = 1; m <= 32; m <<= 1) v += __shfl_xor(v, m);
    red[t] = v;
  }
  double e0 = red[0] + 1e-10, e1 = red[1] + 1e-10, e2 = red[2] + 1e-10;
  double pv0 = w0 * (red[3] / e0) + w1 * (red[4] / e1) + w2 * (red[5] / e2);
  double pv1 = w0 * (red[6] / e0) + w1 * (red[7] / e1) + w2 * (red[8] / e2);
  double pv2 = w0 * (red[9] / e0) + w1 * (red[10] / e1) + w2 * (red[11] / e2);

  double minabs = (d13 < 0.0) ? -d13
                              : ((d42 < 0.0) ? fmin(d13, -d42) : fmin(d13, d42));
  double tb = minabs / 0.05;
  double bnd = 1.0 / (1.0 + tb * tb);

  atomicAdd(&out[oy * 256 + ox], (float)pv0);
  atomicAdd(&out[65536 + oy * 256 + ox], (float)pv1);
  atomicAdd(&out[131072 + oy * 256 + ox], (float)pv2);
  atomicAdd(&out[196608 + oy * 256 + ox], (float)bnd);
}

// ---------------- Kernel C: divide by num_patches -----------------------
__global__ void __launch_bounds__(256) foj_norm(float* __restrict__ out) {
  int idx = blockIdx.x * 256 + threadIdx.x;
  int y = idx >> 8, xx = idx & 255;
  int hlo = (y >= 4) ? ((y - 4) >> 2) : 0;
  int hhi = min(62, y >> 2);
  int wlo = (xx >= 4) ? ((xx - 4) >> 2) : 0;
  int whi = min(62, xx >> 2);
  float np_ = (float)((hhi - hlo + 1) * (whi - wlo + 1));
  out[idx] /= np_;
  out[65536 + idx] /= np_;
  out[131072 + idx] /= np_;
  out[196608 + idx] /= np_;
}

extern "C" void kernel_launch(void* const* d_in, const int* in_sizes, int n_in,
                              void* d_out, int out_size, void* d_ws, size_t ws_size,
                              hipStream_t stream) {
  const float* x = (const float*)d_in[0];
  float* out = (float*)d_out;
  double* pws = (double*)d_ws;  // 3969*5 doubles = ~159 KB scratch

  foj_descent<<<(NPATCH + 3) / 4, 256, 0, stream>>>(x, pws);
  hipMemsetAsync(d_out, 0, (size_t)out_size * sizeof(float), stream);
  foj_final<<<(NPATCH + 3) / 4, 256, 0, stream>>>(x, pws, out);
  foj_norm<<<256, 256, 0, stream>>>(out);
}

// Round 9
// 161.030 us; speedup vs baseline: 11.1652x; 1.1533x over previous
//
#include <hip/hip_runtime.h>
#include <math.h>

#define WP_ 63
#define NPATCH 3969
#define PI_D 3.141592653589793
#define TWO_PI_D 6.283185307179586476925287

// numpy remainder(v, 2pi): fmod then fix sign
__device__ __forceinline__ double remtp_d(double v) {
  double r = fmod(v, TWO_PI_D);
  if (r < 0.0) r += TWO_PI_D;
  return r;
}

// np.linspace(-1,1,8): y = i*step + start (two roundings), y[-1]=stop exact
__device__ __forceinline__ double lin8d(int i) {
  if (i == 7) return 1.0;
  return __dadd_rn(__dmul_rn((double)i, 2.0 / 7.0), -1.0);
}
// np.linspace(0,2pi,32)[:31]: i*step (+0.0 exact)
__device__ __forceinline__ double angd(int n) {
  return __dmul_rn((double)n, TWO_PI_D / 31.0);
}
// np.linspace(-3,3,31): i*0.2 + (-3), y[-1]=3 exact
__device__ __forceinline__ double xyd(int n) {
  if (n == 30) return 3.0;
  return __dadd_rn(__dmul_rn((double)n, 6.0 / 30.0), -3.0);
}

// x^35 LSB-first binary exponentiation (numpy npy_pow integer fast path)
__device__ __forceinline__ double pow35_d(double x) {
#pragma clang fp contract(off)
  double x2 = x * x;
  double r = x * x2;      // x^3
  double b = x2 * x2;     // x^4
  b = b * b;              // x^8
  b = b * b;              // x^16
  b = b * b;              // x^32
  return r * b;           // x^35
}

// v_rcp_f64 + 2 Newton iterations: err ~<0.5 ulp for d in [1, 8]
__device__ __forceinline__ double rcp_nr(double d) {
  double r;
  asm("v_rcp_f64 %0, %1" : "=v"(r) : "v"(d));
  r = fma(fma(-d, r, 1.0), r, r);
  r = fma(fma(-d, r, 1.0), r, r);
  return r;
}

// ---------- table-based atan for hstep (descent kernel only) ------------
// atan(u) = atan(c) + atan((u-c)/(1+u*c)), c from 57-entry LDS table
// indexed by exponent+top-2-mantissa bits of u. |t| <= 0.0625 -> 7-term
// Taylor; total ~1 ulp (band proven passing r4-r8).
#define TABN 57
__device__ __forceinline__ void build_atan_tab(double2* tab) {
  int k = threadIdx.x;
  if (k < 56) {
    int hi = ((4076 + k) << 18) | (1 << 17);
    double c = __hiloint2double(hi, 0);
    tab[k] = double2{c, atan(c)};   // ocml atan, once per block
  } else if (k == 56) {
    tab[56] = double2{0.0, 0.0};    // small-|u| bin: c = 0
  }
}

// two hsteps together (independent chains interleave for the scheduler);
// division replaced by rcp_nr
__device__ __forceinline__ void hstep2_tab(const double2* __restrict__ tab,
                                           double da, double db,
                                           double& ha, double& hb) {
  double za = da * 100.0, zb = db * 100.0;  // 1.0/0.01 == 100.0 exactly
  double ua = fabs(za), ub = fabs(zb);
  int ia = (__double2hiint(ua) >> 18) - 4076;
  int ib = (__double2hiint(ub) >> 18) - 4076;
  ia = (ia < 0) ? 56 : ((ia > 55) ? 55 : ia);
  ib = (ib < 0) ? 56 : ((ib > 55) ? 55 : ib);
  double2 ea = tab[ia];
  double2 eb = tab[ib];
  double ta = (ua - ea.x) * rcp_nr(fma(ua, ea.x, 1.0));
  double tb = (ub - eb.x) * rcp_nr(fma(ub, eb.x, 1.0));
  double z2a = ta * ta, z2b = tb * tb;
  double pa = 1.0 / 13.0, pb = 1.0 / 13.0;
  pa = fma(z2a, pa, -1.0 / 11.0); pb = fma(z2b, pb, -1.0 / 11.0);
  pa = fma(z2a, pa, 1.0 / 9.0);   pb = fma(z2b, pb, 1.0 / 9.0);
  pa = fma(z2a, pa, -1.0 / 7.0);  pb = fma(z2b, pb, -1.0 / 7.0);
  pa = fma(z2a, pa, 1.0 / 5.0);   pb = fma(z2b, pb, 1.0 / 5.0);
  pa = fma(z2a, pa, -1.0 / 3.0);  pb = fma(z2b, pb, -1.0 / 3.0);
  pa = fma(z2a, pa, 1.0);         pb = fma(z2b, pb, 1.0);
  double aa = fma(ta, pa, ea.y);
  double ab = fma(tb, pb, eb.y);
  aa = copysign(aa, za);
  ab = copysign(ab, zb);
  ha = fma(aa, 0.31830988618379067154, 0.5);
  hb = fma(ab, 0.31830988618379067154, 0.5);
}

struct JPd {
  double s1, c1, s2, c2, s3, c3, s4, c4;
  double sg13, sg42, gt13, gt42;
};

__device__ JPd jprep_d(double p0, double p1, double p2) {
#pragma clang fp contract(off)
  double r0 = remtp_d(p0), r1 = remtp_d(p1), r2 = remtp_d(p2);
  double mn = fmin(r0, r1), mx = fmax(r0, r1);
  double a1 = fmin(mn, r2);
  double a3 = fmax(mx, r2);
  double a2 = fmax(mn, fmin(mx, r2));  // exact 3-sort median
  double remm = remtp_d(0.5 * (a1 - a3));
  double a4 = 0.5 * (a1 + a3) + ((remm >= PI_D) ? PI_D : 0.0);
  JPd j;
  double r42 = remtp_d(a2 - a4);
  j.sg42 = (r42 < PI_D) ? 1.0 : -1.0;
  j.gt42 = pow35_d(r42 / PI_D - 1.0) * 0.1;
  double r13 = remtp_d(a3 - a1);
  j.sg13 = (r13 < PI_D) ? 1.0 : -1.0;
  j.gt13 = pow35_d(r13 / PI_D - 1.0) * 0.1;
  sincos(a1, &j.s1, &j.c1);
  sincos(a2, &j.s2, &j.c2);
  sincos(a3, &j.s3, &j.c3);
  sincos(a4, &j.s4, &j.c4);
  return j;
}

// distances only
__device__ __forceinline__ void jdist_d(const JPd& j, double dx, double dy,
                                        double& d13, double& d42) {
  double hl1 = (-j.s1) * dx + j.c1 * dy;
  double hl2 = (-j.s2) * dx + j.c2 * dy;
  double hl3 = (-j.s3) * dx + j.c3 * dy;
  double hl4 = (-j.s4) * dx + j.c4 * dy;
  d13 = j.sg13 * fmin(j.sg13 * hl1, (-j.sg13) * hl3) + j.gt13;
  d42 = j.sg42 * fmin(j.sg42 * hl4, (-j.sg42) * hl2) + j.gt42;
}

// ---------------- Kernel A: coordinate descent (float64, one-pass) -------
// 1 wave = 1 patch. lane = 32*pixel_half + candidate. 12 accumulators;
// n*2 / W02 / W12 / W22 derived from sum identities (dev ~1e-14 << gaps).
__global__ void __launch_bounds__(256)
foj_descent(const float* __restrict__ x, double* __restrict__ pout) {
  const int tid = threadIdx.x;
  const int wv = tid >> 6;
  const int lane = tid & 63;
  const int hp = lane >> 5;     // pixel half (0: rows 0-3, 1: rows 4-7)
  const int cand = lane & 31;
  const int patch = blockIdx.x * 4 + wv;

  __shared__ double2 stab[TABN];
  __shared__ float4 simg[4][64];
  build_atan_tab(stab);
  if (patch < NPATCH) {
    int ph = patch / WP_;
    int pw = patch - ph * WP_;
    int py = lane >> 3, pxx = lane & 7;
    int base = (ph * 4 + py) * 256 + (pw * 4 + pxx);
    float4 v;
    v.x = x[base];
    v.y = x[65536 + base];
    v.z = x[131072 + base];
    v.w = 0.0f;
    simg[wv][lane] = v;
  }
  __syncthreads();
  if (patch >= NPATCH) return;
  const float4* sp = simg[wv];

  // per-patch channel sums (once): sx_c = sum over all 64 px
  double sx0 = 0.0, sx1 = 0.0, sx2 = 0.0;
  {
    const float4* hbase = sp + hp * 32;
#pragma unroll
    for (int t = 0; t < 32; ++t) {
      float4 im = hbase[t];
      sx0 += (double)im.x; sx1 += (double)im.y; sx2 += (double)im.z;
    }
    sx0 += __shfl_xor(sx0, 32);
    sx1 += __shfl_xor(sx1, 32);
    sx2 += __shfl_xor(sx2, 32);
  }

  double q0 = 0.0, q1 = 0.0, q2 = 0.0, q3 = 0.0, q4 = 0.0;

#pragma unroll 1
  for (int i = 0; i < 5; ++i) {
    double rv = (i < 3) ? angd(cand) : xyd(cand);
    double p0 = q0 + ((i == 0) ? rv : 0.0);
    double p1 = q1 + ((i == 1) ? rv : 0.0);
    double p2 = q2 + ((i == 2) ? rv : 0.0);
    double x0 = q3 + ((i == 3) ? rv : 0.0);
    double y0 = q4 + ((i == 4) ? rv : 0.0);

    JPd j = jprep_d(p0, p1, p2);

    double den0 = 0, den1 = 0, den2 = 0;
    double n00 = 0, n01 = 0, n10 = 0, n11 = 0, n20 = 0, n21 = 0;
    double W00 = 0, W01 = 0, W11 = 0;
#pragma unroll 1
    for (int r = 0; r < 4; ++r) {
      int iy = hp * 4 + r;
      double liny = (iy == 7) ? 1.0
                  : __dadd_rn(__dmul_rn((double)iy, 2.0 / 7.0), -1.0);
      double dy = liny - y0;
      const float4* rowp = sp + hp * 32 + r * 8;
#pragma unroll
      for (int c = 0; c < 8; ++c) {
        double dx = lin8d(c) - x0;
        double d13, d42;
        jdist_d(j, dx, dy, d13, d42);
        double h1, h2;
        hstep2_tab(stab, d13, d42, h1, h2);
        double w0 = 1.0 - h1;
        double w1 = h1 * (1.0 - h2);
        double w2 = h1 * h2;
        float4 im = rowp[c];
        double ix = (double)im.x, iy2 = (double)im.y, iz = (double)im.z;
        den0 += w0; den1 += w1; den2 += w2;
        n00 += ix * w0; n01 += ix * w1;
        n10 += iy2 * w0; n11 += iy2 * w1;
        n20 += iz * w0; n21 += iz * w1;
        W00 += w0 * w0; W01 += w0 * w1; W11 += w1 * w1;
      }
    }
    // combine halves (lane i <-> i+32)
    den0 += __shfl_xor(den0, 32); den1 += __shfl_xor(den1, 32); den2 += __shfl_xor(den2, 32);
    n00 += __shfl_xor(n00, 32); n01 += __shfl_xor(n01, 32);
    n10 += __shfl_xor(n10, 32); n11 += __shfl_xor(n11, 32);
    n20 += __shfl_xor(n20, 32); n21 += __shfl_xor(n21, 32);
    W00 += __shfl_xor(W00, 32); W01 += __shfl_xor(W01, 32); W11 += __shfl_xor(W11, 32);

    // derived third columns (sum identities; dev ~1e-14 absolute)
    double n02 = sx0 - n00 - n01;
    double n12 = sx1 - n10 - n11;
    double n22 = sx2 - n20 - n21;
    double W02 = den0 - W00 - W01;
    double W12 = den1 - W01 - W11;
    double W22 = den2 - W02 - W12;

    double r0 = rcp_nr(den0 + 1e-10);
    double r1 = rcp_nr(den1 + 1e-10);
    double r2 = rcp_nr(den2 + 1e-10);
    double c00 = n00 * r0, c01 = n01 * r1, c02 = n02 * r2;
    double c10 = n10 * r0, c11 = n11 * r1, c12 = n12 * r2;
    double c20 = n20 * r0, c21 = n21 * r1, c22 = n22 * r2;

    // expanded residual: loss + ssq = c^T W c - 2 c.n (ssq const -> argmin inv)
    double loss =
        c00 * (W00 * c00 + W01 * c01 + W02 * c02 - 2.0 * n00) +
        c01 * (W01 * c00 + W11 * c01 + W12 * c02 - 2.0 * n01) +
        c02 * (W02 * c00 + W12 * c01 + W22 * c02 - 2.0 * n02) +
        c10 * (W00 * c10 + W01 * c11 + W02 * c12 - 2.0 * n10) +
        c11 * (W01 * c10 + W11 * c11 + W12 * c12 - 2.0 * n11) +
        c12 * (W02 * c10 + W12 * c11 + W22 * c12 - 2.0 * n12) +
        c20 * (W00 * c20 + W01 * c21 + W02 * c22 - 2.0 * n20) +
        c21 * (W01 * c20 + W11 * c21 + W12 * c22 - 2.0 * n21) +
        c22 * (W02 * c20 + W12 * c21 + W22 * c22 - 2.0 * n22);

    // argmin over 31 candidates, first-index tie-break (np.argmin)
    double bl = (cand < 31) ? loss : (double)INFINITY;
    int bi = cand;
#pragma unroll
    for (int m = 1; m <= 16; m <<= 1) {
      double ol = __shfl_xor(bl, m);
      int oi = __shfl_xor(bi, m);
      if (ol < bl || (ol == bl && oi < bi)) { bl = ol; bi = oi; }
    }
    double upd = (i < 3) ? angd(bi) : xyd(bi);
    if (i == 0) q0 += upd;
    else if (i == 1) q1 += upd;
    else if (i == 2) q2 += upd;
    else if (i == 3) q3 += upd;
    else q4 += upd;
  }

  if (lane == 0) {
    pout[patch * 5 + 0] = q0;
    pout[patch * 5 + 1] = q1;
    pout[patch * 5 + 2] = q2;
    pout[patch * 5 + 3] = q3;
    pout[patch * 5 + 4] = q4;
  }
}

// ---------------- Kernel B: final reconstruction + fold (atomic) --------
__global__ void __launch_bounds__(256) foj_final(const float* __restrict__ x,
                                                 const double* __restrict__ pin,
                                                 float* __restrict__ out) {
  int lane = threadIdx.x & 63;
  int patch = blockIdx.x * 4 + (threadIdx.x >> 6);
  if (patch >= NPATCH) return;
  int ph = patch / WP_;
  int pw = patch - ph * WP_;
  double q0 = pin[patch * 5 + 0];
  double q1 = pin[patch * 5 + 1];
  double q2 = pin[patch * 5 + 2];
  double x0 = pin[patch * 5 + 3];
  double y0 = pin[patch * 5 + 4];

  JPd j = jprep_d(q0, q1, q2);
  int pi2 = lane >> 3, pj = lane & 7;
  double dx = lin8d(pj) - x0;
  double dy = lin8d(pi2) - y0;
  double d13, d42;
  jdist_d(j, dx, dy, d13, d42);
  double h1 = 0.5 + 0.31830988618379067154 * atan(d13 * 100.0);  // ocml
  double h2 = 0.5 + 0.31830988618379067154 * atan(d42 * 100.0);
  double w0 = 1.0 - h1;
  double w1 = h1 * (1.0 - h2);
  double w2 = h1 * h2;

  int oy = ph * 4 + pi2, ox = pw * 4 + pj;
  double im0 = (double)x[oy * 256 + ox];
  double im1 = (double)x[65536 + oy * 256 + ox];
  double im2 = (double)x[131072 + oy * 256 + ox];

  double red[12] = {w0, w1, w2,
                    im0 * w0, im0 * w1, im0 * w2,
                    im1 * w0, im1 * w1, im1 * w2,
                    im2 * w0, im2 * w1, im2 * w2};
#pragma unroll
  for (int t = 0; t < 12; ++t) {
    double v = red[t];
#pragma unroll
    for (int m = 1; m <= 32; m <<= 1) v += __shfl_xor(v, m);
    red[t] = v;
  }
  double e0 = red[0] + 1e-10, e1 = red[1] + 1e-10, e2 = red[2] + 1e-10;
  double pv0 = w0 * (red[3] / e0) + w1 * (red[4] / e1) + w2 * (red[5] / e2);
  double pv1 = w0 * (red[6] / e0) + w1 * (red[7] / e1) + w2 * (red[8] / e2);
  double pv2 = w0 * (red[9] / e0) + w1 * (red[10] / e1) + w2 * (red[11] / e2);

  double minabs = (d13 < 0.0) ? -d13
                              : ((d42 < 0.0) ? fmin(d13, -d42) : fmin(d13, d42));
  double tb = minabs / 0.05;
  double bnd = 1.0 / (1.0 + tb * tb);

  atomicAdd(&out[oy * 256 + ox], (float)pv0);
  atomicAdd(&out[65536 + oy * 256 + ox], (float)pv1);
  atomicAdd(&out[131072 + oy * 256 + ox], (float)pv2);
  atomicAdd(&out[196608 + oy * 256 + ox], (float)bnd);
}

// ---------------- Kernel C: divide by num_patches -----------------------
__global__ void __launch_bounds__(256) foj_norm(float* __restrict__ out) {
  int idx = blockIdx.x * 256 + threadIdx.x;
  int y = idx >> 8, xx = idx & 255;
  int hlo = (y >= 4) ? ((y - 4) >> 2) : 0;
  int hhi = min(62, y >> 2);
  int wlo = (xx >= 4) ? ((xx - 4) >> 2) : 0;
  int whi = min(62, xx >> 2);
  float np_ = (float)((hhi - hlo + 1) * (whi - wlo + 1));
  out[idx] /= np_;
  out[65536 + idx] /= np_;
  out[131072 + idx] /= np_;
  out[196608 + idx] /= np_;
}

extern "C" void kernel_launch(void* const* d_in, const int* in_sizes, int n_in,
                              void* d_out, int out_size, void* d_ws, size_t ws_size,
                              hipStream_t stream) {
  const float* x = (const float*)d_in[0];
  float* out = (float*)d_out;
  double* pws = (double*)d_ws;  // 3969*5 doubles = ~159 KB scratch

  foj_descent<<<(NPATCH + 3) / 4, 256, 0, stream>>>(x, pws);
  hipMemsetAsync(d_out, 0, (size_t)out_size * sizeof(float), stream);
  foj_final<<<(NPATCH + 3) / 4, 256, 0, stream>>>(x, pws, out);
  foj_norm<<<256, 256, 0, stream>>>(out);
}

// Round 10
// 140.334 us; speedup vs baseline: 12.8118x; 1.1475x over previous
//
#include <hip/hip_runtime.h>
#include <math.h>

#define WP_ 63
#define NPATCH 3969
#define PI_D 3.141592653589793
#define TWO_PI_D 6.283185307179586476925287
#define BANDF 4e-3f

// numpy remainder(v, 2pi): fmod then fix sign (fmod is exact -> keep ocml)
__device__ __forceinline__ double remtp_d(double v) {
  double r = fmod(v, TWO_PI_D);
  if (r < 0.0) r += TWO_PI_D;
  return r;
}

__device__ __forceinline__ double lin8d(int i) {
  if (i == 7) return 1.0;
  return __dadd_rn(__dmul_rn((double)i, 2.0 / 7.0), -1.0);
}
__device__ __forceinline__ double angd(int n) {
  return __dmul_rn((double)n, TWO_PI_D / 31.0);
}
__device__ __forceinline__ double xyd(int n) {
  if (n == 30) return 3.0;
  return __dadd_rn(__dmul_rn((double)n, 6.0 / 30.0), -3.0);
}

__device__ __forceinline__ double pow35_d(double x) {
#pragma clang fp contract(off)
  double x2 = x * x;
  double r = x * x2;
  double b = x2 * x2;
  b = b * b; b = b * b; b = b * b;
  return r * b;
}

__device__ __forceinline__ double rcp_nr(double d) {
  double r;
  asm("v_rcp_f64 %0, %1" : "=v"(r) : "v"(d));
  r = fma(fma(-d, r, 1.0), r, r);
  r = fma(fma(-d, r, 1.0), r, r);
  return r;
}

// branchless sincos for 0 <= x < ~13 (fdlibm kernels, 2-part Cody-Waite,
// ~1e-16 rel -- same "different-libm ulp" noise class proven r4-r9)
__device__ __forceinline__ void sincos_fast(double x, double* so, double* co) {
  double kd = rint(x * 6.36619772367581382433e-01);
  int q = (int)kd & 3;
  double r = fma(-kd, 1.57079632673412561417e+00, x);
  r = fma(-kd, 6.07710050650619224932e-11, r);
  double z = r * r;
  double ps = 1.58969099521155010221e-10;
  ps = fma(z, ps, -2.50507602534068634195e-08);
  ps = fma(z, ps, 2.75573137070700676789e-06);
  ps = fma(z, ps, -1.98412698298579493134e-04);
  ps = fma(z, ps, 8.33333333332248946124e-03);
  ps = fma(z, ps, -1.66666666666666324348e-01);
  double sr = fma(z * r, ps, r);
  double pc = -1.13596475577881948265e-11;
  pc = fma(z, pc, 2.08757232129817482790e-09);
  pc = fma(z, pc, -2.75573143513906633035e-07);
  pc = fma(z, pc, 2.48015872894767294178e-05);
  pc = fma(z, pc, -1.38888888888741095749e-03);
  pc = fma(z, pc, 4.16666666666666019037e-02);
  double cr = fma(z, fma(z, pc, -0.5), 1.0);
  bool swp = q & 1;
  double s0 = swp ? cr : sr;
  double c0 = swp ? sr : cr;
  *so = (q & 2) ? -s0 : s0;
  *co = (((q + 1) & 2)) ? -c0 : c0;
}

// ---------- atan tables (f64 + f32 views, same binning) -----------------
#define TABN 57
__device__ __forceinline__ void build_atan_tab(double2* tab, float2* tabf) {
  int k = threadIdx.x;
  if (k < 56) {
    int hi = ((4076 + k) << 18) | (1 << 17);
    double c = __hiloint2double(hi, 0);
    double a = atan(c);
    tab[k] = double2{c, a};
    tabf[k] = float2{(float)c, (float)a};  // c has 3 mant bits: f32-exact
  } else if (k == 56) {
    tab[56] = double2{0.0, 0.0};
    tabf[56] = float2{0.0f, 0.0f};
  }
}

// f64 pair hstep (verify path -- byte-compatible with proven r9)
__device__ __forceinline__ void hstep2_tab(const double2* __restrict__ tab,
                                           double da, double db,
                                           double& ha, double& hb) {
  double za = da * 100.0, zb = db * 100.0;
  double ua = fabs(za), ub = fabs(zb);
  int ia = (__double2hiint(ua) >> 18) - 4076;
  int ib = (__double2hiint(ub) >> 18) - 4076;
  ia = (ia < 0) ? 56 : ((ia > 55) ? 55 : ia);
  ib = (ib < 0) ? 56 : ((ib > 55) ? 55 : ib);
  double2 ea = tab[ia];
  double2 eb = tab[ib];
  double ta = (ua - ea.x) * rcp_nr(fma(ua, ea.x, 1.0));
  double tb = (ub - eb.x) * rcp_nr(fma(ub, eb.x, 1.0));
  double z2a = ta * ta, z2b = tb * tb;
  double pa = 1.0 / 13.0, pb = 1.0 / 13.0;
  pa = fma(z2a, pa, -1.0 / 11.0); pb = fma(z2b, pb, -1.0 / 11.0);
  pa = fma(z2a, pa, 1.0 / 9.0);   pb = fma(z2b, pb, 1.0 / 9.0);
  pa = fma(z2a, pa, -1.0 / 7.0);  pb = fma(z2b, pb, -1.0 / 7.0);
  pa = fma(z2a, pa, 1.0 / 5.0);   pb = fma(z2b, pb, 1.0 / 5.0);
  pa = fma(z2a, pa, -1.0 / 3.0);  pb = fma(z2b, pb, -1.0 / 3.0);
  pa = fma(z2a, pa, 1.0);         pb = fma(z2b, pb, 1.0);
  double aa = fma(ta, pa, ea.y);
  double ab = fma(tb, pb, eb.y);
  aa = copysign(aa, za);
  ab = copysign(ab, zb);
  ha = fma(aa, 0.31830988618379067154, 0.5);
  hb = fma(ab, 0.31830988618379067154, 0.5);
}

// f32 pair hstep (prescreen; err ~<1e-6 abs in h)
__device__ __forceinline__ void hstep2f(const float2* __restrict__ tabf,
                                        float da, float db,
                                        float& ha, float& hb) {
  float za = da * 100.0f, zb = db * 100.0f;
  float ua = fabsf(za), ub = fabsf(zb);
  int ia = (int)(__float_as_uint(ua) >> 21) - 492;
  int ib = (int)(__float_as_uint(ub) >> 21) - 492;
  ia = (ia < 0) ? 56 : ((ia > 55) ? 55 : ia);
  ib = (ib < 0) ? 56 : ((ib > 55) ? 55 : ib);
  float2 ea = tabf[ia], eb = tabf[ib];
  float dena = fmaf(ua, ea.x, 1.0f), denb = fmaf(ub, eb.x, 1.0f);
  float ra, rb;
  asm("v_rcp_f32 %0, %1" : "=v"(ra) : "v"(dena));
  asm("v_rcp_f32 %0, %1" : "=v"(rb) : "v"(denb));
  ra = fmaf(fmaf(-dena, ra, 1.0f), ra, ra);
  rb = fmaf(fmaf(-denb, rb, 1.0f), rb, rb);
  float ta = (ua - ea.x) * ra, tb = (ub - eb.x) * rb;
  float z2a = ta * ta, z2b = tb * tb;
  float pa = fmaf(z2a, 0.2f, -0.33333334f);
  float pb = fmaf(z2b, 0.2f, -0.33333334f);
  pa = fmaf(z2a, pa, 1.0f);
  pb = fmaf(z2b, pb, 1.0f);
  float aa = fmaf(ta, pa, ea.y);
  float ab = fmaf(tb, pb, eb.y);
  aa = copysignf(aa, za);
  ab = copysignf(ab, zb);
  ha = fmaf(aa, 0.31830987f, 0.5f);
  hb = fmaf(ab, 0.31830987f, 0.5f);
}

struct JPd {
  double s1, c1, s2, c2, s3, c3, s4, c4;
  double sg13, sg42, gt13, gt42;
};

__device__ JPd jprep_d(double p0, double p1, double p2) {
#pragma clang fp contract(off)
  double r0 = remtp_d(p0), r1 = remtp_d(p1), r2 = remtp_d(p2);
  double mn = fmin(r0, r1), mx = fmax(r0, r1);
  double a1 = fmin(mn, r2);
  double a3 = fmax(mx, r2);
  double a2 = fmax(mn, fmin(mx, r2));
  double remm = remtp_d(0.5 * (a1 - a3));
  double a4 = 0.5 * (a1 + a3) + ((remm >= PI_D) ? PI_D : 0.0);
  JPd j;
  double r42 = remtp_d(a2 - a4);
  j.sg42 = (r42 < PI_D) ? 1.0 : -1.0;
  j.gt42 = pow35_d(r42 / PI_D - 1.0) * 0.1;
  double r13 = remtp_d(a3 - a1);
  j.sg13 = (r13 < PI_D) ? 1.0 : -1.0;
  j.gt13 = pow35_d(r13 / PI_D - 1.0) * 0.1;
  sincos_fast(a1, &j.s1, &j.c1);
  sincos_fast(a2, &j.s2, &j.c2);
  sincos_fast(a3, &j.s3, &j.c3);
  sincos_fast(a4, &j.s4, &j.c4);
  return j;
}

__device__ __forceinline__ void jdist_d(const JPd& j, double dx, double dy,
                                        double& d13, double& d42) {
  double hl1 = (-j.s1) * dx + j.c1 * dy;
  double hl2 = (-j.s2) * dx + j.c2 * dy;
  double hl3 = (-j.s3) * dx + j.c3 * dy;
  double hl4 = (-j.s4) * dx + j.c4 * dy;
  d13 = j.sg13 * fmin(j.sg13 * hl1, (-j.sg13) * hl3) + j.gt13;
  d42 = j.sg42 * fmin(j.sg42 * hl4, (-j.sg42) * hl2) + j.gt42;
}

// ---------------- Kernel A: descent, f32 prescreen + f64 verify ----------
__global__ void __launch_bounds__(256)
foj_descent(const float* __restrict__ x, double* __restrict__ pout) {
  const int tid = threadIdx.x;
  const int wv = tid >> 6;
  const int lane = tid & 63;
  const int hp = lane >> 5;
  const int cand = lane & 31;
  const int patch = blockIdx.x * 4 + wv;

  __shared__ double2 stab[TABN];
  __shared__ float2 stabf[TABN];
  __shared__ float4 simg[4][64];
  build_atan_tab(stab, stabf);
  if (patch < NPATCH) {
    int ph = patch / WP_;
    int pw = patch - ph * WP_;
    int py = lane >> 3, pxx = lane & 7;
    int base = (ph * 4 + py) * 256 + (pw * 4 + pxx);
    float4 v;
    v.x = x[base];
    v.y = x[65536 + base];
    v.z = x[131072 + base];
    v.w = 0.0f;
    simg[wv][lane] = v;
  }
  __syncthreads();
  if (patch >= NPATCH) return;
  const float4* sp = simg[wv];

  // per-patch channel sums
  double sx0 = 0.0, sx1 = 0.0, sx2 = 0.0;
  {
    const float4* hbase = sp + hp * 32;
#pragma unroll
    for (int t = 0; t < 32; ++t) {
      float4 im = hbase[t];
      sx0 += (double)im.x; sx1 += (double)im.y; sx2 += (double)im.z;
    }
    sx0 += __shfl_xor(sx0, 32);
    sx1 += __shfl_xor(sx1, 32);
    sx2 += __shfl_xor(sx2, 32);
  }
  const float sx0f = (float)sx0, sx1f = (float)sx1, sx2f = (float)sx2;

  double q0 = 0.0, q1 = 0.0, q2 = 0.0, q3 = 0.0, q4 = 0.0;

#pragma unroll 1
  for (int i = 0; i < 5; ++i) {
    double rv = (i < 3) ? angd(cand) : xyd(cand);
    double p0 = q0 + ((i == 0) ? rv : 0.0);
    double p1 = q1 + ((i == 1) ? rv : 0.0);
    double p2 = q2 + ((i == 2) ? rv : 0.0);
    double x0 = q3 + ((i == 3) ? rv : 0.0);
    double y0 = q4 + ((i == 4) ? rv : 0.0);

    JPd j = jprep_d(p0, p1, p2);  // f64 always: discrete decisions exact

    // ---------------- f32 prescreen pass ----------------
    float blf;
    {
      float ns1f = (float)(-j.s1), c1f = (float)j.c1;
      float ns2f = (float)(-j.s2), c2f = (float)j.c2;
      float ns3f = (float)(-j.s3), c3f = (float)j.c3;
      float ns4f = (float)(-j.s4), c4f = (float)j.c4;
      float sg13f = (float)j.sg13, gt13f = (float)j.gt13;
      float sg42f = (float)j.sg42, gt42f = (float)j.gt42;
      float nsg13f = -sg13f, nsg42f = -sg42f;
      float dxf[8];
#pragma unroll
      for (int t = 0; t < 8; ++t) dxf[t] = (float)(lin8d(t) - x0);

      float den0f = 0, den1f = 0, den2f = 0;
      float n00f = 0, n01f = 0, n10f = 0, n11f = 0, n20f = 0, n21f = 0;
      float W00f = 0, W01f = 0, W11f = 0;
#pragma unroll 1
      for (int r = 0; r < 4; ++r) {
        int iyy = hp * 4 + r;
        double liny = (iyy == 7) ? 1.0
                    : __dadd_rn(__dmul_rn((double)iyy, 2.0 / 7.0), -1.0);
        float dyf = (float)(liny - y0);
        const float4* rowp = sp + hp * 32 + r * 8;
#pragma unroll
        for (int c = 0; c < 8; ++c) {
          float dxc = dxf[c];
          float hl1 = fmaf(ns1f, dxc, c1f * dyf);
          float hl2 = fmaf(ns2f, dxc, c2f * dyf);
          float hl3 = fmaf(ns3f, dxc, c3f * dyf);
          float hl4 = fmaf(ns4f, dxc, c4f * dyf);
          float d13 = fmaf(sg13f, fminf(sg13f * hl1, nsg13f * hl3), gt13f);
          float d42 = fmaf(sg42f, fminf(sg42f * hl4, nsg42f * hl2), gt42f);
          float h1, h2;
          hstep2f(stabf, d13, d42, h1, h2);
          float w0 = 1.0f - h1;
          float w1 = h1 * (1.0f - h2);
          float w2 = h1 * h2;
          float4 im = rowp[c];
          den0f += w0; den1f += w1; den2f += w2;
          n00f += im.x * w0; n01f += im.x * w1;
          n10f += im.y * w0; n11f += im.y * w1;
          n20f += im.z * w0; n21f += im.z * w1;
          W00f += w0 * w0; W01f += w0 * w1; W11f += w1 * w1;
        }
      }
      den0f += __shfl_xor(den0f, 32); den1f += __shfl_xor(den1f, 32); den2f += __shfl_xor(den2f, 32);
      n00f += __shfl_xor(n00f, 32); n01f += __shfl_xor(n01f, 32);
      n10f += __shfl_xor(n10f, 32); n11f += __shfl_xor(n11f, 32);
      n20f += __shfl_xor(n20f, 32); n21f += __shfl_xor(n21f, 32);
      W00f += __shfl_xor(W00f, 32); W01f += __shfl_xor(W01f, 32); W11f += __shfl_xor(W11f, 32);

      float n02f = sx0f - n00f - n01f;
      float n12f = sx1f - n10f - n11f;
      float n22f = sx2f - n20f - n21f;
      float W02f = den0f - W00f - W01f;
      float W12f = den1f - W01f - W11f;
      float W22f = den2f - W02f - W12f;

      float e0 = den0f + 1e-10f, e1 = den1f + 1e-10f, e2 = den2f + 1e-10f;
      float r0f, r1f, r2f;
      asm("v_rcp_f32 %0, %1" : "=v"(r0f) : "v"(e0));
      asm("v_rcp_f32 %0, %1" : "=v"(r1f) : "v"(e1));
      asm("v_rcp_f32 %0, %1" : "=v"(r2f) : "v"(e2));
      r0f = fmaf(fmaf(-e0, r0f, 1.0f), r0f, r0f);
      r1f = fmaf(fmaf(-e1, r1f, 1.0f), r1f, r1f);
      r2f = fmaf(fmaf(-e2, r2f, 1.0f), r2f, r2f);
      float c00 = n00f * r0f, c01 = n01f * r1f, c02 = n02f * r2f;
      float c10 = n10f * r0f, c11 = n11f * r1f, c12 = n12f * r2f;
      float c20 = n20f * r0f, c21 = n21f * r1f, c22 = n22f * r2f;

      float lossf =
          c00 * (W00f * c00 + W01f * c01 + W02f * c02 - 2.0f * n00f) +
          c01 * (W01f * c00 + W11f * c01 + W12f * c02 - 2.0f * n01f) +
          c02 * (W02f * c00 + W12f * c01 + W22f * c02 - 2.0f * n02f) +
          c10 * (W00f * c10 + W01f * c11 + W02f * c12 - 2.0f * n10f) +
          c11 * (W01f * c10 + W11f * c11 + W12f * c12 - 2.0f * n11f) +
          c12 * (W02f * c10 + W12f * c11 + W22f * c12 - 2.0f * n12f) +
          c20 * (W00f * c20 + W01f * c21 + W02f * c22 - 2.0f * n20f) +
          c21 * (W01f * c20 + W11f * c21 + W12f * c22 - 2.0f * n21f) +
          c22 * (W02f * c20 + W12f * c21 + W22f * c22 - 2.0f * n22f);

      blf = (cand < 31) ? lossf : 3.0e38f;
    }

    float mnf = blf;
#pragma unroll
    for (int m = 1; m <= 16; m <<= 1) mnf = fminf(mnf, __shfl_xor(mnf, m));
    bool inb = (cand < 31) && (blf <= mnf + BANDF);
    unsigned bal32 = (unsigned)__ballot(inb);

    int bi;
    if (__popc(bal32) == 1) {
      bi = __ffs(bal32) - 1;   // unique winner: f32 decision is safe
    } else {
      // ---------------- f64 verify pass (r9-exact) ----------------
      double den0 = 0, den1 = 0, den2 = 0;
      double n00 = 0, n01 = 0, n10 = 0, n11 = 0, n20 = 0, n21 = 0;
      double W00 = 0, W01 = 0, W11 = 0;
#pragma unroll 1
      for (int r = 0; r < 4; ++r) {
        int iyy = hp * 4 + r;
        double liny = (iyy == 7) ? 1.0
                    : __dadd_rn(__dmul_rn((double)iyy, 2.0 / 7.0), -1.0);
        double dy = liny - y0;
        const float4* rowp = sp + hp * 32 + r * 8;
#pragma unroll
        for (int c = 0; c < 8; ++c) {
          double dx = lin8d(c) - x0;
          double d13, d42;
          jdist_d(j, dx, dy, d13, d42);
          double h1, h2;
          hstep2_tab(stab, d13, d42, h1, h2);
          double w0 = 1.0 - h1;
          double w1 = h1 * (1.0 - h2);
          double w2 = h1 * h2;
          float4 im = rowp[c];
          double ix = (double)im.x, iy2 = (double)im.y, iz = (double)im.z;
          den0 += w0; den1 += w1; den2 += w2;
          n00 += ix * w0; n01 += ix * w1;
          n10 += iy2 * w0; n11 += iy2 * w1;
          n20 += iz * w0; n21 += iz * w1;
          W00 += w0 * w0; W01 += w0 * w1; W11 += w1 * w1;
        }
      }
      den0 += __shfl_xor(den0, 32); den1 += __shfl_xor(den1, 32); den2 += __shfl_xor(den2, 32);
      n00 += __shfl_xor(n00, 32); n01 += __shfl_xor(n01, 32);
      n10 += __shfl_xor(n10, 32); n11 += __shfl_xor(n11, 32);
      n20 += __shfl_xor(n20, 32); n21 += __shfl_xor(n21, 32);
      W00 += __shfl_xor(W00, 32); W01 += __shfl_xor(W01, 32); W11 += __shfl_xor(W11, 32);

      double n02 = sx0 - n00 - n01;
      double n12 = sx1 - n10 - n11;
      double n22 = sx2 - n20 - n21;
      double W02 = den0 - W00 - W01;
      double W12 = den1 - W01 - W11;
      double W22 = den2 - W02 - W12;

      double r0 = rcp_nr(den0 + 1e-10);
      double r1 = rcp_nr(den1 + 1e-10);
      double r2 = rcp_nr(den2 + 1e-10);
      double c00 = n00 * r0, c01 = n01 * r1, c02 = n02 * r2;
      double c10 = n10 * r0, c11 = n11 * r1, c12 = n12 * r2;
      double c20 = n20 * r0, c21 = n21 * r1, c22 = n22 * r2;

      double loss =
          c00 * (W00 * c00 + W01 * c01 + W02 * c02 - 2.0 * n00) +
          c01 * (W01 * c00 + W11 * c01 + W12 * c02 - 2.0 * n01) +
          c02 * (W02 * c00 + W12 * c01 + W22 * c02 - 2.0 * n02) +
          c10 * (W00 * c10 + W01 * c11 + W02 * c12 - 2.0 * n10) +
          c11 * (W01 * c10 + W11 * c11 + W12 * c12 - 2.0 * n11) +
          c12 * (W02 * c10 + W12 * c11 + W22 * c12 - 2.0 * n12) +
          c20 * (W00 * c20 + W01 * c21 + W02 * c22 - 2.0 * n20) +
          c21 * (W01 * c20 + W11 * c21 + W12 * c22 - 2.0 * n21) +
          c22 * (W02 * c20 + W12 * c21 + W22 * c22 - 2.0 * n22);

      double bl = (cand < 31) ? loss : (double)INFINITY;
      int bi0 = cand;
#pragma unroll
      for (int m = 1; m <= 16; m <<= 1) {
        double ol = __shfl_xor(bl, m);
        int oi = __shfl_xor(bi0, m);
        if (ol < bl || (ol == bl && oi < bi0)) { bl = ol; bi0 = oi; }
      }
      bi = bi0;
    }

    double upd = (i < 3) ? angd(bi) : xyd(bi);
    if (i == 0) q0 += upd;
    else if (i == 1) q1 += upd;
    else if (i == 2) q2 += upd;
    else if (i == 3) q3 += upd;
    else q4 += upd;
  }

  if (lane == 0) {
    pout[patch * 5 + 0] = q0;
    pout[patch * 5 + 1] = q1;
    pout[patch * 5 + 2] = q2;
    pout[patch * 5 + 3] = q3;
    pout[patch * 5 + 4] = q4;
  }
}

// ---------------- Kernel B: final reconstruction + fold (atomic) --------
__global__ void __launch_bounds__(256) foj_final(const float* __restrict__ x,
                                                 const double* __restrict__ pin,
                                                 float* __restrict__ out) {
  int lane = threadIdx.x & 63;
  int patch = blockIdx.x * 4 + (threadIdx.x >> 6);
  if (patch >= NPATCH) return;
  int ph = patch / WP_;
  int pw = patch - ph * WP_;
  double q0 = pin[patch * 5 + 0];
  double q1 = pin[patch * 5 + 1];
  double q2 = pin[patch * 5 + 2];
  double x0 = pin[patch * 5 + 3];
  double y0 = pin[patch * 5 + 4];

  JPd j = jprep_d(q0, q1, q2);
  int pi2 = lane >> 3, pj = lane & 7;
  double dx = lin8d(pj) - x0;
  double dy = lin8d(pi2) - y0;
  double d13, d42;
  jdist_d(j, dx, dy, d13, d42);
  double h1 = 0.5 + 0.31830988618379067154 * atan(d13 * 100.0);  // ocml
  double h2 = 0.5 + 0.31830988618379067154 * atan(d42 * 100.0);
  double w0 = 1.0 - h1;
  double w1 = h1 * (1.0 - h2);
  double w2 = h1 * h2;

  int oy = ph * 4 + pi2, ox = pw * 4 + pj;
  double im0 = (double)x[oy * 256 + ox];
  double im1 = (double)x[65536 + oy * 256 + ox];
  double im2 = (double)x[131072 + oy * 256 + ox];

  double red[12] = {w0, w1, w2,
                    im0 * w0, im0 * w1, im0 * w2,
                    im1 * w0, im1 * w1, im1 * w2,
                    im2 * w0, im2 * w1, im2 * w2};
#pragma unroll
  for (int t = 0; t < 12; ++t) {
    double v = red[t];
#pragma unroll
    for (int m = 1; m <= 32; m <<= 1) v += __shfl_xor(v, m);
    red[t] = v;
  }
  double e0 = red[0] + 1e-10, e1 = red[1] + 1e-10, e2 = red[2] + 1e-10;
  double pv0 = w0 * (red[3] / e0) + w1 * (red[4] / e1) + w2 * (red[5] / e2);
  double pv1 = w0 * (red[6] / e0) + w1 * (red[7] / e1) + w2 * (red[8] / e2);
  double pv2 = w0 * (red[9] / e0) + w1 * (red[10] / e1) + w2 * (red[11] / e2);

  double minabs = (d13 < 0.0) ? -d13
                              : ((d42 < 0.0) ? fmin(d13, -d42) : fmin(d13, d42));
  double tb = minabs / 0.05;
  double bnd = 1.0 / (1.0 + tb * tb);

  atomicAdd(&out[oy * 256 + ox], (float)pv0);
  atomicAdd(&out[65536 + oy * 256 + ox], (float)pv1);
  atomicAdd(&out[131072 + oy * 256 + ox], (float)pv2);
  atomicAdd(&out[196608 + oy * 256 + ox], (float)bnd);
}

// ---------------- Kernel C: divide by num_patches -----------------------
__global__ void __launch_bounds__(256) foj_norm(float* __restrict__ out) {
  int idx = blockIdx.x * 256 + threadIdx.x;
  int y = idx >> 8, xx = idx & 255;
  int hlo = (y >= 4) ? ((y - 4) >> 2) : 0;
  int hhi = min(62, y >> 2);
  int wlo = (xx >= 4) ? ((xx - 4) >> 2) : 0;
  int whi = min(62, xx >> 2);
  float np_ = (float)((hhi - hlo + 1) * (whi - wlo + 1));
  out[idx] /= np_;
  out[65536 + idx] /= np_;
  out[131072 + idx] /= np_;
  out[196608 + idx] /= np_;
}

extern "C" void kernel_launch(void* const* d_in, const int* in_sizes, int n_in,
                              void* d_out, int out_size, void* d_ws, size_t ws_size,
                              hipStream_t stream) {
  const float* x = (const float*)d_in[0];
  float* out = (float*)d_out;
  double* pws = (double*)d_ws;  // 3969*5 doubles = ~159 KB scratch

  foj_descent<<<(NPATCH + 3) / 4, 256, 0, stream>>>(x, pws);
  hipMemsetAsync(d_out, 0, (size_t)out_size * sizeof(float), stream);
  foj_final<<<(NPATCH + 3) / 4, 256, 0, stream>>>(x, pws, out);
  foj_norm<<<256, 256, 0, stream>>>(out);
}

// Round 11
// 136.883 us; speedup vs baseline: 13.1349x; 1.0252x over previous
//
#include <hip/hip_runtime.h>
#include <math.h>

#define WP_ 63
#define NPATCH 3969
#define PI_D 3.141592653589793
#define TWO_PI_D 6.283185307179586476925287
#define BANDF 4e-3f

typedef float f32x2 __attribute__((ext_vector_type(2)));
__device__ __forceinline__ f32x2 v2(float s) { return (f32x2){s, s}; }
__device__ __forceinline__ f32x2 fma2(f32x2 a, f32x2 b, f32x2 c) {
  return __builtin_elementwise_fma(a, b, c);
}

// numpy remainder(v, 2pi): fmod then fix sign
__device__ __forceinline__ double remtp_d(double v) {
  double r = fmod(v, TWO_PI_D);
  if (r < 0.0) r += TWO_PI_D;
  return r;
}

__device__ __forceinline__ double lin8d(int i) {
  if (i == 7) return 1.0;
  return __dadd_rn(__dmul_rn((double)i, 2.0 / 7.0), -1.0);
}
__device__ __forceinline__ double angd(int n) {
  return __dmul_rn((double)n, TWO_PI_D / 31.0);
}
__device__ __forceinline__ double xyd(int n) {
  if (n == 30) return 3.0;
  return __dadd_rn(__dmul_rn((double)n, 6.0 / 30.0), -3.0);
}

__device__ __forceinline__ double pow35_d(double x) {
#pragma clang fp contract(off)
  double x2 = x * x;
  double r = x * x2;
  double b = x2 * x2;
  b = b * b; b = b * b; b = b * b;
  return r * b;
}

__device__ __forceinline__ double rcp_nr(double d) {
  double r;
  asm("v_rcp_f64 %0, %1" : "=v"(r) : "v"(d));
  r = fma(fma(-d, r, 1.0), r, r);
  r = fma(fma(-d, r, 1.0), r, r);
  return r;
}

// branchless sincos for 0 <= x < ~13 (fdlibm kernels, 2-part Cody-Waite)
__device__ __forceinline__ void sincos_fast(double x, double* so, double* co) {
  double kd = rint(x * 6.36619772367581382433e-01);
  int q = (int)kd & 3;
  double r = fma(-kd, 1.57079632673412561417e+00, x);
  r = fma(-kd, 6.07710050650619224932e-11, r);
  double z = r * r;
  double ps = 1.58969099521155010221e-10;
  ps = fma(z, ps, -2.50507602534068634195e-08);
  ps = fma(z, ps, 2.75573137070700676789e-06);
  ps = fma(z, ps, -1.98412698298579493134e-04);
  ps = fma(z, ps, 8.33333333332248946124e-03);
  ps = fma(z, ps, -1.66666666666666324348e-01);
  double sr = fma(z * r, ps, r);
  double pc = -1.13596475577881948265e-11;
  pc = fma(z, pc, 2.08757232129817482790e-09);
  pc = fma(z, pc, -2.75573143513906633035e-07);
  pc = fma(z, pc, 2.48015872894767294178e-05);
  pc = fma(z, pc, -1.38888888888741095749e-03);
  pc = fma(z, pc, 4.16666666666666019037e-02);
  double cr = fma(z, fma(z, pc, -0.5), 1.0);
  bool swp = q & 1;
  double s0 = swp ? cr : sr;
  double c0 = swp ? sr : cr;
  *so = (q & 2) ? -s0 : s0;
  *co = (((q + 1) & 2)) ? -c0 : c0;
}

// ---------- atan tables (f64 + f32 views, same binning) -----------------
#define TABN 57
__device__ __forceinline__ void build_atan_tab(double2* tab, float2* tabf) {
  int k = threadIdx.x;
  if (k < 56) {
    int hi = ((4076 + k) << 18) | (1 << 17);
    double c = __hiloint2double(hi, 0);
    double a = atan(c);
    tab[k] = double2{c, a};
    tabf[k] = float2{(float)c, (float)a};
  } else if (k == 56) {
    tab[56] = double2{0.0, 0.0};
    tabf[56] = float2{0.0f, 0.0f};
  }
}

// f64 pair hstep (verify path -- byte-identical to r9/r10)
__device__ __forceinline__ void hstep2_tab(const double2* __restrict__ tab,
                                           double da, double db,
                                           double& ha, double& hb) {
  double za = da * 100.0, zb = db * 100.0;
  double ua = fabs(za), ub = fabs(zb);
  int ia = (__double2hiint(ua) >> 18) - 4076;
  int ib = (__double2hiint(ub) >> 18) - 4076;
  ia = (ia < 0) ? 56 : ((ia > 55) ? 55 : ia);
  ib = (ib < 0) ? 56 : ((ib > 55) ? 55 : ib);
  double2 ea = tab[ia];
  double2 eb = tab[ib];
  double ta = (ua - ea.x) * rcp_nr(fma(ua, ea.x, 1.0));
  double tb = (ub - eb.x) * rcp_nr(fma(ub, eb.x, 1.0));
  double z2a = ta * ta, z2b = tb * tb;
  double pa = 1.0 / 13.0, pb = 1.0 / 13.0;
  pa = fma(z2a, pa, -1.0 / 11.0); pb = fma(z2b, pb, -1.0 / 11.0);
  pa = fma(z2a, pa, 1.0 / 9.0);   pb = fma(z2b, pb, 1.0 / 9.0);
  pa = fma(z2a, pa, -1.0 / 7.0);  pb = fma(z2b, pb, -1.0 / 7.0);
  pa = fma(z2a, pa, 1.0 / 5.0);   pb = fma(z2b, pb, 1.0 / 5.0);
  pa = fma(z2a, pa, -1.0 / 3.0);  pb = fma(z2b, pb, -1.0 / 3.0);
  pa = fma(z2a, pa, 1.0);         pb = fma(z2b, pb, 1.0);
  double aa = fma(ta, pa, ea.y);
  double ab = fma(tb, pb, eb.y);
  aa = copysign(aa, za);
  ab = copysign(ab, zb);
  ha = fma(aa, 0.31830988618379067154, 0.5);
  hb = fma(ab, 0.31830988618379067154, 0.5);
}

// f32 packed-pair hstep: component op order identical to r10 scalar
__device__ __forceinline__ f32x2 hstep2fv(const float2* __restrict__ tabf,
                                          f32x2 d) {
  f32x2 z = d * 100.0f;
  f32x2 u = __builtin_elementwise_abs(z);
  int ia = (int)(__float_as_uint(u.x) >> 21) - 492;
  int ib = (int)(__float_as_uint(u.y) >> 21) - 492;
  ia = (ia < 0) ? 56 : ((ia > 55) ? 55 : ia);
  ib = (ib < 0) ? 56 : ((ib > 55) ? 55 : ib);
  float2 ea = tabf[ia], eb = tabf[ib];
  f32x2 ec = {ea.x, eb.x};
  f32x2 ey = {ea.y, eb.y};
  f32x2 den = fma2(u, ec, v2(1.0f));
  float ra, rb;
  asm("v_rcp_f32 %0, %1" : "=v"(ra) : "v"(den.x));
  asm("v_rcp_f32 %0, %1" : "=v"(rb) : "v"(den.y));
  f32x2 r = {ra, rb};
  r = fma2(fma2(-den, r, v2(1.0f)), r, r);
  f32x2 t = (u - ec) * r;
  f32x2 z2 = t * t;
  f32x2 p = fma2(z2, v2(0.2f), v2(-0.33333334f));
  p = fma2(z2, p, v2(1.0f));
  f32x2 a = fma2(t, p, ey);
  a = __builtin_elementwise_copysign(a, z);
  return fma2(a, v2(0.31830987f), v2(0.5f));
}

struct JPd {
  double s1, c1, s2, c2, s3, c3, s4, c4;
  double sg13, sg42, gt13, gt42;
};

__device__ JPd jprep_d(double p0, double p1, double p2) {
#pragma clang fp contract(off)
  double r0 = remtp_d(p0), r1 = remtp_d(p1), r2 = remtp_d(p2);
  double mn = fmin(r0, r1), mx = fmax(r0, r1);
  double a1 = fmin(mn, r2);
  double a3 = fmax(mx, r2);
  double a2 = fmax(mn, fmin(mx, r2));
  double remm = remtp_d(0.5 * (a1 - a3));
  double a4 = 0.5 * (a1 + a3) + ((remm >= PI_D) ? PI_D : 0.0);
  JPd j;
  double r42 = remtp_d(a2 - a4);
  j.sg42 = (r42 < PI_D) ? 1.0 : -1.0;
  j.gt42 = pow35_d(r42 / PI_D - 1.0) * 0.1;
  double r13 = remtp_d(a3 - a1);
  j.sg13 = (r13 < PI_D) ? 1.0 : -1.0;
  j.gt13 = pow35_d(r13 / PI_D - 1.0) * 0.1;
  sincos_fast(a1, &j.s1, &j.c1);
  sincos_fast(a2, &j.s2, &j.c2);
  sincos_fast(a3, &j.s3, &j.c3);
  sincos_fast(a4, &j.s4, &j.c4);
  return j;
}

__device__ __forceinline__ void jdist_d(const JPd& j, double dx, double dy,
                                        double& d13, double& d42) {
  double hl1 = (-j.s1) * dx + j.c1 * dy;
  double hl2 = (-j.s2) * dx + j.c2 * dy;
  double hl3 = (-j.s3) * dx + j.c3 * dy;
  double hl4 = (-j.s4) * dx + j.c4 * dy;
  d13 = j.sg13 * fmin(j.sg13 * hl1, (-j.sg13) * hl3) + j.gt13;
  d42 = j.sg42 * fmin(j.sg42 * hl4, (-j.sg42) * hl2) + j.gt42;
}

// ---------------- Kernel A: descent, packed-f32 prescreen + f64 verify ---
__global__ void __launch_bounds__(256)
foj_descent(const float* __restrict__ x, double* __restrict__ pout) {
  const int tid = threadIdx.x;
  const int wv = tid >> 6;
  const int lane = tid & 63;
  const int hp = lane >> 5;
  const int cand = lane & 31;
  const int patch = blockIdx.x * 4 + wv;

  __shared__ double2 stab[TABN];
  __shared__ float2 stabf[TABN];
  __shared__ float4 simg[4][64];
  build_atan_tab(stab, stabf);
  if (patch < NPATCH) {
    int ph = patch / WP_;
    int pw = patch - ph * WP_;
    int py = lane >> 3, pxx = lane & 7;
    int base = (ph * 4 + py) * 256 + (pw * 4 + pxx);
    float4 v;
    v.x = x[base];
    v.y = x[65536 + base];
    v.z = x[131072 + base];
    v.w = 0.0f;
    simg[wv][lane] = v;
  }
  __syncthreads();
  if (patch >= NPATCH) return;
  const float4* sp = simg[wv];

  // per-patch channel sums
  double sx0 = 0.0, sx1 = 0.0, sx2 = 0.0;
  {
    const float4* hbase = sp + hp * 32;
#pragma unroll
    for (int t = 0; t < 32; ++t) {
      float4 im = hbase[t];
      sx0 += (double)im.x; sx1 += (double)im.y; sx2 += (double)im.z;
    }
    sx0 += __shfl_xor(sx0, 32);
    sx1 += __shfl_xor(sx1, 32);
    sx2 += __shfl_xor(sx2, 32);
  }
  const float sx0f = (float)sx0, sx1f = (float)sx1, sx2f = (float)sx2;

  double q0 = 0.0, q1 = 0.0, q2 = 0.0, q3 = 0.0, q4 = 0.0;

#pragma unroll 1
  for (int i = 0; i < 5; ++i) {
    double rv = (i < 3) ? angd(cand) : xyd(cand);
    double p0 = q0 + ((i == 0) ? rv : 0.0);
    double p1 = q1 + ((i == 1) ? rv : 0.0);
    double p2 = q2 + ((i == 2) ? rv : 0.0);
    double x0 = q3 + ((i == 3) ? rv : 0.0);
    double y0 = q4 + ((i == 4) ? rv : 0.0);

    JPd j = jprep_d(p0, p1, p2);  // f64 always: discrete decisions exact

    // ---------------- packed f32 prescreen ----------------
    float blf;
    {
      // vector pairing: lane0 = 13-chain, lane1 = 42-chain
      f32x2 ns14 = {(float)(-j.s1), (float)(-j.s4)};
      f32x2 c14v = {(float)j.c1, (float)j.c4};
      f32x2 ns32 = {(float)(-j.s3), (float)(-j.s2)};
      f32x2 c32v = {(float)j.c3, (float)j.c2};
      f32x2 sgv = {(float)j.sg13, (float)j.sg42};
      f32x2 nsgv = -sgv;
      f32x2 gtv = {(float)j.gt13, (float)j.gt42};
      float dxf[8];
#pragma unroll
      for (int t = 0; t < 8; ++t) dxf[t] = (float)(lin8d(t) - x0);

      f32x2 den01 = {0, 0};   // {den0, den1}
      f32x2 WW = {0, 0};      // {W00, W11}
      f32x2 n0v = {0, 0};     // {n00, n01}
      f32x2 n1v = {0, 0};     // {n10, n11}
      f32x2 n2v = {0, 0};     // {n20, n21}
      float den2f = 0, W01f = 0;
#pragma unroll 1
      for (int r = 0; r < 4; ++r) {
        int iyy = hp * 4 + r;
        double liny = (iyy == 7) ? 1.0
                    : __dadd_rn(__dmul_rn((double)iyy, 2.0 / 7.0), -1.0);
        float dyf = (float)(liny - y0);
        const float4* rowp = sp + hp * 32 + r * 8;
#pragma unroll
        for (int c = 0; c < 8; ++c) {
          f32x2 dxv = v2(dxf[c]);
          f32x2 P = fma2(ns14, dxv, c14v * dyf);   // {hl1, hl4}
          f32x2 Q = fma2(ns32, dxv, c32v * dyf);   // {hl3, hl2}
          f32x2 dv = fma2(sgv, __builtin_elementwise_min(sgv * P, nsgv * Q),
                          gtv);                    // {d13, d42}
          f32x2 hv = hstep2fv(stabf, dv);
          float w0 = 1.0f - hv.x;
          float w1 = hv.x * (1.0f - hv.y);
          float w2 = hv.x * hv.y;
          f32x2 w01 = {w0, w1};
          float4 im = rowp[c];
          den01 += w01;
          WW = fma2(w01, w01, WW);
          W01f = fmaf(w0, w1, W01f);
          den2f += w2;
          n0v = fma2(v2(im.x), w01, n0v);
          n1v = fma2(v2(im.y), w01, n1v);
          n2v = fma2(v2(im.z), w01, n2v);
        }
      }
      float den0f = den01.x, den1f = den01.y;
      float W00f = WW.x, W11f = WW.y;
      float n00f = n0v.x, n01f = n0v.y;
      float n10f = n1v.x, n11f = n1v.y;
      float n20f = n2v.x, n21f = n2v.y;

      den0f += __shfl_xor(den0f, 32); den1f += __shfl_xor(den1f, 32); den2f += __shfl_xor(den2f, 32);
      n00f += __shfl_xor(n00f, 32); n01f += __shfl_xor(n01f, 32);
      n10f += __shfl_xor(n10f, 32); n11f += __shfl_xor(n11f, 32);
      n20f += __shfl_xor(n20f, 32); n21f += __shfl_xor(n21f, 32);
      W00f += __shfl_xor(W00f, 32); W01f += __shfl_xor(W01f, 32); W11f += __shfl_xor(W11f, 32);

      float n02f = sx0f - n00f - n01f;
      float n12f = sx1f - n10f - n11f;
      float n22f = sx2f - n20f - n21f;
      float W02f = den0f - W00f - W01f;
      float W12f = den1f - W01f - W11f;
      float W22f = den2f - W02f - W12f;

      float e0 = den0f + 1e-10f, e1 = den1f + 1e-10f, e2 = den2f + 1e-10f;
      float r0f, r1f, r2f;
      asm("v_rcp_f32 %0, %1" : "=v"(r0f) : "v"(e0));
      asm("v_rcp_f32 %0, %1" : "=v"(r1f) : "v"(e1));
      asm("v_rcp_f32 %0, %1" : "=v"(r2f) : "v"(e2));
      r0f = fmaf(fmaf(-e0, r0f, 1.0f), r0f, r0f);
      r1f = fmaf(fmaf(-e1, r1f, 1.0f), r1f, r1f);
      r2f = fmaf(fmaf(-e2, r2f, 1.0f), r2f, r2f);
      float c00 = n00f * r0f, c01 = n01f * r1f, c02 = n02f * r2f;
      float c10 = n10f * r0f, c11 = n11f * r1f, c12 = n12f * r2f;
      float c20 = n20f * r0f, c21 = n21f * r1f, c22 = n22f * r2f;

      float lossf =
          c00 * (W00f * c00 + W01f * c01 + W02f * c02 - 2.0f * n00f) +
          c01 * (W01f * c00 + W11f * c01 + W12f * c02 - 2.0f * n01f) +
          c02 * (W02f * c00 + W12f * c01 + W22f * c02 - 2.0f * n02f) +
          c10 * (W00f * c10 + W01f * c11 + W02f * c12 - 2.0f * n10f) +
          c11 * (W01f * c10 + W11f * c11 + W12f * c12 - 2.0f * n11f) +
          c12 * (W02f * c10 + W12f * c11 + W22f * c12 - 2.0f * n12f) +
          c20 * (W00f * c20 + W01f * c21 + W02f * c22 - 2.0f * n20f) +
          c21 * (W01f * c20 + W11f * c21 + W12f * c22 - 2.0f * n21f) +
          c22 * (W02f * c20 + W12f * c21 + W22f * c22 - 2.0f * n22f);

      blf = (cand < 31) ? lossf : 3.0e38f;
    }

    float mnf = blf;
#pragma unroll
    for (int m = 1; m <= 16; m <<= 1) mnf = fminf(mnf, __shfl_xor(mnf, m));
    bool inb = (cand < 31) && (blf <= mnf + BANDF);
    unsigned bal32 = (unsigned)__ballot(inb);

    int bi;
    if (__popc(bal32) == 1) {
      bi = __ffs(bal32) - 1;   // unique winner: f32 decision is safe
    } else {
      // ---------------- f64 verify pass (r9-exact) ----------------
      double den0 = 0, den1 = 0, den2 = 0;
      double n00 = 0, n01 = 0, n10 = 0, n11 = 0, n20 = 0, n21 = 0;
      double W00 = 0, W01 = 0, W11 = 0;
#pragma unroll 1
      for (int r = 0; r < 4; ++r) {
        int iyy = hp * 4 + r;
        double liny = (iyy == 7) ? 1.0
                    : __dadd_rn(__dmul_rn((double)iyy, 2.0 / 7.0), -1.0);
        double dy = liny - y0;
        const float4* rowp = sp + hp * 32 + r * 8;
#pragma unroll
        for (int c = 0; c < 8; ++c) {
          double dx = lin8d(c) - x0;
          double d13, d42;
          jdist_d(j, dx, dy, d13, d42);
          double h1, h2;
          hstep2_tab(stab, d13, d42, h1, h2);
          double w0 = 1.0 - h1;
          double w1 = h1 * (1.0 - h2);
          double w2 = h1 * h2;
          float4 im = rowp[c];
          double ix = (double)im.x, iy2 = (double)im.y, iz = (double)im.z;
          den0 += w0; den1 += w1; den2 += w2;
          n00 += ix * w0; n01 += ix * w1;
          n10 += iy2 * w0; n11 += iy2 * w1;
          n20 += iz * w0; n21 += iz * w1;
          W00 += w0 * w0; W01 += w0 * w1; W11 += w1 * w1;
        }
      }
      den0 += __shfl_xor(den0, 32); den1 += __shfl_xor(den1, 32); den2 += __shfl_xor(den2, 32);
      n00 += __shfl_xor(n00, 32); n01 += __shfl_xor(n01, 32);
      n10 += __shfl_xor(n10, 32); n11 += __shfl_xor(n11, 32);
      n20 += __shfl_xor(n20, 32); n21 += __shfl_xor(n21, 32);
      W00 += __shfl_xor(W00, 32); W01 += __shfl_xor(W01, 32); W11 += __shfl_xor(W11, 32);

      double n02 = sx0 - n00 - n01;
      double n12 = sx1 - n10 - n11;
      double n22 = sx2 - n20 - n21;
      double W02 = den0 - W00 - W01;
      double W12 = den1 - W01 - W11;
      double W22 = den2 - W02 - W12;

      double r0 = rcp_nr(den0 + 1e-10);
      double r1 = rcp_nr(den1 + 1e-10);
      double r2 = rcp_nr(den2 + 1e-10);
      double c00 = n00 * r0, c01 = n01 * r1, c02 = n02 * r2;
      double c10 = n10 * r0, c11 = n11 * r1, c12 = n12 * r2;
      double c20 = n20 * r0, c21 = n21 * r1, c22 = n22 * r2;

      double loss =
          c00 * (W00 * c00 + W01 * c01 + W02 * c02 - 2.0 * n00) +
          c01 * (W01 * c00 + W11 * c01 + W12 * c02 - 2.0 * n01) +
          c02 * (W02 * c00 + W12 * c01 + W22 * c02 - 2.0 * n02) +
          c10 * (W00 * c10 + W01 * c11 + W02 * c12 - 2.0 * n10) +
          c11 * (W01 * c10 + W11 * c11 + W12 * c12 - 2.0 * n11) +
          c12 * (W02 * c10 + W12 * c11 + W22 * c12 - 2.0 * n12) +
          c20 * (W00 * c20 + W01 * c21 + W02 * c22 - 2.0 * n20) +
          c21 * (W01 * c20 + W11 * c21 + W12 * c22 - 2.0 * n21) +
          c22 * (W02 * c20 + W12 * c21 + W22 * c22 - 2.0 * n22);

      double bl = (cand < 31) ? loss : (double)INFINITY;
      int bi0 = cand;
#pragma unroll
      for (int m = 1; m <= 16; m <<= 1) {
        double ol = __shfl_xor(bl, m);
        int oi = __shfl_xor(bi0, m);
        if (ol < bl || (ol == bl && oi < bi0)) { bl = ol; bi0 = oi; }
      }
      bi = bi0;
    }

    double upd = (i < 3) ? angd(bi) : xyd(bi);
    if (i == 0) q0 += upd;
    else if (i == 1) q1 += upd;
    else if (i == 2) q2 += upd;
    else if (i == 3) q3 += upd;
    else q4 += upd;
  }

  if (lane == 0) {
    pout[patch * 5 + 0] = q0;
    pout[patch * 5 + 1] = q1;
    pout[patch * 5 + 2] = q2;
    pout[patch * 5 + 3] = q3;
    pout[patch * 5 + 4] = q4;
  }
}

// ---------------- Kernel B: final reconstruction + fold (atomic) --------
__global__ void __launch_bounds__(256) foj_final(const float* __restrict__ x,
                                                 const double* __restrict__ pin,
                                                 float* __restrict__ out) {
  int lane = threadIdx.x & 63;
  int patch = blockIdx.x * 4 + (threadIdx.x >> 6);
  if (patch >= NPATCH) return;
  int ph = patch / WP_;
  int pw = patch - ph * WP_;
  double q0 = pin[patch * 5 + 0];
  double q1 = pin[patch * 5 + 1];
  double q2 = pin[patch * 5 + 2];
  double x0 = pin[patch * 5 + 3];
  double y0 = pin[patch * 5 + 4];

  JPd j = jprep_d(q0, q1, q2);
  int pi2 = lane >> 3, pj = lane & 7;
  double dx = lin8d(pj) - x0;
  double dy = lin8d(pi2) - y0;
  double d13, d42;
  jdist_d(j, dx, dy, d13, d42);
  double h1 = 0.5 + 0.31830988618379067154 * atan(d13 * 100.0);  // ocml
  double h2 = 0.5 + 0.31830988618379067154 * atan(d42 * 100.0);
  double w0 = 1.0 - h1;
  double w1 = h1 * (1.0 - h2);
  double w2 = h1 * h2;

  int oy = ph * 4 + pi2, ox = pw * 4 + pj;
  double im0 = (double)x[oy * 256 + ox];
  double im1 = (double)x[65536 + oy * 256 + ox];
  double im2 = (double)x[131072 + oy * 256 + ox];

  double red[12] = {w0, w1, w2,
                    im0 * w0, im0 * w1, im0 * w2,
                    im1 * w0, im1 * w1, im1 * w2,
                    im2 * w0, im2 * w1, im2 * w2};
#pragma unroll
  for (int t = 0; t < 12; ++t) {
    double v = red[t];
#pragma unroll
    for (int m = 1; m <= 32; m <<= 1) v += __shfl_xor(v, m);
    red[t] = v;
  }
  double e0 = red[0] + 1e-10, e1 = red[1] + 1e-10, e2 = red[2] + 1e-10;
  double pv0 = w0 * (red[3] / e0) + w1 * (red[4] / e1) + w2 * (red[5] / e2);
  double pv1 = w0 * (red[6] / e0) + w1 * (red[7] / e1) + w2 * (red[8] / e2);
  double pv2 = w0 * (red[9] / e0) + w1 * (red[10] / e1) + w2 * (red[11] / e2);

  double minabs = (d13 < 0.0) ? -d13
                              : ((d42 < 0.0) ? fmin(d13, -d42) : fmin(d13, d42));
  double tb = minabs / 0.05;
  double bnd = 1.0 / (1.0 + tb * tb);

  atomicAdd(&out[oy * 256 + ox], (float)pv0);
  atomicAdd(&out[65536 + oy * 256 + ox], (float)pv1);
  atomicAdd(&out[131072 + oy * 256 + ox], (float)pv2);
  atomicAdd(&out[196608 + oy * 256 + ox], (float)bnd);
}

// ---------------- Kernel C: divide by num_patches -----------------------
__global__ void __launch_bounds__(256) foj_norm(float* __restrict__ out) {
  int idx = blockIdx.x * 256 + threadIdx.x;
  int y = idx >> 8, xx = idx & 255;
  int hlo = (y >= 4) ? ((y - 4) >> 2) : 0;
  int hhi = min(62, y >> 2);
  int wlo = (xx >= 4) ? ((xx - 4) >> 2) : 0;
  int whi = min(62, xx >> 2);
  float np_ = (float)((hhi - hlo + 1) * (whi - wlo + 1));
  out[idx] /= np_;
  out[65536 + idx] /= np_;
  out[131072 + idx] /= np_;
  out[196608 + idx] /= np_;
}

extern "C" void kernel_launch(void* const* d_in, const int* in_sizes, int n_in,
                              void* d_out, int out_size, void* d_ws, size_t ws_size,
                              hipStream_t stream) {
  const float* x = (const float*)d_in[0];
  float* out = (float*)d_out;
  double* pws = (double*)d_ws;  // 3969*5 doubles = ~159 KB scratch

  foj_descent<<<(NPATCH + 3) / 4, 256, 0, stream>>>(x, pws);
  hipMemsetAsync(d_out, 0, (size_t)out_size * sizeof(float), stream);
  foj_final<<<(NPATCH + 3) / 4, 256, 0, stream>>>(x, pws, out);
  foj_norm<<<256, 256, 0, stream>>>(out);
}

// Round 13
// 120.346 us; speedup vs baseline: 14.9397x; 1.1374x over previous
//
#include <hip/hip_runtime.h>
#include <math.h>

#define WP_ 63
#define NPATCH 3969
#define PI_D 3.141592653589793
#define TWO_PI_D 6.283185307179586476925287
#define BANDF 4e-3f

typedef float f32x2 __attribute__((ext_vector_type(2)));
__device__ __forceinline__ f32x2 v2(float s) { return (f32x2){s, s}; }
__device__ __forceinline__ f32x2 fma2(f32x2 a, f32x2 b, f32x2 c) {
  return __builtin_elementwise_fma(a, b, c);
}

// numpy remainder(v, 2pi) for v in (-3pi, 4pi): branchless, BIT-EXACT vs
// fmod-based (fmod exact for |v|<2pi; Sterbenz for the +-2pi corrections).
__device__ __forceinline__ double remtp_d(double v) {
  double r = (v < 0.0) ? v + TWO_PI_D : v;
  r = (r < 0.0) ? r + TWO_PI_D : r;
  r = (r >= TWO_PI_D) ? r - TWO_PI_D : r;
  return r;
}

__device__ __forceinline__ double lin8d(int i) {
  if (i == 7) return 1.0;
  return __dadd_rn(__dmul_rn((double)i, 2.0 / 7.0), -1.0);
}
__device__ __forceinline__ double angd(int n) {
  return __dmul_rn((double)n, TWO_PI_D / 31.0);
}
__device__ __forceinline__ double xyd(int n) {
  if (n == 30) return 3.0;
  return __dadd_rn(__dmul_rn((double)n, 6.0 / 30.0), -3.0);
}

__device__ __forceinline__ double pow35_d(double x) {
#pragma clang fp contract(off)
  double x2 = x * x;
  double r = x * x2;
  double b = x2 * x2;
  b = b * b; b = b * b; b = b * b;
  return r * b;
}

__device__ __forceinline__ double rcp_nr(double d) {
  double r;
  asm("v_rcp_f64 %0, %1" : "=v"(r) : "v"(d));
  r = fma(fma(-d, r, 1.0), r, r);
  r = fma(fma(-d, r, 1.0), r, r);
  return r;
}

// branchless sincos for 0 <= x < ~13 (fdlibm kernels, 2-part Cody-Waite)
__device__ __forceinline__ void sincos_fast(double x, double* so, double* co) {
  double kd = rint(x * 6.36619772367581382433e-01);
  int q = (int)kd & 3;
  double r = fma(-kd, 1.57079632673412561417e+00, x);
  r = fma(-kd, 6.07710050650619224932e-11, r);
  double z = r * r;
  double ps = 1.58969099521155010221e-10;
  ps = fma(z, ps, -2.50507602534068634195e-08);
  ps = fma(z, ps, 2.75573137070700676789e-06);
  ps = fma(z, ps, -1.98412698298579493134e-04);
  ps = fma(z, ps, 8.33333333332248946124e-03);
  ps = fma(z, ps, -1.66666666666666324348e-01);
  double sr = fma(z * r, ps, r);
  double pc = -1.13596475577881948265e-11;
  pc = fma(z, pc, 2.08757232129817482790e-09);
  pc = fma(z, pc, -2.75573143513906633035e-07);
  pc = fma(z, pc, 2.48015872894767294178e-05);
  pc = fma(z, pc, -1.38888888888741095749e-03);
  pc = fma(z, pc, 4.16666666666666019037e-02);
  double cr = fma(z, fma(z, pc, -0.5), 1.0);
  bool swp = q & 1;
  double s0 = swp ? cr : sr;
  double c0 = swp ? sr : cr;
  *so = (q & 2) ? -s0 : s0;
  *co = (((q + 1) & 2)) ? -c0 : c0;
}

// ---------- atan tables ----------
// f64: 57 entries, old indexing (verify path byte-identical to r9-r11).
// f32: 58 entries, [0]={0,0} tiny-bin, idx = clamp(ia,-1,55)+1.
#define TABN 57
__device__ __forceinline__ void build_atan_tab(double2* tab, float2* tabf) {
  int k = threadIdx.x;
  if (k < 56) {
    int hi = ((4076 + k) << 18) | (1 << 17);
    double c = __hiloint2double(hi, 0);
    double a = atan(c);
    tab[k] = double2{c, a};
    tabf[k + 1] = float2{(float)c, (float)a};
  } else if (k == 56) {
    tab[56] = double2{0.0, 0.0};
    tabf[0] = float2{0.0f, 0.0f};
  }
}

// f64 pair hstep (verify path -- byte-identical to r9/r10/r11)
__device__ __forceinline__ void hstep2_tab(const double2* __restrict__ tab,
                                           double da, double db,
                                           double& ha, double& hb) {
  double za = da * 100.0, zb = db * 100.0;
  double ua = fabs(za), ub = fabs(zb);
  int ia = (__double2hiint(ua) >> 18) - 4076;
  int ib = (__double2hiint(ub) >> 18) - 4076;
  ia = (ia < 0) ? 56 : ((ia > 55) ? 55 : ia);
  ib = (ib < 0) ? 56 : ((ib > 55) ? 55 : ib);
  double2 ea = tab[ia];
  double2 eb = tab[ib];
  double ta = (ua - ea.x) * rcp_nr(fma(ua, ea.x, 1.0));
  double tb = (ub - eb.x) * rcp_nr(fma(ub, eb.x, 1.0));
  double z2a = ta * ta, z2b = tb * tb;
  double pa = 1.0 / 13.0, pb = 1.0 / 13.0;
  pa = fma(z2a, pa, -1.0 / 11.0); pb = fma(z2b, pb, -1.0 / 11.0);
  pa = fma(z2a, pa, 1.0 / 9.0);   pb = fma(z2b, pb, 1.0 / 9.0);
  pa = fma(z2a, pa, -1.0 / 7.0);  pb = fma(z2b, pb, -1.0 / 7.0);
  pa = fma(z2a, pa, 1.0 / 5.0);   pb = fma(z2b, pb, 1.0 / 5.0);
  pa = fma(z2a, pa, -1.0 / 3.0);  pb = fma(z2b, pb, -1.0 / 3.0);
  pa = fma(z2a, pa, 1.0);         pb = fma(z2b, pb, 1.0);
  double aa = fma(ta, pa, ea.y);
  double ab = fma(tb, pb, eb.y);
  aa = copysign(aa, za);
  ab = copysign(ab, zb);
  ha = fma(aa, 0.31830988618379067154, 0.5);
  hb = fma(ab, 0.31830988618379067154, 0.5);
}

// f32 packed hstep over a PIXEL PAIR of one distance field (trimmed: raw
// hw rcp (err~1e-7 -> h-err ~2e-9), 1-term poly (h-err ~6e-8); both
// negligible vs the 4e-3 band).
__device__ __forceinline__ f32x2 hstepv(const float2* __restrict__ tabf,
                                        f32x2 d) {
  f32x2 z = d * 100.0f;
  f32x2 u = __builtin_elementwise_abs(z);
  int ia = (int)(__float_as_uint(u.x) >> 21) - 492;
  int ib = (int)(__float_as_uint(u.y) >> 21) - 492;
  ia = min(max(ia, -1), 55) + 1;
  ib = min(max(ib, -1), 55) + 1;
  float2 ea = tabf[ia], eb = tabf[ib];
  f32x2 ec = {ea.x, eb.x};
  f32x2 ey = {ea.y, eb.y};
  f32x2 den = fma2(u, ec, v2(1.0f));
  float ra, rb;
  asm("v_rcp_f32 %0, %1" : "=v"(ra) : "v"(den.x));
  asm("v_rcp_f32 %0, %1" : "=v"(rb) : "v"(den.y));
  f32x2 r = {ra, rb};
  f32x2 t = (u - ec) * r;
  f32x2 p = fma2(t * t, v2(-0.33333334f), v2(1.0f));
  f32x2 a = fma2(t, p, ey);
  a = __builtin_elementwise_copysign(a, z);
  return fma2(a, v2(0.31830987f), v2(0.5f));
}

struct JPd {
  double s1, c1, s2, c2, s3, c3, s4, c4;
  double sg13, sg42, gt13, gt42;
};

__device__ JPd jprep_d(double p0, double p1, double p2) {
#pragma clang fp contract(off)
  double r0 = remtp_d(p0), r1 = remtp_d(p1), r2 = remtp_d(p2);
  double mn = fmin(r0, r1), mx = fmax(r0, r1);
  double a1 = fmin(mn, r2);
  double a3 = fmax(mx, r2);
  double a2 = fmax(mn, fmin(mx, r2));
  double remm = remtp_d(0.5 * (a1 - a3));
  double a4 = 0.5 * (a1 + a3) + ((remm >= PI_D) ? PI_D : 0.0);
  JPd j;
  double r42 = remtp_d(a2 - a4);
  j.sg42 = (r42 < PI_D) ? 1.0 : -1.0;
  j.gt42 = pow35_d(r42 / PI_D - 1.0) * 0.1;
  double r13 = remtp_d(a3 - a1);
  j.sg13 = (r13 < PI_D) ? 1.0 : -1.0;
  j.gt13 = pow35_d(r13 / PI_D - 1.0) * 0.1;
  sincos_fast(a1, &j.s1, &j.c1);
  sincos_fast(a2, &j.s2, &j.c2);
  sincos_fast(a3, &j.s3, &j.c3);
  sincos_fast(a4, &j.s4, &j.c4);
  return j;
}

__device__ __forceinline__ void jdist_d(const JPd& j, double dx, double dy,
                                        double& d13, double& d42) {
  double hl1 = (-j.s1) * dx + j.c1 * dy;
  double hl2 = (-j.s2) * dx + j.c2 * dy;
  double hl3 = (-j.s3) * dx + j.c3 * dy;
  double hl4 = (-j.s4) * dx + j.c4 * dy;
  d13 = j.sg13 * fmin(j.sg13 * hl1, (-j.sg13) * hl3) + j.gt13;
  d42 = j.sg42 * fmin(j.sg42 * hl4, (-j.sg42) * hl2) + j.gt42;
}

// ---------------- Kernel A: descent, packed-f32 prescreen + f64 verify ---
__global__ void __launch_bounds__(256)
foj_descent(const float* __restrict__ x, double* __restrict__ pout) {
  const int tid = threadIdx.x;
  const int wv = tid >> 6;
  const int lane = tid & 63;
  const int hp = lane >> 5;
  const int cand = lane & 31;
  const int patch = blockIdx.x * 4 + wv;

  __shared__ double2 stab[TABN];
  __shared__ float2 stabf[TABN + 1];
  __shared__ float4 simg[4][64];       // AoS for verify + sums
  __shared__ float simgp[4][3][64];    // SoA planes for packed prescreen
  build_atan_tab(stab, stabf);
  if (patch < NPATCH) {
    int ph = patch / WP_;
    int pw = patch - ph * WP_;
    int py = lane >> 3, pxx = lane & 7;
    int base = (ph * 4 + py) * 256 + (pw * 4 + pxx);
    float4 v;
    v.x = x[base];
    v.y = x[65536 + base];
    v.z = x[131072 + base];
    v.w = 0.0f;
    simg[wv][lane] = v;
    simgp[wv][0][lane] = v.x;
    simgp[wv][1][lane] = v.y;
    simgp[wv][2][lane] = v.z;
  }
  __syncthreads();
  if (patch >= NPATCH) return;
  const float4* sp = simg[wv];

  // per-patch channel sums
  double sx0 = 0.0, sx1 = 0.0, sx2 = 0.0;
  {
    const float4* hbase = sp + hp * 32;
#pragma unroll
    for (int t = 0; t < 32; ++t) {
      float4 im = hbase[t];
      sx0 += (double)im.x; sx1 += (double)im.y; sx2 += (double)im.z;
    }
    sx0 += __shfl_xor(sx0, 32);
    sx1 += __shfl_xor(sx1, 32);
    sx2 += __shfl_xor(sx2, 32);
  }
  const float sx0f = (float)sx0, sx1f = (float)sx1, sx2f = (float)sx2;

  double q0 = 0.0, q1 = 0.0, q2 = 0.0, q3 = 0.0, q4 = 0.0;

#pragma unroll 1
  for (int i = 0; i < 5; ++i) {
    double rv = (i < 3) ? angd(cand) : xyd(cand);
    double p0 = q0 + ((i == 0) ? rv : 0.0);
    double p1 = q1 + ((i == 1) ? rv : 0.0);
    double p2 = q2 + ((i == 2) ? rv : 0.0);
    double x0 = q3 + ((i == 3) ? rv : 0.0);
    double y0 = q4 + ((i == 4) ? rv : 0.0);

    JPd j = jprep_d(p0, p1, p2);  // f64 always: discrete decisions exact

    // ---------------- packed f32 prescreen (pixel-pair lanes) -----------
    float blf;
    {
      f32x2 ns1v = v2((float)(-j.s1)), ns2v = v2((float)(-j.s2));
      f32x2 ns3v = v2((float)(-j.s3)), ns4v = v2((float)(-j.s4));
      float c1f = (float)j.c1, c2f = (float)j.c2;
      float c3f = (float)j.c3, c4f = (float)j.c4;
      f32x2 sg13v = v2((float)j.sg13), sg42v = v2((float)j.sg42);
      f32x2 nsg13v = -sg13v, nsg42v = -sg42v;
      f32x2 gt13v = v2((float)j.gt13), gt42v = v2((float)j.gt42);
      f32x2 dxp[4];
#pragma unroll
      for (int t = 0; t < 4; ++t)
        dxp[t] = (f32x2){(float)(lin8d(2 * t) - x0),
                         (float)(lin8d(2 * t + 1) - x0)};

      f32x2 den0v = {0, 0}, den1v = {0, 0}, den2v = {0, 0};
      f32x2 n00v = {0, 0}, n01v = {0, 0}, n10v = {0, 0}, n11v = {0, 0};
      f32x2 n20v = {0, 0}, n21v = {0, 0};
      f32x2 W00v = {0, 0}, W01v = {0, 0}, W11v = {0, 0};
#pragma unroll 1
      for (int r = 0; r < 4; ++r) {
        int iyy = hp * 4 + r;
        double liny = (iyy == 7) ? 1.0
                    : __dadd_rn(__dmul_rn((double)iyy, 2.0 / 7.0), -1.0);
        float dyf = (float)(liny - y0);
        f32x2 cdy1 = v2(c1f * dyf), cdy2 = v2(c2f * dyf);
        f32x2 cdy3 = v2(c3f * dyf), cdy4 = v2(c4f * dyf);
        const float* q0p = &simgp[wv][0][hp * 32 + r * 8];
        const float* q1p = &simgp[wv][1][hp * 32 + r * 8];
        const float* q2p = &simgp[wv][2][hp * 32 + r * 8];
#pragma unroll
        for (int cp = 0; cp < 4; ++cp) {
          f32x2 dxv = dxp[cp];
          f32x2 hl1 = fma2(ns1v, dxv, cdy1);
          f32x2 hl3 = fma2(ns3v, dxv, cdy3);
          f32x2 hl4 = fma2(ns4v, dxv, cdy4);
          f32x2 hl2 = fma2(ns2v, dxv, cdy2);
          f32x2 d13 = fma2(sg13v,
              __builtin_elementwise_min(sg13v * hl1, nsg13v * hl3), gt13v);
          f32x2 d42 = fma2(sg42v,
              __builtin_elementwise_min(sg42v * hl4, nsg42v * hl2), gt42v);
          f32x2 h1 = hstepv(stabf, d13);
          f32x2 h2 = hstepv(stabf, d42);
          f32x2 w0 = v2(1.0f) - h1;
          f32x2 om = v2(1.0f) - h2;
          f32x2 w1 = h1 * om;
          f32x2 w2 = h1 * h2;
          f32x2 i0 = *(const f32x2*)(q0p + 2 * cp);
          f32x2 i1 = *(const f32x2*)(q1p + 2 * cp);
          f32x2 i2 = *(const f32x2*)(q2p + 2 * cp);
          den0v += w0; den1v += w1; den2v += w2;
          n00v = fma2(i0, w0, n00v); n01v = fma2(i0, w1, n01v);
          n10v = fma2(i1, w0, n10v); n11v = fma2(i1, w1, n11v);
          n20v = fma2(i2, w0, n20v); n21v = fma2(i2, w1, n21v);
          W00v = fma2(w0, w0, W00v); W01v = fma2(w0, w1, W01v);
          W11v = fma2(w1, w1, W11v);
        }
      }
      float den0f = den0v.x + den0v.y, den1f = den1v.x + den1v.y;
      float den2f = den2v.x + den2v.y;
      float n00f = n00v.x + n00v.y, n01f = n01v.x + n01v.y;
      float n10f = n10v.x + n10v.y, n11f = n11v.x + n11v.y;
      float n20f = n20v.x + n20v.y, n21f = n21v.x + n21v.y;
      float W00f = W00v.x + W00v.y, W01f = W01v.x + W01v.y;
      float W11f = W11v.x + W11v.y;

      den0f += __shfl_xor(den0f, 32); den1f += __shfl_xor(den1f, 32); den2f += __shfl_xor(den2f, 32);
      n00f += __shfl_xor(n00f, 32); n01f += __shfl_xor(n01f, 32);
      n10f += __shfl_xor(n10f, 32); n11f += __shfl_xor(n11f, 32);
      n20f += __shfl_xor(n20f, 32); n21f += __shfl_xor(n21f, 32);
      W00f += __shfl_xor(W00f, 32); W01f += __shfl_xor(W01f, 32); W11f += __shfl_xor(W11f, 32);

      float n02f = sx0f - n00f - n01f;
      float n12f = sx1f - n10f - n11f;
      float n22f = sx2f - n20f - n21f;
      float W02f = den0f - W00f - W01f;
      float W12f = den1f - W01f - W11f;
      float W22f = den2f - W02f - W12f;

      float e0 = den0f + 1e-10f, e1 = den1f + 1e-10f, e2 = den2f + 1e-10f;
      float r0f, r1f, r2f;
      asm("v_rcp_f32 %0, %1" : "=v"(r0f) : "v"(e0));
      asm("v_rcp_f32 %0, %1" : "=v"(r1f) : "v"(e1));
      asm("v_rcp_f32 %0, %1" : "=v"(r2f) : "v"(e2));
      r0f = fmaf(fmaf(-e0, r0f, 1.0f), r0f, r0f);
      r1f = fmaf(fmaf(-e1, r1f, 1.0f), r1f, r1f);
      r2f = fmaf(fmaf(-e2, r2f, 1.0f), r2f, r2f);
      float c00 = n00f * r0f, c01 = n01f * r1f, c02 = n02f * r2f;
      float c10 = n10f * r0f, c11 = n11f * r1f, c12 = n12f * r2f;
      float c20 = n20f * r0f, c21 = n21f * r1f, c22 = n22f * r2f;

      float lossf =
          c00 * (W00f * c00 + W01f * c01 + W02f * c02 - 2.0f * n00f) +
          c01 * (W01f * c00 + W11f * c01 + W12f * c02 - 2.0f * n01f) +
          c02 * (W02f * c00 + W12f * c01 + W22f * c02 - 2.0f * n02f) +
          c10 * (W00f * c10 + W01f * c11 + W02f * c12 - 2.0f * n10f) +
          c11 * (W01f * c10 + W11f * c11 + W12f * c12 - 2.0f * n11f) +
          c12 * (W02f * c10 + W12f * c11 + W22f * c12 - 2.0f * n12f) +
          c20 * (W00f * c20 + W01f * c21 + W02f * c22 - 2.0f * n20f) +
          c21 * (W01f * c20 + W11f * c21 + W12f * c22 - 2.0f * n21f) +
          c22 * (W02f * c20 + W12f * c21 + W22f * c22 - 2.0f * n22f);

      blf = (cand < 31) ? lossf : 3.0e38f;
    }

    float mnf = blf;
#pragma unroll
    for (int m = 1; m <= 16; m <<= 1) mnf = fminf(mnf, __shfl_xor(mnf, m));
    bool inb = (cand < 31) && (blf <= mnf + BANDF);
    unsigned bal32 = (unsigned)__ballot(inb);

    int bi;
    if (__popc(bal32) == 1) {
      bi = __ffs(bal32) - 1;   // unique winner: f32 decision is safe
    } else {
      // ---------------- f64 verify pass (byte-identical to r9) ----------
      double den0 = 0, den1 = 0, den2 = 0;
      double n00 = 0, n01 = 0, n10 = 0, n11 = 0, n20 = 0, n21 = 0;
      double W00 = 0, W01 = 0, W11 = 0;
#pragma unroll 1
      for (int r = 0; r < 4; ++r) {
        int iyy = hp * 4 + r;
        double liny = (iyy == 7) ? 1.0
                    : __dadd_rn(__dmul_rn((double)iyy, 2.0 / 7.0), -1.0);
        double dy = liny - y0;
        const float4* rowp = sp + hp * 32 + r * 8;
#pragma unroll
        for (int c = 0; c < 8; ++c) {
          double dx = lin8d(c) - x0;
          double d13, d42;
          jdist_d(j, dx, dy, d13, d42);
          double h1, h2;
          hstep2_tab(stab, d13, d42, h1, h2);
          double w0 = 1.0 - h1;
          double w1 = h1 * (1.0 - h2);
          double w2 = h1 * h2;
          float4 im = rowp[c];
          double ix = (double)im.x, iy2 = (double)im.y, iz = (double)im.z;
          den0 += w0; den1 += w1; den2 += w2;
          n00 += ix * w0; n01 += ix * w1;
          n10 += iy2 * w0; n11 += iy2 * w1;
          n20 += iz * w0; n21 += iz * w1;
          W00 += w0 * w0; W01 += w0 * w1; W11 += w1 * w1;
        }
      }
      den0 += __shfl_xor(den0, 32); den1 += __shfl_xor(den1, 32); den2 += __shfl_xor(den2, 32);
      n00 += __shfl_xor(n00, 32); n01 += __shfl_xor(n01, 32);
      n10 += __shfl_xor(n10, 32); n11 += __shfl_xor(n11, 32);
      n20 += __shfl_xor(n20, 32); n21 += __shfl_xor(n21, 32);
      W00 += __shfl_xor(W00, 32); W01 += __shfl_xor(W01, 32); W11 += __shfl_xor(W11, 32);

      double n02 = sx0 - n00 - n01;
      double n12 = sx1 - n10 - n11;
      double n22 = sx2 - n20 - n21;
      double W02 = den0 - W00 - W01;
      double W12 = den1 - W01 - W11;
      double W22 = den2 - W02 - W12;

      double r0 = rcp_nr(den0 + 1e-10);
      double r1 = rcp_nr(den1 + 1e-10);
      double r2 = rcp_nr(den2 + 1e-10);
      double c00 = n00 * r0, c01 = n01 * r1, c02 = n02 * r2;
      double c10 = n10 * r0, c11 = n11 * r1, c12 = n12 * r2;
      double c20 = n20 * r0, c21 = n21 * r1, c22 = n22 * r2;

      double loss =
          c00 * (W00 * c00 + W01 * c01 + W02 * c02 - 2.0 * n00) +
          c01 * (W01 * c00 + W11 * c01 + W12 * c02 - 2.0 * n01) +
          c02 * (W02 * c00 + W12 * c01 + W22 * c02 - 2.0 * n02) +
          c10 * (W00 * c10 + W01 * c11 + W02 * c12 - 2.0 * n10) +
          c11 * (W01 * c10 + W11 * c11 + W12 * c12 - 2.0 * n11) +
          c12 * (W02 * c10 + W12 * c11 + W22 * c12 - 2.0 * n12) +
          c20 * (W00 * c20 + W01 * c21 + W02 * c22 - 2.0 * n20) +
          c21 * (W01 * c20 + W11 * c21 + W12 * c22 - 2.0 * n21) +
          c22 * (W02 * c20 + W12 * c21 + W22 * c22 - 2.0 * n22);

      double bl = (cand < 31) ? loss : (double)INFINITY;
      int bi0 = cand;
#pragma unroll
      for (int m = 1; m <= 16; m <<= 1) {
        double ol = __shfl_xor(bl, m);
        int oi = __shfl_xor(bi0, m);
        if (ol < bl || (ol == bl && oi < bi0)) { bl = ol; bi0 = oi; }
      }
      bi = bi0;
    }

    double upd = (i < 3) ? angd(bi) : xyd(bi);
    if (i == 0) q0 += upd;
    else if (i == 1) q1 += upd;
    else if (i == 2) q2 += upd;
    else if (i == 3) q3 += upd;
    else q4 += upd;
  }

  if (lane == 0) {
    pout[patch * 5 + 0] = q0;
    pout[patch * 5 + 1] = q1;
    pout[patch * 5 + 2] = q2;
    pout[patch * 5 + 3] = q3;
    pout[patch * 5 + 4] = q4;
  }
}

// ---------------- Kernel B: final reconstruction + fold (atomic) --------
__global__ void __launch_bounds__(256) foj_final(const float* __restrict__ x,
                                                 const double* __restrict__ pin,
                                                 float* __restrict__ out) {
  int lane = threadIdx.x & 63;
  int patch = blockIdx.x * 4 + (threadIdx.x >> 6);
  if (patch >= NPATCH) return;
  int ph = patch / WP_;
  int pw = patch - ph * WP_;
  double q0 = pin[patch * 5 + 0];
  double q1 = pin[patch * 5 + 1];
  double q2 = pin[patch * 5 + 2];
  double x0 = pin[patch * 5 + 3];
  double y0 = pin[patch * 5 + 4];

  JPd j = jprep_d(q0, q1, q2);
  int pi2 = lane >> 3, pj = lane & 7;
  double dx = lin8d(pj) - x0;
  double dy = lin8d(pi2) - y0;
  double d13, d42;
  jdist_d(j, dx, dy, d13, d42);
  double h1 = 0.5 + 0.31830988618379067154 * atan(d13 * 100.0);  // ocml
  double h2 = 0.5 + 0.31830988618379067154 * atan(d42 * 100.0);
  double w0 = 1.0 - h1;
  double w1 = h1 * (1.0 - h2);
  double w2 = h1 * h2;

  int oy = ph * 4 + pi2, ox = pw * 4 + pj;
  double im0 = (double)x[oy * 256 + ox];
  double im1 = (double)x[65536 + oy * 256 + ox];
  double im2 = (double)x[131072 + oy * 256 + ox];

  double red[12] = {w0, w1, w2,
                    im0 * w0, im0 * w1, im0 * w2,
                    im1 * w0, im1 * w1, im1 * w2,
                    im2 * w0, im2 * w1, im2 * w2};
#pragma unroll
  for (int t = 0; t < 12; ++t) {
    double v = red[t];
#pragma unroll
    for (int m = 1; m <= 32; m <<= 1) v += __shfl_xor(v, m);
    red[t] = v;
  }
  double e0 = red[0] + 1e-10, e1 = red[1] + 1e-10, e2 = red[2] + 1e-10;
  double pv0 = w0 * (red[3] / e0) + w1 * (red[4] / e1) + w2 * (red[5] / e2);
  double pv1 = w0 * (red[6] / e0) + w1 * (red[7] / e1) + w2 * (red[8] / e2);
  double pv2 = w0 * (red[9] / e0) + w1 * (red[10] / e1) + w2 * (red[11] / e2);

  double minabs = (d13 < 0.0) ? -d13
                              : ((d42 < 0.0) ? fmin(d13, -d42) : fmin(d13, d42));
  double tb = minabs / 0.05;
  double bnd = 1.0 / (1.0 + tb * tb);

  atomicAdd(&out[oy * 256 + ox], (float)pv0);
  atomicAdd(&out[65536 + oy * 256 + ox], (float)pv1);
  atomicAdd(&out[131072 + oy * 256 + ox], (float)pv2);
  atomicAdd(&out[196608 + oy * 256 + ox], (float)bnd);
}

// ---------------- Kernel C: divide by num_patches -----------------------
__global__ void __launch_bounds__(256) foj_norm(float* __restrict__ out) {
  int idx = blockIdx.x * 256 + threadIdx.x;
  int y = idx >> 8, xx = idx & 255;
  int hlo = (y >= 4) ? ((y - 4) >> 2) : 0;
  int hhi = min(62, y >> 2);
  int wlo = (xx >= 4) ? ((xx - 4) >> 2) : 0;
  int whi = min(62, xx >> 2);
  float np_ = (float)((hhi - hlo + 1) * (whi - wlo + 1));
  out[idx] /= np_;
  out[65536 + idx] /= np_;
  out[131072 + idx] /= np_;
  out[196608 + idx] /= np_;
}

extern "C" void kernel_launch(void* const* d_in, const int* in_sizes, int n_in,
                              void* d_out, int out_size, void* d_ws, size_t ws_size,
                              hipStream_t stream) {
  const float* x = (const float*)d_in[0];
  float* out = (float*)d_out;
  double* pws = (double*)d_ws;  // 3969*5 doubles = ~159 KB scratch

  foj_descent<<<(NPATCH + 3) / 4, 256, 0, stream>>>(x, pws);
  hipMemsetAsync(d_out, 0, (size_t)out_size * sizeof(float), stream);
  foj_final<<<(NPATCH + 3) / 4, 256, 0, stream>>>(x, pws, out);
  foj_norm<<<256, 256, 0, stream>>>(out);
}

// Round 16
// 101.505 us; speedup vs baseline: 17.7128x; 1.1856x over previous
//
#include <hip/hip_runtime.h>
#include <math.h>

#define WP_ 63
#define NPATCH 3969
#define PI_D 3.141592653589793
#define TWO_PI_D 6.283185307179586476925287
#define BANDF 4e-3f

typedef float f32x2 __attribute__((ext_vector_type(2)));
__device__ __forceinline__ f32x2 v2(float s) { return (f32x2){s, s}; }
__device__ __forceinline__ f32x2 fma2(f32x2 a, f32x2 b, f32x2 c) {
  return __builtin_elementwise_fma(a, b, c);
}

// numpy remainder(v, 2pi) for v in (-3pi, 4pi): branchless, BIT-EXACT vs
// fmod-based (fmod exact for |v|<2pi; Sterbenz for the +-2pi corrections).
__device__ __forceinline__ double remtp_d(double v) {
  double r = (v < 0.0) ? v + TWO_PI_D : v;
  r = (r < 0.0) ? r + TWO_PI_D : r;
  r = (r >= TWO_PI_D) ? r - TWO_PI_D : r;
  return r;
}

__device__ __forceinline__ double lin8d(int i) {
  if (i == 7) return 1.0;
  return __dadd_rn(__dmul_rn((double)i, 2.0 / 7.0), -1.0);
}
__device__ __forceinline__ double angd(int n) {
  return __dmul_rn((double)n, TWO_PI_D / 31.0);
}
__device__ __forceinline__ double xyd(int n) {
  if (n == 30) return 3.0;
  return __dadd_rn(__dmul_rn((double)n, 6.0 / 30.0), -3.0);
}

__device__ __forceinline__ double pow35_d(double x) {
#pragma clang fp contract(off)
  double x2 = x * x;
  double r = x * x2;
  double b = x2 * x2;
  b = b * b; b = b * b; b = b * b;
  return r * b;
}

__device__ __forceinline__ double rcp_nr(double d) {
  double r;
  asm("v_rcp_f64 %0, %1" : "=v"(r) : "v"(d));
  r = fma(fma(-d, r, 1.0), r, r);
  r = fma(fma(-d, r, 1.0), r, r);
  return r;
}

// branchless sincos for 0 <= x < ~13 (fdlibm kernels, 2-part Cody-Waite)
__device__ __forceinline__ void sincos_fast(double x, double* so, double* co) {
  double kd = rint(x * 6.36619772367581382433e-01);
  int q = (int)kd & 3;
  double r = fma(-kd, 1.57079632673412561417e+00, x);
  r = fma(-kd, 6.07710050650619224932e-11, r);
  double z = r * r;
  double ps = 1.58969099521155010221e-10;
  ps = fma(z, ps, -2.50507602534068634195e-08);
  ps = fma(z, ps, 2.75573137070700676789e-06);
  ps = fma(z, ps, -1.98412698298579493134e-04);
  ps = fma(z, ps, 8.33333333332248946124e-03);
  ps = fma(z, ps, -1.66666666666666324348e-01);
  double sr = fma(z * r, ps, r);
  double pc = -1.13596475577881948265e-11;
  pc = fma(z, pc, 2.08757232129817482790e-09);
  pc = fma(z, pc, -2.75573143513906633035e-07);
  pc = fma(z, pc, 2.48015872894767294178e-05);
  pc = fma(z, pc, -1.38888888888741095749e-03);
  pc = fma(z, pc, 4.16666666666666019037e-02);
  double cr = fma(z, fma(z, pc, -0.5), 1.0);
  bool swp = q & 1;
  double s0 = swp ? cr : sr;
  double c0 = swp ? sr : cr;
  *so = (q & 2) ? -s0 : s0;
  *co = (((q + 1) & 2)) ? -c0 : c0;
}

// ---------- atan tables ----------
// f64: 57 entries, old indexing (verify path element math identical).
// f32: 58 entries, [0]={0,0} tiny-bin, idx = clamp(ia,-1,55)+1.
#define TABN 57
__device__ __forceinline__ void build_atan_tab(double2* tab, float2* tabf) {
  int k = threadIdx.x;
  if (k < 56) {
    int hi = ((4076 + k) << 18) | (1 << 17);
    double c = __hiloint2double(hi, 0);
    double a = atan(c);
    tab[k] = double2{c, a};
    tabf[k + 1] = float2{(float)c, (float)a};
  } else if (k == 56) {
    tab[56] = double2{0.0, 0.0};
    tabf[0] = float2{0.0f, 0.0f};
  }
}

// f64 pair hstep (element math identical to r9-r13)
__device__ __forceinline__ void hstep2_tab(const double2* __restrict__ tab,
                                           double da, double db,
                                           double& ha, double& hb) {
  double za = da * 100.0, zb = db * 100.0;
  double ua = fabs(za), ub = fabs(zb);
  int ia = (__double2hiint(ua) >> 18) - 4076;
  int ib = (__double2hiint(ub) >> 18) - 4076;
  ia = (ia < 0) ? 56 : ((ia > 55) ? 55 : ia);
  ib = (ib < 0) ? 56 : ((ib > 55) ? 55 : ib);
  double2 ea = tab[ia];
  double2 eb = tab[ib];
  double ta = (ua - ea.x) * rcp_nr(fma(ua, ea.x, 1.0));
  double tb = (ub - eb.x) * rcp_nr(fma(ub, eb.x, 1.0));
  double z2a = ta * ta, z2b = tb * tb;
  double pa = 1.0 / 13.0, pb = 1.0 / 13.0;
  pa = fma(z2a, pa, -1.0 / 11.0); pb = fma(z2b, pb, -1.0 / 11.0);
  pa = fma(z2a, pa, 1.0 / 9.0);   pb = fma(z2b, pb, 1.0 / 9.0);
  pa = fma(z2a, pa, -1.0 / 7.0);  pb = fma(z2b, pb, -1.0 / 7.0);
  pa = fma(z2a, pa, 1.0 / 5.0);   pb = fma(z2b, pb, 1.0 / 5.0);
  pa = fma(z2a, pa, -1.0 / 3.0);  pb = fma(z2b, pb, -1.0 / 3.0);
  pa = fma(z2a, pa, 1.0);         pb = fma(z2b, pb, 1.0);
  double aa = fma(ta, pa, ea.y);
  double ab = fma(tb, pb, eb.y);
  aa = copysign(aa, za);
  ab = copysign(ab, zb);
  ha = fma(aa, 0.31830988618379067154, 0.5);
  hb = fma(ab, 0.31830988618379067154, 0.5);
}

// f32 packed hstep over a PIXEL PAIR of one distance field (trimmed: raw
// hw rcp, 1-term poly; err ~<1e-5 in loss, vs 4e-3 band).
__device__ __forceinline__ f32x2 hstepv(const float2* __restrict__ tabf,
                                        f32x2 d) {
  f32x2 z = d * 100.0f;
  f32x2 u = __builtin_elementwise_abs(z);
  int ia = (int)(__float_as_uint(u.x) >> 21) - 492;
  int ib = (int)(__float_as_uint(u.y) >> 21) - 492;
  ia = min(max(ia, -1), 55) + 1;
  ib = min(max(ib, -1), 55) + 1;
  float2 ea = tabf[ia], eb = tabf[ib];
  f32x2 ec = {ea.x, eb.x};
  f32x2 ey = {ea.y, eb.y};
  f32x2 den = fma2(u, ec, v2(1.0f));
  float ra, rb;
  asm("v_rcp_f32 %0, %1" : "=v"(ra) : "v"(den.x));
  asm("v_rcp_f32 %0, %1" : "=v"(rb) : "v"(den.y));
  f32x2 r = {ra, rb};
  f32x2 t = (u - ec) * r;
  f32x2 p = fma2(t * t, v2(-0.33333334f), v2(1.0f));
  f32x2 a = fma2(t, p, ey);
  a = __builtin_elementwise_copysign(a, z);
  return fma2(a, v2(0.31830987f), v2(0.5f));
}

struct JPd {
  double s1, c1, s2, c2, s3, c3, s4, c4;
  double sg13, sg42, gt13, gt42;
};

__device__ JPd jprep_d(double p0, double p1, double p2) {
#pragma clang fp contract(off)
  double r0 = remtp_d(p0), r1 = remtp_d(p1), r2 = remtp_d(p2);
  double mn = fmin(r0, r1), mx = fmax(r0, r1);
  double a1 = fmin(mn, r2);
  double a3 = fmax(mx, r2);
  double a2 = fmax(mn, fmin(mx, r2));
  double remm = remtp_d(0.5 * (a1 - a3));
  double a4 = 0.5 * (a1 + a3) + ((remm >= PI_D) ? PI_D : 0.0);
  JPd j;
  double r42 = remtp_d(a2 - a4);
  j.sg42 = (r42 < PI_D) ? 1.0 : -1.0;
  j.gt42 = pow35_d(r42 / PI_D - 1.0) * 0.1;
  double r13 = remtp_d(a3 - a1);
  j.sg13 = (r13 < PI_D) ? 1.0 : -1.0;
  j.gt13 = pow35_d(r13 / PI_D - 1.0) * 0.1;
  sincos_fast(a1, &j.s1, &j.c1);
  sincos_fast(a2, &j.s2, &j.c2);
  sincos_fast(a3, &j.s3, &j.c3);
  sincos_fast(a4, &j.s4, &j.c4);
  return j;
}

__device__ __forceinline__ void jdist_d(const JPd& j, double dx, double dy,
                                        double& d13, double& d42) {
  double hl1 = (-j.s1) * dx + j.c1 * dy;
  double hl2 = (-j.s2) * dx + j.c2 * dy;
  double hl3 = (-j.s3) * dx + j.c3 * dy;
  double hl4 = (-j.s4) * dx + j.c4 * dy;
  d13 = j.sg13 * fmin(j.sg13 * hl1, (-j.sg13) * hl3) + j.gt13;
  d42 = j.sg42 * fmin(j.sg42 * hl4, (-j.sg42) * hl2) + j.gt42;
}

// ---------------- Kernel A: descent, packed-f32 prescreen + cooperative
// f64 verify (lane = pixel, only in-band candidates) ----------------------
__global__ void __launch_bounds__(256)
foj_descent(const float* __restrict__ x, double* __restrict__ pout) {
  const int tid = threadIdx.x;
  const int wv = tid >> 6;
  const int lane = tid & 63;
  const int hp = lane >> 5;
  const int cand = lane & 31;
  const int patch = blockIdx.x * 4 + wv;

  __shared__ double2 stab[TABN];
  __shared__ float2 stabf[TABN + 1];
  __shared__ float4 simg[4][64];       // AoS for verify + sums
  __shared__ float simgp[4][3][64];    // SoA planes for packed prescreen
  build_atan_tab(stab, stabf);
  if (patch < NPATCH) {
    int ph = patch / WP_;
    int pw = patch - ph * WP_;
    int py = lane >> 3, pxx = lane & 7;
    int base = (ph * 4 + py) * 256 + (pw * 4 + pxx);
    float4 v;
    v.x = x[base];
    v.y = x[65536 + base];
    v.z = x[131072 + base];
    v.w = 0.0f;
    simg[wv][lane] = v;
    simgp[wv][0][lane] = v.x;
    simgp[wv][1][lane] = v.y;
    simgp[wv][2][lane] = v.z;
  }
  __syncthreads();
  if (patch >= NPATCH) return;
  const float4* sp = simg[wv];

  // per-patch channel sums
  double sx0 = 0.0, sx1 = 0.0, sx2 = 0.0;
  {
    const float4* hbase = sp + hp * 32;
#pragma unroll
    for (int t = 0; t < 32; ++t) {
      float4 im = hbase[t];
      sx0 += (double)im.x; sx1 += (double)im.y; sx2 += (double)im.z;
    }
    sx0 += __shfl_xor(sx0, 32);
    sx1 += __shfl_xor(sx1, 32);
    sx2 += __shfl_xor(sx2, 32);
  }
  const float sx0f = (float)sx0, sx1f = (float)sx1, sx2f = (float)sx2;

  // this lane's pixel for cooperative verify (lane = pixel 0..63)
  const double vlinx = lin8d(lane & 7);
  const double vliny = lin8d(lane >> 3);
  const float4 vim = sp[lane];

  double q0 = 0.0, q1 = 0.0, q2 = 0.0, q3 = 0.0, q4 = 0.0;

#pragma unroll 1
  for (int i = 0; i < 5; ++i) {
    double rv = (i < 3) ? angd(cand) : xyd(cand);
    double p0 = q0 + ((i == 0) ? rv : 0.0);
    double p1 = q1 + ((i == 1) ? rv : 0.0);
    double p2 = q2 + ((i == 2) ? rv : 0.0);
    double x0 = q3 + ((i == 3) ? rv : 0.0);
    double y0 = q4 + ((i == 4) ? rv : 0.0);

    JPd j = jprep_d(p0, p1, p2);  // f64 always: discrete decisions exact

    // ---------------- packed f32 prescreen (pixel-pair lanes) -----------
    float blf;
    {
      f32x2 ns1v = v2((float)(-j.s1)), ns2v = v2((float)(-j.s2));
      f32x2 ns3v = v2((float)(-j.s3)), ns4v = v2((float)(-j.s4));
      float c1f = (float)j.c1, c2f = (float)j.c2;
      float c3f = (float)j.c3, c4f = (float)j.c4;
      f32x2 sg13v = v2((float)j.sg13), sg42v = v2((float)j.sg42);
      f32x2 nsg13v = -sg13v, nsg42v = -sg42v;
      f32x2 gt13v = v2((float)j.gt13), gt42v = v2((float)j.gt42);
      f32x2 dxp[4];
#pragma unroll
      for (int t = 0; t < 4; ++t)
        dxp[t] = (f32x2){(float)(lin8d(2 * t) - x0),
                         (float)(lin8d(2 * t + 1) - x0)};

      f32x2 den0v = {0, 0}, den1v = {0, 0}, den2v = {0, 0};
      f32x2 n00v = {0, 0}, n01v = {0, 0}, n10v = {0, 0}, n11v = {0, 0};
      f32x2 n20v = {0, 0}, n21v = {0, 0};
      f32x2 W00v = {0, 0}, W01v = {0, 0}, W11v = {0, 0};
#pragma unroll 1
      for (int r = 0; r < 4; ++r) {
        int iyy = hp * 4 + r;
        double liny = (iyy == 7) ? 1.0
                    : __dadd_rn(__dmul_rn((double)iyy, 2.0 / 7.0), -1.0);
        float dyf = (float)(liny - y0);
        f32x2 cdy1 = v2(c1f * dyf), cdy2 = v2(c2f * dyf);
        f32x2 cdy3 = v2(c3f * dyf), cdy4 = v2(c4f * dyf);
        const float* q0p = &simgp[wv][0][hp * 32 + r * 8];
        const float* q1p = &simgp[wv][1][hp * 32 + r * 8];
        const float* q2p = &simgp[wv][2][hp * 32 + r * 8];
#pragma unroll
        for (int cp = 0; cp < 4; ++cp) {
          f32x2 dxv = dxp[cp];
          f32x2 hl1 = fma2(ns1v, dxv, cdy1);
          f32x2 hl3 = fma2(ns3v, dxv, cdy3);
          f32x2 hl4 = fma2(ns4v, dxv, cdy4);
          f32x2 hl2 = fma2(ns2v, dxv, cdy2);
          f32x2 d13 = fma2(sg13v,
              __builtin_elementwise_min(sg13v * hl1, nsg13v * hl3), gt13v);
          f32x2 d42 = fma2(sg42v,
              __builtin_elementwise_min(sg42v * hl4, nsg42v * hl2), gt42v);
          f32x2 h1 = hstepv(stabf, d13);
          f32x2 h2 = hstepv(stabf, d42);
          f32x2 w0 = v2(1.0f) - h1;
          f32x2 om = v2(1.0f) - h2;
          f32x2 w1 = h1 * om;
          f32x2 w2 = h1 * h2;
          f32x2 i0 = *(const f32x2*)(q0p + 2 * cp);
          f32x2 i1 = *(const f32x2*)(q1p + 2 * cp);
          f32x2 i2 = *(const f32x2*)(q2p + 2 * cp);
          den0v += w0; den1v += w1; den2v += w2;
          n00v = fma2(i0, w0, n00v); n01v = fma2(i0, w1, n01v);
          n10v = fma2(i1, w0, n10v); n11v = fma2(i1, w1, n11v);
          n20v = fma2(i2, w0, n20v); n21v = fma2(i2, w1, n21v);
          W00v = fma2(w0, w0, W00v); W01v = fma2(w0, w1, W01v);
          W11v = fma2(w1, w1, W11v);
        }
      }
      float den0f = den0v.x + den0v.y, den1f = den1v.x + den1v.y;
      float den2f = den2v.x + den2v.y;
      float n00f = n00v.x + n00v.y, n01f = n01v.x + n01v.y;
      float n10f = n10v.x + n10v.y, n11f = n11v.x + n11v.y;
      float n20f = n20v.x + n20v.y, n21f = n21v.x + n21v.y;
      float W00f = W00v.x + W00v.y, W01f = W01v.x + W01v.y;
      float W11f = W11v.x + W11v.y;

      den0f += __shfl_xor(den0f, 32); den1f += __shfl_xor(den1f, 32); den2f += __shfl_xor(den2f, 32);
      n00f += __shfl_xor(n00f, 32); n01f += __shfl_xor(n01f, 32);
      n10f += __shfl_xor(n10f, 32); n11f += __shfl_xor(n11f, 32);
      n20f += __shfl_xor(n20f, 32); n21f += __shfl_xor(n21f, 32);
      W00f += __shfl_xor(W00f, 32); W01f += __shfl_xor(W01f, 32); W11f += __shfl_xor(W11f, 32);

      float n02f = sx0f - n00f - n01f;
      float n12f = sx1f - n10f - n11f;
      float n22f = sx2f - n20f - n21f;
      float W02f = den0f - W00f - W01f;
      float W12f = den1f - W01f - W11f;
      float W22f = den2f - W02f - W12f;

      float e0 = den0f + 1e-10f, e1 = den1f + 1e-10f, e2 = den2f + 1e-10f;
      float r0f, r1f, r2f;
      asm("v_rcp_f32 %0, %1" : "=v"(r0f) : "v"(e0));
      asm("v_rcp_f32 %0, %1" : "=v"(r1f) : "v"(e1));
      asm("v_rcp_f32 %0, %1" : "=v"(r2f) : "v"(e2));
      r0f = fmaf(fmaf(-e0, r0f, 1.0f), r0f, r0f);
      r1f = fmaf(fmaf(-e1, r1f, 1.0f), r1f, r1f);
      r2f = fmaf(fmaf(-e2, r2f, 1.0f), r2f, r2f);
      float c00 = n00f * r0f, c01 = n01f * r1f, c02 = n02f * r2f;
      float c10 = n10f * r0f, c11 = n11f * r1f, c12 = n12f * r2f;
      float c20 = n20f * r0f, c21 = n21f * r1f, c22 = n22f * r2f;

      float lossf =
          c00 * (W00f * c00 + W01f * c01 + W02f * c02 - 2.0f * n00f) +
          c01 * (W01f * c00 + W11f * c01 + W12f * c02 - 2.0f * n01f) +
          c02 * (W02f * c00 + W12f * c01 + W22f * c02 - 2.0f * n02f) +
          c10 * (W00f * c10 + W01f * c11 + W02f * c12 - 2.0f * n10f) +
          c11 * (W01f * c10 + W11f * c11 + W12f * c12 - 2.0f * n11f) +
          c12 * (W02f * c10 + W12f * c11 + W22f * c12 - 2.0f * n12f) +
          c20 * (W00f * c20 + W01f * c21 + W02f * c22 - 2.0f * n20f) +
          c21 * (W01f * c20 + W11f * c21 + W12f * c22 - 2.0f * n21f) +
          c22 * (W02f * c20 + W12f * c21 + W22f * c22 - 2.0f * n22f);

      blf = (cand < 31) ? lossf : 3.0e38f;
    }

    float mnf = blf;
#pragma unroll
    for (int m = 1; m <= 16; m <<= 1) mnf = fminf(mnf, __shfl_xor(mnf, m));
    bool inb = (cand < 31) && (blf <= mnf + BANDF);
    unsigned bal32 = (unsigned)__ballot(inb);

    int bi;
    if (__popc(bal32) == 1) {
      bi = __ffs(bal32) - 1;   // unique winner: f32 decision is safe
    } else {
      // ---- cooperative f64 verify: lane = pixel, serial over in-band
      // candidates (ascending index = np.argmin first-index tie-break).
      // Out-of-band candidates provably lose: band(4e-3) >> 2*f32err.
      double bestLoss = (double)INFINITY;
      int bi0 = 0;
      unsigned rem = bal32;
#pragma unroll 1
      while (rem) {
        int c = __ffs(rem) - 1;
        rem &= rem - 1;
        // candidate c's params (q's are wave-uniform)
        double rvc = (i < 3) ? angd(c) : xyd(c);
        double x0c = q3 + ((i == 3) ? rvc : 0.0);
        double y0c = q4 + ((i == 4) ? rvc : 0.0);
        // broadcast candidate c's JPd from lane c
        JPd jc;
        jc.s1 = __shfl(j.s1, c);  jc.c1 = __shfl(j.c1, c);
        jc.s2 = __shfl(j.s2, c);  jc.c2 = __shfl(j.c2, c);
        jc.s3 = __shfl(j.s3, c);  jc.c3 = __shfl(j.c3, c);
        jc.s4 = __shfl(j.s4, c);  jc.c4 = __shfl(j.c4, c);
        jc.sg13 = __shfl(j.sg13, c); jc.sg42 = __shfl(j.sg42, c);
        jc.gt13 = __shfl(j.gt13, c); jc.gt42 = __shfl(j.gt42, c);

        double d13, d42;
        jdist_d(jc, vlinx - x0c, vliny - y0c, d13, d42);
        double h1, h2;
        hstep2_tab(stab, d13, d42, h1, h2);
        double w0 = 1.0 - h1;
        double w1 = h1 * (1.0 - h2);
        double w2 = h1 * h2;
        double ix = (double)vim.x, iy2 = (double)vim.y, iz = (double)vim.z;
        double s0 = w0, s1 = w1, s2 = w2;
        double s3 = ix * w0, s4 = ix * w1;
        double s5 = iy2 * w0, s6 = iy2 * w1;
        double s7 = iz * w0, s8 = iz * w1;
        double s9 = w0 * w0, s10 = w0 * w1, s11 = w1 * w1;
#pragma unroll
        for (int m = 1; m <= 32; m <<= 1) {
          s0 += __shfl_xor(s0, m);  s1 += __shfl_xor(s1, m);
          s2 += __shfl_xor(s2, m);  s3 += __shfl_xor(s3, m);
          s4 += __shfl_xor(s4, m);  s5 += __shfl_xor(s5, m);
          s6 += __shfl_xor(s6, m);  s7 += __shfl_xor(s7, m);
          s8 += __shfl_xor(s8, m);  s9 += __shfl_xor(s9, m);
          s10 += __shfl_xor(s10, m); s11 += __shfl_xor(s11, m);
        }
        double den0 = s0, den1 = s1, den2 = s2;
        double n00 = s3, n01 = s4, n10 = s5, n11 = s6, n20 = s7, n21 = s8;
        double W00 = s9, W01 = s10, W11 = s11;

        double n02 = sx0 - n00 - n01;
        double n12 = sx1 - n10 - n11;
        double n22 = sx2 - n20 - n21;
        double W02 = den0 - W00 - W01;
        double W12 = den1 - W01 - W11;
        double W22 = den2 - W02 - W12;

        double r0 = rcp_nr(den0 + 1e-10);
        double r1 = rcp_nr(den1 + 1e-10);
        double r2 = rcp_nr(den2 + 1e-10);
        double c00 = n00 * r0, c01 = n01 * r1, c02 = n02 * r2;
        double c10 = n10 * r0, c11 = n11 * r1, c12 = n12 * r2;
        double c20 = n20 * r0, c21 = n21 * r1, c22 = n22 * r2;

        double loss =
            c00 * (W00 * c00 + W01 * c01 + W02 * c02 - 2.0 * n00) +
            c01 * (W01 * c00 + W11 * c01 + W12 * c02 - 2.0 * n01) +
            c02 * (W02 * c00 + W12 * c01 + W22 * c02 - 2.0 * n02) +
            c10 * (W00 * c10 + W01 * c11 + W02 * c12 - 2.0 * n10) +
            c11 * (W01 * c10 + W11 * c11 + W12 * c12 - 2.0 * n11) +
            c12 * (W02 * c10 + W12 * c11 + W22 * c12 - 2.0 * n12) +
            c20 * (W00 * c20 + W01 * c21 + W02 * c22 - 2.0 * n20) +
            c21 * (W01 * c20 + W11 * c21 + W12 * c22 - 2.0 * n21) +
            c22 * (W02 * c20 + W12 * c21 + W22 * c22 - 2.0 * n22);

        if (loss < bestLoss) { bestLoss = loss; bi0 = c; }
      }
      bi = bi0;
    }

    double upd = (i < 3) ? angd(bi) : xyd(bi);
    if (i == 0) q0 += upd;
    else if (i == 1) q1 += upd;
    else if (i == 2) q2 += upd;
    else if (i == 3) q3 += upd;
    else q4 += upd;
  }

  if (lane == 0) {
    pout[patch * 5 + 0] = q0;
    pout[patch * 5 + 1] = q1;
    pout[patch * 5 + 2] = q2;
    pout[patch * 5 + 3] = q3;
    pout[patch * 5 + 4] = q4;
  }
}

// ---------------- Kernel B: final reconstruction + fold (atomic) --------
__global__ void __launch_bounds__(256) foj_final(const float* __restrict__ x,
                                                 const double* __restrict__ pin,
                                                 float* __restrict__ out) {
  int lane = threadIdx.x & 63;
  int patch = blockIdx.x * 4 + (threadIdx.x >> 6);
  if (patch >= NPATCH) return;
  int ph = patch / WP_;
  int pw = patch - ph * WP_;
  double q0 = pin[patch * 5 + 0];
  double q1 = pin[patch * 5 + 1];
  double q2 = pin[patch * 5 + 2];
  double x0 = pin[patch * 5 + 3];
  double y0 = pin[patch * 5 + 4];

  JPd j = jprep_d(q0, q1, q2);
  int pi2 = lane >> 3, pj = lane & 7;
  double dx = lin8d(pj) - x0;
  double dy = lin8d(pi2) - y0;
  double d13, d42;
  jdist_d(j, dx, dy, d13, d42);
  double h1 = 0.5 + 0.31830988618379067154 * atan(d13 * 100.0);  // ocml
  double h2 = 0.5 + 0.31830988618379067154 * atan(d42 * 100.0);
  double w0 = 1.0 - h1;
  double w1 = h1 * (1.0 - h2);
  double w2 = h1 * h2;

  int oy = ph * 4 + pi2, ox = pw * 4 + pj;
  double im0 = (double)x[oy * 256 + ox];
  double im1 = (double)x[65536 + oy * 256 + ox];
  double im2 = (double)x[131072 + oy * 256 + ox];

  double red[12] = {w0, w1, w2,
                    im0 * w0, im0 * w1, im0 * w2,
                    im1 * w0, im1 * w1, im1 * w2,
                    im2 * w0, im2 * w1, im2 * w2};
#pragma unroll
  for (int t = 0; t < 12; ++t) {
    double v = red[t];
#pragma unroll
    for (int m = 1; m <= 32; m <<= 1) v += __shfl_xor(v, m);
    red[t] = v;
  }
  double e0 = red[0] + 1e-10, e1 = red[1] + 1e-10, e2 = red[2] + 1e-10;
  double pv0 = w0 * (red[3] / e0) + w1 * (red[4] / e1) + w2 * (red[5] / e2);
  double pv1 = w0 * (red[6] / e0) + w1 * (red[7] / e1) + w2 * (red[8] / e2);
  double pv2 = w0 * (red[9] / e0) + w1 * (red[10] / e1) + w2 * (red[11] / e2);

  double minabs = (d13 < 0.0) ? -d13
                              : ((d42 < 0.0) ? fmin(d13, -d42) : fmin(d13, d42));
  double tb = minabs / 0.05;
  double bnd = 1.0 / (1.0 + tb * tb);

  atomicAdd(&out[oy * 256 + ox], (float)pv0);
  atomicAdd(&out[65536 + oy * 256 + ox], (float)pv1);
  atomicAdd(&out[131072 + oy * 256 + ox], (float)pv2);
  atomicAdd(&out[196608 + oy * 256 + ox], (float)bnd);
}

// ---------------- Kernel C: divide by num_patches -----------------------
__global__ void __launch_bounds__(256) foj_norm(float* __restrict__ out) {
  int idx = blockIdx.x * 256 + threadIdx.x;
  int y = idx >> 8, xx = idx & 255;
  int hlo = (y >= 4) ? ((y - 4) >> 2) : 0;
  int hhi = min(62, y >> 2);
  int wlo = (xx >= 4) ? ((xx - 4) >> 2) : 0;
  int whi = min(62, xx >> 2);
  float np_ = (float)((hhi - hlo + 1) * (whi - wlo + 1));
  out[idx] /= np_;
  out[65536 + idx] /= np_;
  out[131072 + idx] /= np_;
  out[196608 + idx] /= np_;
}

extern "C" void kernel_launch(void* const* d_in, const int* in_sizes, int n_in,
                              void* d_out, int out_size, void* d_ws, size_t ws_size,
                              hipStream_t stream) {
  const float* x = (const float*)d_in[0];
  float* out = (float*)d_out;
  double* pws = (double*)d_ws;  // 3969*5 doubles = ~159 KB scratch

  foj_descent<<<(NPATCH + 3) / 4, 256, 0, stream>>>(x, pws);
  hipMemsetAsync(d_out, 0, (size_t)out_size * sizeof(float), stream);
  foj_final<<<(NPATCH + 3) / 4, 256, 0, stream>>>(x, pws, out);
  foj_norm<<<256, 256, 0, stream>>>(out);
}

// Round 19
// 100.524 us; speedup vs baseline: 17.8857x; 1.0098x over previous
//
#include <hip/hip_runtime.h>
#include <math.h>

#define WP_ 63
#define NPATCH 3969
#define PI_D 3.141592653589793
#define TWO_PI_D 6.283185307179586476925287
#define BANDF 4e-3f

typedef float f32x2 __attribute__((ext_vector_type(2)));
__device__ __forceinline__ f32x2 v2(float s) { return (f32x2){s, s}; }
__device__ __forceinline__ f32x2 fma2(f32x2 a, f32x2 b, f32x2 c) {
  return __builtin_elementwise_fma(a, b, c);
}

// numpy remainder(v, 2pi) for v in (-3pi, 4pi): branchless, BIT-EXACT vs
// fmod-based (fmod exact for |v|<2pi; Sterbenz for the +-2pi corrections).
__device__ __forceinline__ double remtp_d(double v) {
  double r = (v < 0.0) ? v + TWO_PI_D : v;
  r = (r < 0.0) ? r + TWO_PI_D : r;
  r = (r >= TWO_PI_D) ? r - TWO_PI_D : r;
  return r;
}

__device__ __forceinline__ double lin8d(int i) {
  if (i == 7) return 1.0;
  return __dadd_rn(__dmul_rn((double)i, 2.0 / 7.0), -1.0);
}
__device__ __forceinline__ double angd(int n) {
  return __dmul_rn((double)n, TWO_PI_D / 31.0);
}
__device__ __forceinline__ double xyd(int n) {
  if (n == 30) return 3.0;
  return __dadd_rn(__dmul_rn((double)n, 6.0 / 30.0), -3.0);
}

__device__ __forceinline__ double pow35_d(double x) {
#pragma clang fp contract(off)
  double x2 = x * x;
  double r = x * x2;
  double b = x2 * x2;
  b = b * b; b = b * b; b = b * b;
  return r * b;
}

__device__ __forceinline__ double rcp_nr(double d) {
  double r;
  asm("v_rcp_f64 %0, %1" : "=v"(r) : "v"(d));
  r = fma(fma(-d, r, 1.0), r, r);
  r = fma(fma(-d, r, 1.0), r, r);
  return r;
}

// branchless sincos for 0 <= x < ~13 (fdlibm kernels, 2-part Cody-Waite)
__device__ __forceinline__ void sincos_fast(double x, double* so, double* co) {
  double kd = rint(x * 6.36619772367581382433e-01);
  int q = (int)kd & 3;
  double r = fma(-kd, 1.57079632673412561417e+00, x);
  r = fma(-kd, 6.07710050650619224932e-11, r);
  double z = r * r;
  double ps = 1.58969099521155010221e-10;
  ps = fma(z, ps, -2.50507602534068634195e-08);
  ps = fma(z, ps, 2.75573137070700676789e-06);
  ps = fma(z, ps, -1.98412698298579493134e-04);
  ps = fma(z, ps, 8.33333333332248946124e-03);
  ps = fma(z, ps, -1.66666666666666324348e-01);
  double sr = fma(z * r, ps, r);
  double pc = -1.13596475577881948265e-11;
  pc = fma(z, pc, 2.08757232129817482790e-09);
  pc = fma(z, pc, -2.75573143513906633035e-07);
  pc = fma(z, pc, 2.48015872894767294178e-05);
  pc = fma(z, pc, -1.38888888888741095749e-03);
  pc = fma(z, pc, 4.16666666666666019037e-02);
  double cr = fma(z, fma(z, pc, -0.5), 1.0);
  bool swp = q & 1;
  double s0 = swp ? cr : sr;
  double c0 = swp ? sr : cr;
  *so = (q & 2) ? -s0 : s0;
  *co = (((q + 1) & 2)) ? -c0 : c0;
}

// ---------- atan tables ----------
#define TABN 57
__device__ __forceinline__ void build_atan_tab(double2* tab, float2* tabf) {
  int k = threadIdx.x;
  if (k < 56) {
    int hi = ((4076 + k) << 18) | (1 << 17);
    double c = __hiloint2double(hi, 0);
    double a = atan(c);
    tab[k] = double2{c, a};
    tabf[k + 1] = float2{(float)c, (float)a};
  } else if (k == 56) {
    tab[56] = double2{0.0, 0.0};
    tabf[0] = float2{0.0f, 0.0f};
  }
}

// f64 pair hstep (element math identical to r9-r16)
__device__ __forceinline__ void hstep2_tab(const double2* __restrict__ tab,
                                           double da, double db,
                                           double& ha, double& hb) {
  double za = da * 100.0, zb = db * 100.0;
  double ua = fabs(za), ub = fabs(zb);
  int ia = (__double2hiint(ua) >> 18) - 4076;
  int ib = (__double2hiint(ub) >> 18) - 4076;
  ia = (ia < 0) ? 56 : ((ia > 55) ? 55 : ia);
  ib = (ib < 0) ? 56 : ((ib > 55) ? 55 : ib);
  double2 ea = tab[ia];
  double2 eb = tab[ib];
  double ta = (ua - ea.x) * rcp_nr(fma(ua, ea.x, 1.0));
  double tb = (ub - eb.x) * rcp_nr(fma(ub, eb.x, 1.0));
  double z2a = ta * ta, z2b = tb * tb;
  double pa = 1.0 / 13.0, pb = 1.0 / 13.0;
  pa = fma(z2a, pa, -1.0 / 11.0); pb = fma(z2b, pb, -1.0 / 11.0);
  pa = fma(z2a, pa, 1.0 / 9.0);   pb = fma(z2b, pb, 1.0 / 9.0);
  pa = fma(z2a, pa, -1.0 / 7.0);  pb = fma(z2b, pb, -1.0 / 7.0);
  pa = fma(z2a, pa, 1.0 / 5.0);   pb = fma(z2b, pb, 1.0 / 5.0);
  pa = fma(z2a, pa, -1.0 / 3.0);  pb = fma(z2b, pb, -1.0 / 3.0);
  pa = fma(z2a, pa, 1.0);         pb = fma(z2b, pb, 1.0);
  double aa = fma(ta, pa, ea.y);
  double ab = fma(tb, pb, eb.y);
  aa = copysign(aa, za);
  ab = copysign(ab, zb);
  ha = fma(aa, 0.31830988618379067154, 0.5);
  hb = fma(ab, 0.31830988618379067154, 0.5);
}

// f32 packed hstep over a PIXEL PAIR of one distance field
__device__ __forceinline__ f32x2 hstepv(const float2* __restrict__ tabf,
                                        f32x2 d) {
  f32x2 z = d * 100.0f;
  f32x2 u = __builtin_elementwise_abs(z);
  int ia = (int)(__float_as_uint(u.x) >> 21) - 492;
  int ib = (int)(__float_as_uint(u.y) >> 21) - 492;
  ia = min(max(ia, -1), 55) + 1;
  ib = min(max(ib, -1), 55) + 1;
  float2 ea = tabf[ia], eb = tabf[ib];
  f32x2 ec = {ea.x, eb.x};
  f32x2 ey = {ea.y, eb.y};
  f32x2 den = fma2(u, ec, v2(1.0f));
  float ra, rb;
  asm("v_rcp_f32 %0, %1" : "=v"(ra) : "v"(den.x));
  asm("v_rcp_f32 %0, %1" : "=v"(rb) : "v"(den.y));
  f32x2 r = {ra, rb};
  f32x2 t = (u - ec) * r;
  f32x2 p = fma2(t * t, v2(-0.33333334f), v2(1.0f));
  f32x2 a = fma2(t, p, ey);
  a = __builtin_elementwise_copysign(a, z);
  return fma2(a, v2(0.31830987f), v2(0.5f));
}

struct JPd {
  double s1, c1, s2, c2, s3, c3, s4, c4;
  double sg13, sg42, gt13, gt42;
};

__device__ JPd jprep_d(double p0, double p1, double p2) {
#pragma clang fp contract(off)
  double r0 = remtp_d(p0), r1 = remtp_d(p1), r2 = remtp_d(p2);
  double mn = fmin(r0, r1), mx = fmax(r0, r1);
  double a1 = fmin(mn, r2);
  double a3 = fmax(mx, r2);
  double a2 = fmax(mn, fmin(mx, r2));
  double remm = remtp_d(0.5 * (a1 - a3));
  double a4 = 0.5 * (a1 + a3) + ((remm >= PI_D) ? PI_D : 0.0);
  JPd j;
  double r42 = remtp_d(a2 - a4);
  j.sg42 = (r42 < PI_D) ? 1.0 : -1.0;
  j.gt42 = pow35_d(r42 / PI_D - 1.0) * 0.1;
  double r13 = remtp_d(a3 - a1);
  j.sg13 = (r13 < PI_D) ? 1.0 : -1.0;
  j.gt13 = pow35_d(r13 / PI_D - 1.0) * 0.1;
  sincos_fast(a1, &j.s1, &j.c1);
  sincos_fast(a2, &j.s2, &j.c2);
  sincos_fast(a3, &j.s3, &j.c3);
  sincos_fast(a4, &j.s4, &j.c4);
  return j;
}

__device__ __forceinline__ void jdist_d(const JPd& j, double dx, double dy,
                                        double& d13, double& d42) {
  double hl1 = (-j.s1) * dx + j.c1 * dy;
  double hl2 = (-j.s2) * dx + j.c2 * dy;
  double hl3 = (-j.s3) * dx + j.c3 * dy;
  double hl4 = (-j.s4) * dx + j.c4 * dy;
  d13 = j.sg13 * fmin(j.sg13 * hl1, (-j.sg13) * hl3) + j.gt13;
  d42 = j.sg42 * fmin(j.sg42 * hl4, (-j.sg42) * hl2) + j.gt42;
}

// ---------------- Kernel A: descent. 1 WAVE = 1 BLOCK = 1 PATCH. ---------
// packed-f32 prescreen + cooperative f64 verify (lane = pixel).
__global__ void __launch_bounds__(64)
foj_descent(const float* __restrict__ x, double* __restrict__ pout) {
  const int lane = threadIdx.x;
  const int hp = lane >> 5;
  const int cand = lane & 31;
  const int patch = blockIdx.x;

  __shared__ double2 stab[TABN];
  __shared__ float2 stabf[TABN + 1];
  __shared__ float4 simg[64];       // AoS for verify + sums
  __shared__ float simgp[3][64];    // SoA planes for packed prescreen
  build_atan_tab(stab, stabf);
  {
    int ph = patch / WP_;
    int pw = patch - ph * WP_;
    int py = lane >> 3, pxx = lane & 7;
    int base = (ph * 4 + py) * 256 + (pw * 4 + pxx);
    float4 v;
    v.x = x[base];
    v.y = x[65536 + base];
    v.z = x[131072 + base];
    v.w = 0.0f;
    simg[lane] = v;
    simgp[0][lane] = v.x;
    simgp[1][lane] = v.y;
    simgp[2][lane] = v.z;
  }
  __syncthreads();
  const float4* sp = simg;

  // per-patch channel sums
  double sx0 = 0.0, sx1 = 0.0, sx2 = 0.0;
  {
    const float4* hbase = sp + hp * 32;
#pragma unroll
    for (int t = 0; t < 32; ++t) {
      float4 im = hbase[t];
      sx0 += (double)im.x; sx1 += (double)im.y; sx2 += (double)im.z;
    }
    sx0 += __shfl_xor(sx0, 32);
    sx1 += __shfl_xor(sx1, 32);
    sx2 += __shfl_xor(sx2, 32);
  }
  const float sx0f = (float)sx0, sx1f = (float)sx1, sx2f = (float)sx2;

  // this lane's pixel for cooperative verify (lane = pixel 0..63)
  const double vlinx = lin8d(lane & 7);
  const double vliny = lin8d(lane >> 3);
  const float4 vim = sp[lane];

  double q0 = 0.0, q1 = 0.0, q2 = 0.0, q3 = 0.0, q4 = 0.0;

#pragma unroll 1
  for (int i = 0; i < 5; ++i) {
    double rv = (i < 3) ? angd(cand) : xyd(cand);
    double p0 = q0 + ((i == 0) ? rv : 0.0);
    double p1 = q1 + ((i == 1) ? rv : 0.0);
    double p2 = q2 + ((i == 2) ? rv : 0.0);
    double x0 = q3 + ((i == 3) ? rv : 0.0);
    double y0 = q4 + ((i == 4) ? rv : 0.0);

    JPd j = jprep_d(p0, p1, p2);  // f64 always: discrete decisions exact

    // ---------------- packed f32 prescreen (pixel-pair lanes) -----------
    float blf;
    {
      f32x2 ns1v = v2((float)(-j.s1)), ns2v = v2((float)(-j.s2));
      f32x2 ns3v = v2((float)(-j.s3)), ns4v = v2((float)(-j.s4));
      float c1f = (float)j.c1, c2f = (float)j.c2;
      float c3f = (float)j.c3, c4f = (float)j.c4;
      f32x2 sg13v = v2((float)j.sg13), sg42v = v2((float)j.sg42);
      f32x2 nsg13v = -sg13v, nsg42v = -sg42v;
      f32x2 gt13v = v2((float)j.gt13), gt42v = v2((float)j.gt42);
      f32x2 dxp[4];
#pragma unroll
      for (int t = 0; t < 4; ++t)
        dxp[t] = (f32x2){(float)(lin8d(2 * t) - x0),
                         (float)(lin8d(2 * t + 1) - x0)};

      f32x2 den0v = {0, 0}, den1v = {0, 0};
      f32x2 n00v = {0, 0}, n01v = {0, 0}, n10v = {0, 0}, n11v = {0, 0};
      f32x2 n20v = {0, 0}, n21v = {0, 0};
      f32x2 W00v = {0, 0}, W01v = {0, 0}, W11v = {0, 0};
#pragma unroll 1
      for (int r = 0; r < 4; ++r) {
        int iyy = hp * 4 + r;
        double liny = (iyy == 7) ? 1.0
                    : __dadd_rn(__dmul_rn((double)iyy, 2.0 / 7.0), -1.0);
        float dyf = (float)(liny - y0);
        f32x2 cdy1 = v2(c1f * dyf), cdy2 = v2(c2f * dyf);
        f32x2 cdy3 = v2(c3f * dyf), cdy4 = v2(c4f * dyf);
        const float* q0p = &simgp[0][hp * 32 + r * 8];
        const float* q1p = &simgp[1][hp * 32 + r * 8];
        const float* q2p = &simgp[2][hp * 32 + r * 8];
#pragma unroll
        for (int cp = 0; cp < 4; ++cp) {
          f32x2 dxv = dxp[cp];
          f32x2 hl1 = fma2(ns1v, dxv, cdy1);
          f32x2 hl3 = fma2(ns3v, dxv, cdy3);
          f32x2 hl4 = fma2(ns4v, dxv, cdy4);
          f32x2 hl2 = fma2(ns2v, dxv, cdy2);
          f32x2 d13 = fma2(sg13v,
              __builtin_elementwise_min(sg13v * hl1, nsg13v * hl3), gt13v);
          f32x2 d42 = fma2(sg42v,
              __builtin_elementwise_min(sg42v * hl4, nsg42v * hl2), gt42v);
          f32x2 h1 = hstepv(stabf, d13);
          f32x2 h2 = hstepv(stabf, d42);
          f32x2 w0 = v2(1.0f) - h1;
          f32x2 om = v2(1.0f) - h2;
          f32x2 w1 = h1 * om;
          f32x2 i0 = *(const f32x2*)(q0p + 2 * cp);
          f32x2 i1 = *(const f32x2*)(q1p + 2 * cp);
          f32x2 i2 = *(const f32x2*)(q2p + 2 * cp);
          den0v += w0; den1v += w1;
          n00v = fma2(i0, w0, n00v); n01v = fma2(i0, w1, n01v);
          n10v = fma2(i1, w0, n10v); n11v = fma2(i1, w1, n11v);
          n20v = fma2(i2, w0, n20v); n21v = fma2(i2, w1, n21v);
          W00v = fma2(w0, w0, W00v); W01v = fma2(w0, w1, W01v);
          W11v = fma2(w1, w1, W11v);
        }
      }
      float den0f = den0v.x + den0v.y, den1f = den1v.x + den1v.y;
      float n00f = n00v.x + n00v.y, n01f = n01v.x + n01v.y;
      float n10f = n10v.x + n10v.y, n11f = n11v.x + n11v.y;
      float n20f = n20v.x + n20v.y, n21f = n21v.x + n21v.y;
      float W00f = W00v.x + W00v.y, W01f = W01v.x + W01v.y;
      float W11f = W11v.x + W11v.y;

      den0f += __shfl_xor(den0f, 32); den1f += __shfl_xor(den1f, 32);
      n00f += __shfl_xor(n00f, 32); n01f += __shfl_xor(n01f, 32);
      n10f += __shfl_xor(n10f, 32); n11f += __shfl_xor(n11f, 32);
      n20f += __shfl_xor(n20f, 32); n21f += __shfl_xor(n21f, 32);
      W00f += __shfl_xor(W00f, 32); W01f += __shfl_xor(W01f, 32); W11f += __shfl_xor(W11f, 32);

      // sum(w0+w1+w2) = 64 exactly in ideal math; f32 dev ~6e-6 << band
      float den2f = 64.0f - den0f - den1f;
      float n02f = sx0f - n00f - n01f;
      float n12f = sx1f - n10f - n11f;
      float n22f = sx2f - n20f - n21f;
      float W02f = den0f - W00f - W01f;
      float W12f = den1f - W01f - W11f;
      float W22f = den2f - W02f - W12f;

      float e0 = den0f + 1e-10f, e1 = den1f + 1e-10f, e2 = den2f + 1e-10f;
      float r0f, r1f, r2f;
      asm("v_rcp_f32 %0, %1" : "=v"(r0f) : "v"(e0));
      asm("v_rcp_f32 %0, %1" : "=v"(r1f) : "v"(e1));
      asm("v_rcp_f32 %0, %1" : "=v"(r2f) : "v"(e2));
      r0f = fmaf(fmaf(-e0, r0f, 1.0f), r0f, r0f);
      r1f = fmaf(fmaf(-e1, r1f, 1.0f), r1f, r1f);
      r2f = fmaf(fmaf(-e2, r2f, 1.0f), r2f, r2f);
      float c00 = n00f * r0f, c01 = n01f * r1f, c02 = n02f * r2f;
      float c10 = n10f * r0f, c11 = n11f * r1f, c12 = n12f * r2f;
      float c20 = n20f * r0f, c21 = n21f * r1f, c22 = n22f * r2f;

      float lossf =
          c00 * (W00f * c00 + W01f * c01 + W02f * c02 - 2.0f * n00f) +
          c01 * (W01f * c00 + W11f * c01 + W12f * c02 - 2.0f * n01f) +
          c02 * (W02f * c00 + W12f * c01 + W22f * c02 - 2.0f * n02f) +
          c10 * (W00f * c10 + W01f * c11 + W02f * c12 - 2.0f * n10f) +
          c11 * (W01f * c10 + W11f * c11 + W12f * c12 - 2.0f * n11f) +
          c12 * (W02f * c10 + W12f * c11 + W22f * c12 - 2.0f * n12f) +
          c20 * (W00f * c20 + W01f * c21 + W02f * c22 - 2.0f * n20f) +
          c21 * (W01f * c20 + W11f * c21 + W12f * c22 - 2.0f * n21f) +
          c22 * (W02f * c20 + W12f * c21 + W22f * c22 - 2.0f * n22f);

      blf = (cand < 31) ? lossf : 3.0e38f;
    }

    float mnf = blf;
#pragma unroll
    for (int m = 1; m <= 16; m <<= 1) mnf = fminf(mnf, __shfl_xor(mnf, m));
    bool inb = (cand < 31) && (blf <= mnf + BANDF);
    unsigned bal32 = (unsigned)__ballot(inb);

    int bi;
    if (__popc(bal32) == 1) {
      bi = __ffs(bal32) - 1;   // unique winner: f32 decision is safe
    } else {
      // ---- cooperative f64 verify: lane = pixel, serial over in-band
      // candidates (ascending index = np.argmin first-index tie-break).
      double bestLoss = (double)INFINITY;
      int bi0 = 0;
      unsigned rem = bal32;
#pragma unroll 1
      while (rem) {
        int c = __ffs(rem) - 1;
        rem &= rem - 1;
        double rvc = (i < 3) ? angd(c) : xyd(c);
        double x0c = q3 + ((i == 3) ? rvc : 0.0);
        double y0c = q4 + ((i == 4) ? rvc : 0.0);
        JPd jc;
        jc.s1 = __shfl(j.s1, c);  jc.c1 = __shfl(j.c1, c);
        jc.s2 = __shfl(j.s2, c);  jc.c2 = __shfl(j.c2, c);
        jc.s3 = __shfl(j.s3, c);  jc.c3 = __shfl(j.c3, c);
        jc.s4 = __shfl(j.s4, c);  jc.c4 = __shfl(j.c4, c);
        jc.sg13 = __shfl(j.sg13, c); jc.sg42 = __shfl(j.sg42, c);
        jc.gt13 = __shfl(j.gt13, c); jc.gt42 = __shfl(j.gt42, c);

        double d13, d42;
        jdist_d(jc, vlinx - x0c, vliny - y0c, d13, d42);
        double h1, h2;
        hstep2_tab(stab, d13, d42, h1, h2);
        double w0 = 1.0 - h1;
        double w1 = h1 * (1.0 - h2);
        double ix = (double)vim.x, iy2 = (double)vim.y, iz = (double)vim.z;
        double s0 = w0, s1 = w1;
        double s3 = ix * w0, s4 = ix * w1;
        double s5 = iy2 * w0, s6 = iy2 * w1;
        double s7 = iz * w0, s8 = iz * w1;
        double s9 = w0 * w0, s10 = w0 * w1, s11 = w1 * w1;
#pragma unroll
        for (int m = 1; m <= 32; m <<= 1) {
          s0 += __shfl_xor(s0, m);  s1 += __shfl_xor(s1, m);
          s3 += __shfl_xor(s3, m);  s4 += __shfl_xor(s4, m);
          s5 += __shfl_xor(s5, m);  s6 += __shfl_xor(s6, m);
          s7 += __shfl_xor(s7, m);  s8 += __shfl_xor(s8, m);
          s9 += __shfl_xor(s9, m);  s10 += __shfl_xor(s10, m);
          s11 += __shfl_xor(s11, m);
        }
        double den0 = s0, den1 = s1;
        double den2 = 64.0 - den0 - den1;   // Sigma w = 1/px (dev ~1e-14)
        double n00 = s3, n01 = s4, n10 = s5, n11 = s6, n20 = s7, n21 = s8;
        double W00 = s9, W01 = s10, W11 = s11;

        double n02 = sx0 - n00 - n01;
        double n12 = sx1 - n10 - n11;
        double n22 = sx2 - n20 - n21;
        double W02 = den0 - W00 - W01;
        double W12 = den1 - W01 - W11;
        double W22 = den2 - W02 - W12;

        double r0 = rcp_nr(den0 + 1e-10);
        double r1 = rcp_nr(den1 + 1e-10);
        double r2 = rcp_nr(den2 + 1e-10);
        double c00 = n00 * r0, c01 = n01 * r1, c02 = n02 * r2;
        double c10 = n10 * r0, c11 = n11 * r1, c12 = n12 * r2;
        double c20 = n20 * r0, c21 = n21 * r1, c22 = n22 * r2;

        double loss =
            c00 * (W00 * c00 + W01 * c01 + W02 * c02 - 2.0 * n00) +
            c01 * (W01 * c00 + W11 * c01 + W12 * c02 - 2.0 * n01) +
            c02 * (W02 * c00 + W12 * c01 + W22 * c02 - 2.0 * n02) +
            c10 * (W00 * c10 + W01 * c11 + W02 * c12 - 2.0 * n10) +
            c11 * (W01 * c10 + W11 * c11 + W12 * c12 - 2.0 * n11) +
            c12 * (W02 * c10 + W12 * c11 + W22 * c12 - 2.0 * n12) +
            c20 * (W00 * c20 + W01 * c21 + W02 * c22 - 2.0 * n20) +
            c21 * (W01 * c20 + W11 * c21 + W12 * c22 - 2.0 * n21) +
            c22 * (W02 * c20 + W12 * c21 + W22 * c22 - 2.0 * n22);

        if (loss < bestLoss) { bestLoss = loss; bi0 = c; }
      }
      bi = bi0;
    }

    double upd = (i < 3) ? angd(bi) : xyd(bi);
    if (i == 0) q0 += upd;
    else if (i == 1) q1 += upd;
    else if (i == 2) q2 += upd;
    else if (i == 3) q3 += upd;
    else q4 += upd;
  }

  if (lane == 0) {
    pout[patch * 5 + 0] = q0;
    pout[patch * 5 + 1] = q1;
    pout[patch * 5 + 2] = q2;
    pout[patch * 5 + 3] = q3;
    pout[patch * 5 + 4] = q4;
  }
}

// ---------------- Kernel B: final reconstruction + fold (atomic) --------
__global__ void __launch_bounds__(256) foj_final(const float* __restrict__ x,
                                                 const double* __restrict__ pin,
                                                 float* __restrict__ out) {
  int lane = threadIdx.x & 63;
  int patch = blockIdx.x * 4 + (threadIdx.x >> 6);
  if (patch >= NPATCH) return;
  int ph = patch / WP_;
  int pw = patch - ph * WP_;
  double q0 = pin[patch * 5 + 0];
  double q1 = pin[patch * 5 + 1];
  double q2 = pin[patch * 5 + 2];
  double x0 = pin[patch * 5 + 3];
  double y0 = pin[patch * 5 + 4];

  JPd j = jprep_d(q0, q1, q2);
  int pi2 = lane >> 3, pj = lane & 7;
  double dx = lin8d(pj) - x0;
  double dy = lin8d(pi2) - y0;
  double d13, d42;
  jdist_d(j, dx, dy, d13, d42);
  double h1 = 0.5 + 0.31830988618379067154 * atan(d13 * 100.0);  // ocml
  double h2 = 0.5 + 0.31830988618379067154 * atan(d42 * 100.0);
  double w0 = 1.0 - h1;
  double w1 = h1 * (1.0 - h2);
  double w2 = h1 * h2;

  int oy = ph * 4 + pi2, ox = pw * 4 + pj;
  double im0 = (double)x[oy * 256 + ox];
  double im1 = (double)x[65536 + oy * 256 + ox];
  double im2 = (double)x[131072 + oy * 256 + ox];

  double red[12] = {w0, w1, w2,
                    im0 * w0, im0 * w1, im0 * w2,
                    im1 * w0, im1 * w1, im1 * w2,
                    im2 * w0, im2 * w1, im2 * w2};
#pragma unroll
  for (int t = 0; t < 12; ++t) {
    double v = red[t];
#pragma unroll
    for (int m = 1; m <= 32; m <<= 1) v += __shfl_xor(v, m);
    red[t] = v;
  }
  double e0 = red[0] + 1e-10, e1 = red[1] + 1e-10, e2 = red[2] + 1e-10;
  double pv0 = w0 * (red[3] / e0) + w1 * (red[4] / e1) + w2 * (red[5] / e2);
  double pv1 = w0 * (red[6] / e0) + w1 * (red[7] / e1) + w2 * (red[8] / e2);
  double pv2 = w0 * (red[9] / e0) + w1 * (red[10] / e1) + w2 * (red[11] / e2);

  double minabs = (d13 < 0.0) ? -d13
                              : ((d42 < 0.0) ? fmin(d13, -d42) : fmin(d13, d42));
  double tb = minabs / 0.05;
  double bnd = 1.0 / (1.0 + tb * tb);

  atomicAdd(&out[oy * 256 + ox], (float)pv0);
  atomicAdd(&out[65536 + oy * 256 + ox], (float)pv1);
  atomicAdd(&out[131072 + oy * 256 + ox], (float)pv2);
  atomicAdd(&out[196608 + oy * 256 + ox], (float)bnd);
}

// ---------------- Kernel C: divide by num_patches -----------------------
__global__ void __launch_bounds__(256) foj_norm(float* __restrict__ out) {
  int idx = blockIdx.x * 256 + threadIdx.x;
  int y = idx >> 8, xx = idx & 255;
  int hlo = (y >= 4) ? ((y - 4) >> 2) : 0;
  int hhi = min(62, y >> 2);
  int wlo = (xx >= 4) ? ((xx - 4) >> 2) : 0;
  int whi = min(62, xx >> 2);
  float np_ = (float)((hhi - hlo + 1) * (whi - wlo + 1));
  out[idx] /= np_;
  out[65536 + idx] /= np_;
  out[131072 + idx] /= np_;
  out[196608 + idx] /= np_;
}

extern "C" void kernel_launch(void* const* d_in, const int* in_sizes, int n_in,
                              void* d_out, int out_size, void* d_ws, size_t ws_size,
                              hipStream_t stream) {
  const float* x = (const float*)d_in[0];
  float* out = (float*)d_out;
  double* pws = (double*)d_ws;  // 3969*5 doubles = ~159 KB scratch

  foj_descent<<<NPATCH, 64, 0, stream>>>(x, pws);
  hipMemsetAsync(d_out, 0, (size_t)out_size * sizeof(float), stream);
  foj_final<<<(NPATCH + 3) / 4, 256, 0, stream>>>(x, pws, out);
  foj_norm<<<256, 256, 0, stream>>>(out);
}

// Round 20
// 98.360 us; speedup vs baseline: 18.2791x; 1.0220x over previous
//
#include <hip/hip_runtime.h>
#include <math.h>

#define WP_ 63
#define NPATCH 3969
#define PI_D 3.141592653589793
#define TWO_PI_D 6.283185307179586476925287
#define BANDF 4e-3f

typedef float f32x2 __attribute__((ext_vector_type(2)));
__device__ __forceinline__ f32x2 v2(float s) { return (f32x2){s, s}; }
__device__ __forceinline__ f32x2 fma2(f32x2 a, f32x2 b, f32x2 c) {
  return __builtin_elementwise_fma(a, b, c);
}

// numpy remainder(v, 2pi) for v in (-3pi, 4pi): branchless, BIT-EXACT vs
// fmod-based (fmod exact for |v|<2pi; Sterbenz for the +-2pi corrections).
__device__ __forceinline__ double remtp_d(double v) {
  double r = (v < 0.0) ? v + TWO_PI_D : v;
  r = (r < 0.0) ? r + TWO_PI_D : r;
  r = (r >= TWO_PI_D) ? r - TWO_PI_D : r;
  return r;
}

__device__ __forceinline__ double lin8d(int i) {
  if (i == 7) return 1.0;
  return __dadd_rn(__dmul_rn((double)i, 2.0 / 7.0), -1.0);
}
__device__ __forceinline__ double angd(int n) {
  return __dmul_rn((double)n, TWO_PI_D / 31.0);
}
__device__ __forceinline__ double xyd(int n) {
  if (n == 30) return 3.0;
  return __dadd_rn(__dmul_rn((double)n, 6.0 / 30.0), -3.0);
}

__device__ __forceinline__ double pow35_d(double x) {
#pragma clang fp contract(off)
  double x2 = x * x;
  double r = x * x2;
  double b = x2 * x2;
  b = b * b; b = b * b; b = b * b;
  return r * b;
}

__device__ __forceinline__ double rcp_nr(double d) {
  double r;
  asm("v_rcp_f64 %0, %1" : "=v"(r) : "v"(d));
  r = fma(fma(-d, r, 1.0), r, r);
  r = fma(fma(-d, r, 1.0), r, r);
  return r;
}

// branchless sincos for 0 <= x < ~13 (fdlibm kernels, 2-part Cody-Waite)
__device__ __forceinline__ void sincos_fast(double x, double* so, double* co) {
  double kd = rint(x * 6.36619772367581382433e-01);
  int q = (int)kd & 3;
  double r = fma(-kd, 1.57079632673412561417e+00, x);
  r = fma(-kd, 6.07710050650619224932e-11, r);
  double z = r * r;
  double ps = 1.58969099521155010221e-10;
  ps = fma(z, ps, -2.50507602534068634195e-08);
  ps = fma(z, ps, 2.75573137070700676789e-06);
  ps = fma(z, ps, -1.98412698298579493134e-04);
  ps = fma(z, ps, 8.33333333332248946124e-03);
  ps = fma(z, ps, -1.66666666666666324348e-01);
  double sr = fma(z * r, ps, r);
  double pc = -1.13596475577881948265e-11;
  pc = fma(z, pc, 2.08757232129817482790e-09);
  pc = fma(z, pc, -2.75573143513906633035e-07);
  pc = fma(z, pc, 2.48015872894767294178e-05);
  pc = fma(z, pc, -1.38888888888741095749e-03);
  pc = fma(z, pc, 4.16666666666666019037e-02);
  double cr = fma(z, fma(z, pc, -0.5), 1.0);
  bool swp = q & 1;
  double s0 = swp ? cr : sr;
  double c0 = swp ? sr : cr;
  *so = (q & 2) ? -s0 : s0;
  *co = (((q + 1) & 2)) ? -c0 : c0;
}

// ---------- f64 atan table (verify path only) ----------
#define TABN 57
__device__ __forceinline__ void build_atan_tab(double2* tab) {
  int k = threadIdx.x;
  if (k < 56) {
    int hi = ((4076 + k) << 18) | (1 << 17);
    double c = __hiloint2double(hi, 0);
    tab[k] = double2{c, atan(c)};
  } else if (k == 56) {
    tab[56] = double2{0.0, 0.0};
  }
}

// f64 pair hstep (element math identical to r9-r19)
__device__ __forceinline__ void hstep2_tab(const double2* __restrict__ tab,
                                           double da, double db,
                                           double& ha, double& hb) {
  double za = da * 100.0, zb = db * 100.0;
  double ua = fabs(za), ub = fabs(zb);
  int ia = (__double2hiint(ua) >> 18) - 4076;
  int ib = (__double2hiint(ub) >> 18) - 4076;
  ia = (ia < 0) ? 56 : ((ia > 55) ? 55 : ia);
  ib = (ib < 0) ? 56 : ((ib > 55) ? 55 : ib);
  double2 ea = tab[ia];
  double2 eb = tab[ib];
  double ta = (ua - ea.x) * rcp_nr(fma(ua, ea.x, 1.0));
  double tb = (ub - eb.x) * rcp_nr(fma(ub, eb.x, 1.0));
  double z2a = ta * ta, z2b = tb * tb;
  double pa = 1.0 / 13.0, pb = 1.0 / 13.0;
  pa = fma(z2a, pa, -1.0 / 11.0); pb = fma(z2b, pb, -1.0 / 11.0);
  pa = fma(z2a, pa, 1.0 / 9.0);   pb = fma(z2b, pb, 1.0 / 9.0);
  pa = fma(z2a, pa, -1.0 / 7.0);  pb = fma(z2b, pb, -1.0 / 7.0);
  pa = fma(z2a, pa, 1.0 / 5.0);   pb = fma(z2b, pb, 1.0 / 5.0);
  pa = fma(z2a, pa, -1.0 / 3.0);  pb = fma(z2b, pb, -1.0 / 3.0);
  pa = fma(z2a, pa, 1.0);         pb = fma(z2b, pb, 1.0);
  double aa = fma(ta, pa, ea.y);
  double ab = fma(tb, pb, eb.y);
  aa = copysign(aa, za);
  ab = copysign(ab, zb);
  ha = fma(aa, 0.31830988618379067154, 0.5);
  hb = fma(ab, 0.31830988618379067154, 0.5);
}

// f32 packed hstep, TABLE-FREE: 6-term odd minimax atan (err ~2e-5 rad ->
// h-err ~7e-6; worst-case correlated loss dev ~2e-4 << 4e-3 band).
// Range fold: arg = min(u, rcp(u)); u>1 -> pi/2 - poly.
__device__ __forceinline__ f32x2 hstepv(f32x2 d) {
  f32x2 z = d * 100.0f;
  f32x2 u = __builtin_elementwise_abs(z);
  float ra, rb;
  asm("v_rcp_f32 %0, %1" : "=v"(ra) : "v"(u.x));
  asm("v_rcp_f32 %0, %1" : "=v"(rb) : "v"(u.y));
  f32x2 ru = {ra, rb};
  f32x2 arg = __builtin_elementwise_min(u, ru);
  f32x2 t = arg * arg;
  f32x2 p = v2(-0.0117212f);
  p = fma2(t, p, v2(0.05265332f));
  p = fma2(t, p, v2(-0.11643287f));
  p = fma2(t, p, v2(0.19354346f));
  p = fma2(t, p, v2(-0.33262347f));
  p = fma2(t, p, v2(0.99997726f));
  f32x2 res = arg * p;
  f32x2 a;
  a.x = (u.x > 1.0f) ? (1.5707964f - res.x) : res.x;
  a.y = (u.y > 1.0f) ? (1.5707964f - res.y) : res.y;
  a = __builtin_elementwise_copysign(a, z);
  return fma2(a, v2(0.31830987f), v2(0.5f));
}

struct JPd {
  double s1, c1, s2, c2, s3, c3, s4, c4;
  double sg13, sg42, gt13, gt42;
};

__device__ JPd jprep_d(double p0, double p1, double p2) {
#pragma clang fp contract(off)
  double r0 = remtp_d(p0), r1 = remtp_d(p1), r2 = remtp_d(p2);
  double mn = fmin(r0, r1), mx = fmax(r0, r1);
  double a1 = fmin(mn, r2);
  double a3 = fmax(mx, r2);
  double a2 = fmax(mn, fmin(mx, r2));
  double remm = remtp_d(0.5 * (a1 - a3));
  double a4 = 0.5 * (a1 + a3) + ((remm >= PI_D) ? PI_D : 0.0);
  JPd j;
  double r42 = remtp_d(a2 - a4);
  j.sg42 = (r42 < PI_D) ? 1.0 : -1.0;
  j.gt42 = pow35_d(r42 / PI_D - 1.0) * 0.1;
  double r13 = remtp_d(a3 - a1);
  j.sg13 = (r13 < PI_D) ? 1.0 : -1.0;
  j.gt13 = pow35_d(r13 / PI_D - 1.0) * 0.1;
  sincos_fast(a1, &j.s1, &j.c1);
  sincos_fast(a2, &j.s2, &j.c2);
  sincos_fast(a3, &j.s3, &j.c3);
  sincos_fast(a4, &j.s4, &j.c4);
  return j;
}

__device__ __forceinline__ void jdist_d(const JPd& j, double dx, double dy,
                                        double& d13, double& d42) {
  double hl1 = (-j.s1) * dx + j.c1 * dy;
  double hl2 = (-j.s2) * dx + j.c2 * dy;
  double hl3 = (-j.s3) * dx + j.c3 * dy;
  double hl4 = (-j.s4) * dx + j.c4 * dy;
  d13 = j.sg13 * fmin(j.sg13 * hl1, (-j.sg13) * hl3) + j.gt13;
  d42 = j.sg42 * fmin(j.sg42 * hl4, (-j.sg42) * hl2) + j.gt42;
}

// ---------------- Kernel A: descent. 1 WAVE = 1 BLOCK = 1 PATCH. ---------
// packed-f32 prescreen (pure ALU) + cooperative f64 verify (lane = pixel).
__global__ void __launch_bounds__(64)
foj_descent(const float* __restrict__ x, double* __restrict__ pout) {
  const int lane = threadIdx.x;
  const int hp = lane >> 5;
  const int cand = lane & 31;
  const int patch = blockIdx.x;

  __shared__ double2 stab[TABN];
  __shared__ float4 simg[64];       // AoS for verify + sums
  __shared__ float simgp[3][64];    // SoA planes for packed prescreen
  build_atan_tab(stab);
  {
    int ph = patch / WP_;
    int pw = patch - ph * WP_;
    int py = lane >> 3, pxx = lane & 7;
    int base = (ph * 4 + py) * 256 + (pw * 4 + pxx);
    float4 v;
    v.x = x[base];
    v.y = x[65536 + base];
    v.z = x[131072 + base];
    v.w = 0.0f;
    simg[lane] = v;
    simgp[0][lane] = v.x;
    simgp[1][lane] = v.y;
    simgp[2][lane] = v.z;
  }
  __syncthreads();
  const float4* sp = simg;

  // per-patch channel sums
  double sx0 = 0.0, sx1 = 0.0, sx2 = 0.0;
  {
    const float4* hbase = sp + hp * 32;
#pragma unroll
    for (int t = 0; t < 32; ++t) {
      float4 im = hbase[t];
      sx0 += (double)im.x; sx1 += (double)im.y; sx2 += (double)im.z;
    }
    sx0 += __shfl_xor(sx0, 32);
    sx1 += __shfl_xor(sx1, 32);
    sx2 += __shfl_xor(sx2, 32);
  }
  const float sx0f = (float)sx0, sx1f = (float)sx1, sx2f = (float)sx2;

  // this lane's pixel for cooperative verify (lane = pixel 0..63)
  const double vlinx = lin8d(lane & 7);
  const double vliny = lin8d(lane >> 3);
  const float4 vim = sp[lane];

  double q0 = 0.0, q1 = 0.0, q2 = 0.0, q3 = 0.0, q4 = 0.0;

#pragma unroll 1
  for (int i = 0; i < 5; ++i) {
    double rv = (i < 3) ? angd(cand) : xyd(cand);
    double p0 = q0 + ((i == 0) ? rv : 0.0);
    double p1 = q1 + ((i == 1) ? rv : 0.0);
    double p2 = q2 + ((i == 2) ? rv : 0.0);
    double x0 = q3 + ((i == 3) ? rv : 0.0);
    double y0 = q4 + ((i == 4) ? rv : 0.0);

    JPd j = jprep_d(p0, p1, p2);  // f64 always: discrete decisions exact

    // ---------------- packed f32 prescreen (pixel-pair lanes) -----------
    float blf;
    {
      f32x2 ns1v = v2((float)(-j.s1)), ns2v = v2((float)(-j.s2));
      f32x2 ns3v = v2((float)(-j.s3)), ns4v = v2((float)(-j.s4));
      float c1f = (float)j.c1, c2f = (float)j.c2;
      float c3f = (float)j.c3, c4f = (float)j.c4;
      f32x2 sg13v = v2((float)j.sg13), sg42v = v2((float)j.sg42);
      f32x2 nsg13v = -sg13v, nsg42v = -sg42v;
      f32x2 gt13v = v2((float)j.gt13), gt42v = v2((float)j.gt42);
      f32x2 dxp[4];
#pragma unroll
      for (int t = 0; t < 4; ++t)
        dxp[t] = (f32x2){(float)(lin8d(2 * t) - x0),
                         (float)(lin8d(2 * t + 1) - x0)};

      f32x2 den0v = {0, 0}, den1v = {0, 0};
      f32x2 n00v = {0, 0}, n01v = {0, 0}, n10v = {0, 0}, n11v = {0, 0};
      f32x2 n20v = {0, 0}, n21v = {0, 0};
      f32x2 W00v = {0, 0}, W01v = {0, 0}, W11v = {0, 0};
#pragma unroll 1
      for (int r = 0; r < 4; ++r) {
        int iyy = hp * 4 + r;
        double liny = (iyy == 7) ? 1.0
                    : __dadd_rn(__dmul_rn((double)iyy, 2.0 / 7.0), -1.0);
        float dyf = (float)(liny - y0);
        f32x2 cdy1 = v2(c1f * dyf), cdy2 = v2(c2f * dyf);
        f32x2 cdy3 = v2(c3f * dyf), cdy4 = v2(c4f * dyf);
        const float* q0p = &simgp[0][hp * 32 + r * 8];
        const float* q1p = &simgp[1][hp * 32 + r * 8];
        const float* q2p = &simgp[2][hp * 32 + r * 8];
#pragma unroll
        for (int cp = 0; cp < 4; ++cp) {
          f32x2 dxv = dxp[cp];
          f32x2 hl1 = fma2(ns1v, dxv, cdy1);
          f32x2 hl3 = fma2(ns3v, dxv, cdy3);
          f32x2 hl4 = fma2(ns4v, dxv, cdy4);
          f32x2 hl2 = fma2(ns2v, dxv, cdy2);
          f32x2 d13 = fma2(sg13v,
              __builtin_elementwise_min(sg13v * hl1, nsg13v * hl3), gt13v);
          f32x2 d42 = fma2(sg42v,
              __builtin_elementwise_min(sg42v * hl4, nsg42v * hl2), gt42v);
          f32x2 h1 = hstepv(d13);
          f32x2 h2 = hstepv(d42);
          f32x2 w0 = v2(1.0f) - h1;
          f32x2 om = v2(1.0f) - h2;
          f32x2 w1 = h1 * om;
          f32x2 i0 = *(const f32x2*)(q0p + 2 * cp);
          f32x2 i1 = *(const f32x2*)(q1p + 2 * cp);
          f32x2 i2 = *(const f32x2*)(q2p + 2 * cp);
          den0v += w0; den1v += w1;
          n00v = fma2(i0, w0, n00v); n01v = fma2(i0, w1, n01v);
          n10v = fma2(i1, w0, n10v); n11v = fma2(i1, w1, n11v);
          n20v = fma2(i2, w0, n20v); n21v = fma2(i2, w1, n21v);
          W00v = fma2(w0, w0, W00v); W01v = fma2(w0, w1, W01v);
          W11v = fma2(w1, w1, W11v);
        }
      }
      float den0f = den0v.x + den0v.y, den1f = den1v.x + den1v.y;
      float n00f = n00v.x + n00v.y, n01f = n01v.x + n01v.y;
      float n10f = n10v.x + n10v.y, n11f = n11v.x + n11v.y;
      float n20f = n20v.x + n20v.y, n21f = n21v.x + n21v.y;
      float W00f = W00v.x + W00v.y, W01f = W01v.x + W01v.y;
      float W11f = W11v.x + W11v.y;

      den0f += __shfl_xor(den0f, 32); den1f += __shfl_xor(den1f, 32);
      n00f += __shfl_xor(n00f, 32); n01f += __shfl_xor(n01f, 32);
      n10f += __shfl_xor(n10f, 32); n11f += __shfl_xor(n11f, 32);
      n20f += __shfl_xor(n20f, 32); n21f += __shfl_xor(n21f, 32);
      W00f += __shfl_xor(W00f, 32); W01f += __shfl_xor(W01f, 32); W11f += __shfl_xor(W11f, 32);

      // sum(w0+w1+w2) = 64 exactly in ideal math; f32 dev ~6e-6 << band
      float den2f = 64.0f - den0f - den1f;
      float n02f = sx0f - n00f - n01f;
      float n12f = sx1f - n10f - n11f;
      float n22f = sx2f - n20f - n21f;
      float W02f = den0f - W00f - W01f;
      float W12f = den1f - W01f - W11f;
      float W22f = den2f - W02f - W12f;

      float e0 = den0f + 1e-10f, e1 = den1f + 1e-10f, e2 = den2f + 1e-10f;
      float r0f, r1f, r2f;
      asm("v_rcp_f32 %0, %1" : "=v"(r0f) : "v"(e0));
      asm("v_rcp_f32 %0, %1" : "=v"(r1f) : "v"(e1));
      asm("v_rcp_f32 %0, %1" : "=v"(r2f) : "v"(e2));
      r0f = fmaf(fmaf(-e0, r0f, 1.0f), r0f, r0f);
      r1f = fmaf(fmaf(-e1, r1f, 1.0f), r1f, r1f);
      r2f = fmaf(fmaf(-e2, r2f, 1.0f), r2f, r2f);
      float c00 = n00f * r0f, c01 = n01f * r1f, c02 = n02f * r2f;
      float c10 = n10f * r0f, c11 = n11f * r1f, c12 = n12f * r2f;
      float c20 = n20f * r0f, c21 = n21f * r1f, c22 = n22f * r2f;

      float lossf =
          c00 * (W00f * c00 + W01f * c01 + W02f * c02 - 2.0f * n00f) +
          c01 * (W01f * c00 + W11f * c01 + W12f * c02 - 2.0f * n01f) +
          c02 * (W02f * c00 + W12f * c01 + W22f * c02 - 2.0f * n02f) +
          c10 * (W00f * c10 + W01f * c11 + W02f * c12 - 2.0f * n10f) +
          c11 * (W01f * c10 + W11f * c11 + W12f * c12 - 2.0f * n11f) +
          c12 * (W02f * c10 + W12f * c11 + W22f * c12 - 2.0f * n12f) +
          c20 * (W00f * c20 + W01f * c21 + W02f * c22 - 2.0f * n20f) +
          c21 * (W01f * c20 + W11f * c21 + W12f * c22 - 2.0f * n21f) +
          c22 * (W02f * c20 + W12f * c21 + W22f * c22 - 2.0f * n22f);

      blf = (cand < 31) ? lossf : 3.0e38f;
    }

    float mnf = blf;
#pragma unroll
    for (int m = 1; m <= 16; m <<= 1) mnf = fminf(mnf, __shfl_xor(mnf, m));
    bool inb = (cand < 31) && (blf <= mnf + BANDF);
    unsigned bal32 = (unsigned)__ballot(inb);

    int bi;
    if (__popc(bal32) == 1) {
      bi = __ffs(bal32) - 1;   // unique winner: f32 decision is safe
    } else {
      // ---- cooperative f64 verify: lane = pixel, serial over in-band
      // candidates (ascending index = np.argmin first-index tie-break).
      double bestLoss = (double)INFINITY;
      int bi0 = 0;
      unsigned rem = bal32;
#pragma unroll 1
      while (rem) {
        int c = __ffs(rem) - 1;
        rem &= rem - 1;
        double rvc = (i < 3) ? angd(c) : xyd(c);
        double x0c = q3 + ((i == 3) ? rvc : 0.0);
        double y0c = q4 + ((i == 4) ? rvc : 0.0);
        JPd jc;
        jc.s1 = __shfl(j.s1, c);  jc.c1 = __shfl(j.c1, c);
        jc.s2 = __shfl(j.s2, c);  jc.c2 = __shfl(j.c2, c);
        jc.s3 = __shfl(j.s3, c);  jc.c3 = __shfl(j.c3, c);
        jc.s4 = __shfl(j.s4, c);  jc.c4 = __shfl(j.c4, c);
        jc.sg13 = __shfl(j.sg13, c); jc.sg42 = __shfl(j.sg42, c);
        jc.gt13 = __shfl(j.gt13, c); jc.gt42 = __shfl(j.gt42, c);

        double d13, d42;
        jdist_d(jc, vlinx - x0c, vliny - y0c, d13, d42);
        double h1, h2;
        hstep2_tab(stab, d13, d42, h1, h2);
        double w0 = 1.0 - h1;
        double w1 = h1 * (1.0 - h2);
        double ix = (double)vim.x, iy2 = (double)vim.y, iz = (double)vim.z;
        double s0 = w0, s1 = w1;
        double s3 = ix * w0, s4 = ix * w1;
        double s5 = iy2 * w0, s6 = iy2 * w1;
        double s7 = iz * w0, s8 = iz * w1;
        double s9 = w0 * w0, s10 = w0 * w1, s11 = w1 * w1;
#pragma unroll
        for (int m = 1; m <= 32; m <<= 1) {
          s0 += __shfl_xor(s0, m);  s1 += __shfl_xor(s1, m);
          s3 += __shfl_xor(s3, m);  s4 += __shfl_xor(s4, m);
          s5 += __shfl_xor(s5, m);  s6 += __shfl_xor(s6, m);
          s7 += __shfl_xor(s7, m);  s8 += __shfl_xor(s8, m);
          s9 += __shfl_xor(s9, m);  s10 += __shfl_xor(s10, m);
          s11 += __shfl_xor(s11, m);
        }
        double den0 = s0, den1 = s1;
        double den2 = 64.0 - den0 - den1;   // Sigma w = 1/px (dev ~1e-14)
        double n00 = s3, n01 = s4, n10 = s5, n11 = s6, n20 = s7, n21 = s8;
        double W00 = s9, W01 = s10, W11 = s11;

        double n02 = sx0 - n00 - n01;
        double n12 = sx1 - n10 - n11;
        double n22 = sx2 - n20 - n21;
        double W02 = den0 - W00 - W01;
        double W12 = den1 - W01 - W11;
        double W22 = den2 - W02 - W12;

        double r0 = rcp_nr(den0 + 1e-10);
        double r1 = rcp_nr(den1 + 1e-10);
        double r2 = rcp_nr(den2 + 1e-10);
        double c00 = n00 * r0, c01 = n01 * r1, c02 = n02 * r2;
        double c10 = n10 * r0, c11 = n11 * r1, c12 = n12 * r2;
        double c20 = n20 * r0, c21 = n21 * r1, c22 = n22 * r2;

        double loss =
            c00 * (W00 * c00 + W01 * c01 + W02 * c02 - 2.0 * n00) +
            c01 * (W01 * c00 + W11 * c01 + W12 * c02 - 2.0 * n01) +
            c02 * (W02 * c00 + W12 * c01 + W22 * c02 - 2.0 * n02) +
            c10 * (W00 * c10 + W01 * c11 + W02 * c12 - 2.0 * n10) +
            c11 * (W01 * c10 + W11 * c11 + W12 * c12 - 2.0 * n11) +
            c12 * (W02 * c10 + W12 * c11 + W22 * c12 - 2.0 * n12) +
            c20 * (W00 * c20 + W01 * c21 + W02 * c22 - 2.0 * n20) +
            c21 * (W01 * c20 + W11 * c21 + W12 * c22 - 2.0 * n21) +
            c22 * (W02 * c20 + W12 * c21 + W22 * c22 - 2.0 * n22);

        if (loss < bestLoss) { bestLoss = loss; bi0 = c; }
      }
      bi = bi0;
    }

    double upd = (i < 3) ? angd(bi) : xyd(bi);
    if (i == 0) q0 += upd;
    else if (i == 1) q1 += upd;
    else if (i == 2) q2 += upd;
    else if (i == 3) q3 += upd;
    else q4 += upd;
  }

  if (lane == 0) {
    pout[patch * 5 + 0] = q0;
    pout[patch * 5 + 1] = q1;
    pout[patch * 5 + 2] = q2;
    pout[patch * 5 + 3] = q3;
    pout[patch * 5 + 4] = q4;
  }
}

// ---------------- Kernel B: final reconstruction + fold (atomic) --------
__global__ void __launch_bounds__(256) foj_final(const float* __restrict__ x,
                                                 const double* __restrict__ pin,
                                                 float* __restrict__ out) {
  int lane = threadIdx.x & 63;
  int patch = blockIdx.x * 4 + (threadIdx.x >> 6);
  if (patch >= NPATCH) return;
  int ph = patch / WP_;
  int pw = patch - ph * WP_;
  double q0 = pin[patch * 5 + 0];
  double q1 = pin[patch * 5 + 1];
  double q2 = pin[patch * 5 + 2];
  double x0 = pin[patch * 5 + 3];
  double y0 = pin[patch * 5 + 4];

  JPd j = jprep_d(q0, q1, q2);
  int pi2 = lane >> 3, pj = lane & 7;
  double dx = lin8d(pj) - x0;
  double dy = lin8d(pi2) - y0;
  double d13, d42;
  jdist_d(j, dx, dy, d13, d42);
  double h1 = 0.5 + 0.31830988618379067154 * atan(d13 * 100.0);  // ocml
  double h2 = 0.5 + 0.31830988618379067154 * atan(d42 * 100.0);
  double w0 = 1.0 - h1;
  double w1 = h1 * (1.0 - h2);
  double w2 = h1 * h2;

  int oy = ph * 4 + pi2, ox = pw * 4 + pj;
  double im0 = (double)x[oy * 256 + ox];
  double im1 = (double)x[65536 + oy * 256 + ox];
  double im2 = (double)x[131072 + oy * 256 + ox];

  double red[12] = {w0, w1, w2,
                    im0 * w0, im0 * w1, im0 * w2,
                    im1 * w0, im1 * w1, im1 * w2,
                    im2 * w0, im2 * w1, im2 * w2};
#pragma unroll
  for (int t = 0; t < 12; ++t) {
    double v = red[t];
#pragma unroll
    for (int m = 1; m <= 32; m <<= 1) v += __shfl_xor(v, m);
    red[t] = v;
  }
  double e0 = red[0] + 1e-10, e1 = red[1] + 1e-10, e2 = red[2] + 1e-10;
  double pv0 = w0 * (red[3] / e0) + w1 * (red[4] / e1) + w2 * (red[5] / e2);
  double pv1 = w0 * (red[6] / e0) + w1 * (red[7] / e1) + w2 * (red[8] / e2);
  double pv2 = w0 * (red[9] / e0) + w1 * (red[10] / e1) + w2 * (red[11] / e2);

  double minabs = (d13 < 0.0) ? -d13
                              : ((d42 < 0.0) ? fmin(d13, -d42) : fmin(d13, d42));
  double tb = minabs / 0.05;
  double bnd = 1.0 / (1.0 + tb * tb);

  atomicAdd(&out[oy * 256 + ox], (float)pv0);
  atomicAdd(&out[65536 + oy * 256 + ox], (float)pv1);
  atomicAdd(&out[131072 + oy * 256 + ox], (float)pv2);
  atomicAdd(&out[196608 + oy * 256 + ox], (float)bnd);
}

// ---------------- Kernel C: divide by num_patches -----------------------
__global__ void __launch_bounds__(256) foj_norm(float* __restrict__ out) {
  int idx = blockIdx.x * 256 + threadIdx.x;
  int y = idx >> 8, xx = idx & 255;
  int hlo = (y >= 4) ? ((y - 4) >> 2) : 0;
  int hhi = min(62, y >> 2);
  int wlo = (xx >= 4) ? ((xx - 4) >> 2) : 0;
  int whi = min(62, xx >> 2);
  float np_ = (float)((hhi - hlo + 1) * (whi - wlo + 1));
  out[idx] /= np_;
  out[65536 + idx] /= np_;
  out[131072 + idx] /= np_;
  out[196608 + idx] /= np_;
}

extern "C" void kernel_launch(void* const* d_in, const int* in_sizes, int n_in,
                              void* d_out, int out_size, void* d_ws, size_t ws_size,
                              hipStream_t stream) {
  const float* x = (const float*)d_in[0];
  float* out = (float*)d_out;
  double* pws = (double*)d_ws;  // 3969*5 doubles = ~159 KB scratch

  foj_descent<<<NPATCH, 64, 0, stream>>>(x, pws);
  hipMemsetAsync(d_out, 0, (size_t)out_size * sizeof(float), stream);
  foj_final<<<(NPATCH + 3) / 4, 256, 0, stream>>>(x, pws, out);
  foj_norm<<<256, 256, 0, stream>>>(out);
}